// Round 5
// baseline (289.467 us; speedup 1.0000x reference)
//
#include <hip/hip_runtime.h>
#include <cstddef>

typedef __attribute__((ext_vector_type(4))) float f32x4;
typedef __attribute__((ext_vector_type(16))) float f32x16;
typedef __attribute__((ext_vector_type(8))) short bf16x8;

#define MFMA16(A, B, C) __builtin_amdgcn_mfma_f32_16x16x32_bf16(A, B, C, 0, 0, 0)
#define MFMA32(A, B, C) __builtin_amdgcn_mfma_f32_32x32x16_bf16(A, B, C, 0, 0, 0)

__device__ __forceinline__ unsigned short f2bf(float f) {
  unsigned u = __float_as_uint(f);
  u += 0x7fffu + ((u >> 16) & 1u);
  return (unsigned short)(u >> 16);
}
__device__ __forceinline__ float bf2f(unsigned short s) {
  return __uint_as_float(((unsigned)s) << 16);
}

// ---------- fused weight prep ----------

__global__ void prep_k(const float* __restrict__ Wf, const float* __restrict__ Wg,
                       const float* __restrict__ Wh, const float* __restrict__ Wv,
                       unsigned short* __restrict__ wfh, unsigned short* __restrict__ wfl,
                       unsigned short* __restrict__ wgh, unsigned short* __restrict__ wgl,
                       unsigned short* __restrict__ whb, unsigned short* __restrict__ wvb) {
  int i = blockIdx.x * 256 + threadIdx.x;
  if (i < 32768) {
    float v = Wf[i]; unsigned short h = f2bf(v);
    wfh[i] = h; wfl[i] = f2bf(v - bf2f(h));
  } else if (i < 65536) {
    int j = i - 32768;
    float v = Wg[j]; unsigned short h = f2bf(v);
    wgh[j] = h; wgl[j] = f2bf(v - bf2f(h));
  } else if (i < 196608) {
    int j = i - 65536;
    whb[j] = f2bf(Wh[j]);
  } else if (i < 327680) {
    int j = i - 196608;
    wvb[j] = f2bf(Wv[j]);
  }
}

// ---------- fused f+g+v conv: role 0 = f+g (split), role 1/2 = v oc-halves ----------
// Double-buffered LDS staging, early-issued float4 loads.

__global__ __launch_bounds__(256)
void conv_fgv(const float* __restrict__ x,
              const unsigned short* __restrict__ wfh_, const unsigned short* __restrict__ wfl_,
              const unsigned short* __restrict__ wgh_, const unsigned short* __restrict__ wgl_,
              const unsigned short* __restrict__ whb_,
              const float* __restrict__ bf_, const float* __restrict__ bg_,
              const float* __restrict__ bh_,
              unsigned short* __restrict__ fhi, unsigned short* __restrict__ flo,
              unsigned short* __restrict__ ghi, unsigned short* __restrict__ glo,
              unsigned short* __restrict__ vp)
{
  __shared__ __align__(16) char smem[40960];
  const int role = blockIdx.y;
  const int b = blockIdx.z, hp = blockIdx.x, n0 = hp * 128;
  const int tid = threadIdx.x, w = tid >> 6, lane = tid & 63, q = lane & 15, qt = lane >> 4;
  const int srow = tid >> 5;          // staging k row base
  const int scol = (tid & 31) * 4;    // staging n col

  if (role == 0) {
    // -------- f + g path (split bf16) --------
    f32x4 accf[2][4], accg[2][4];
    #pragma unroll
    for (int nt = 0; nt < 2; ++nt)
      #pragma unroll
      for (int ot = 0; ot < 4; ++ot) {
        accf[nt][ot] = (f32x4){0.f, 0.f, 0.f, 0.f};
        accg[nt][ot] = (f32x4){0.f, 0.f, 0.f, 0.f};
      }
    float4 st[4];
    #pragma unroll
    for (int i = 0; i < 4; ++i)
      st[i] = *(const float4*)&x[((size_t)(b * 512) + srow + i * 8) * 4096 + n0 + scol];
    {
      unsigned short (*ah)[40] = (unsigned short(*)[40])(smem);
      unsigned short (*al)[40] = (unsigned short(*)[40])(smem + 10240);
      #pragma unroll
      for (int i = 0; i < 4; ++i) {
        int k = srow + i * 8;
        #pragma unroll
        for (int j = 0; j < 4; ++j) {
          float v = ((const float*)&st[i])[j];
          unsigned short h = f2bf(v);
          ah[scol + j][k] = h;
          al[scol + j][k] = f2bf(v - bf2f(h));
        }
      }
    }
    __syncthreads();
    for (int cc = 0; cc < 16; ++cc) {
      const int cur = cc & 1;
      unsigned short (*ah)[40] = (unsigned short(*)[40])(smem + cur * 20480);
      unsigned short (*al)[40] = (unsigned short(*)[40])(smem + cur * 20480 + 10240);
      unsigned short (*nh)[40] = (unsigned short(*)[40])(smem + (cur ^ 1) * 20480);
      unsigned short (*nl)[40] = (unsigned short(*)[40])(smem + (cur ^ 1) * 20480 + 10240);
      if (cc < 15) {
        #pragma unroll
        for (int i = 0; i < 4; ++i)
          st[i] = *(const float4*)&x[((size_t)(b * 512 + (cc + 1) * 32) + srow + i * 8) * 4096 + n0 + scol];
      }
      bf16x8 Ah[2], Al[2];
      #pragma unroll
      for (int nt = 0; nt < 2; ++nt) {
        Ah[nt] = *(const bf16x8*)&ah[w * 32 + nt * 16 + q][qt * 8];
        Al[nt] = *(const bf16x8*)&al[w * 32 + nt * 16 + q][qt * 8];
      }
      const int c0 = cc * 32;
      {
        bf16x8 Bh[4], Bl[4];
        #pragma unroll
        for (int ot = 0; ot < 4; ++ot) {
          size_t wb = (size_t)(ot * 16 + q) * 512 + c0 + qt * 8;
          Bh[ot] = *(const bf16x8*)(wfh_ + wb);
          Bl[ot] = *(const bf16x8*)(wfl_ + wb);
        }
        #pragma unroll
        for (int nt = 0; nt < 2; ++nt)
          #pragma unroll
          for (int ot = 0; ot < 4; ++ot) {
            accf[nt][ot] = MFMA16(Ah[nt], Bh[ot], accf[nt][ot]);
            accf[nt][ot] = MFMA16(Ah[nt], Bl[ot], accf[nt][ot]);
            accf[nt][ot] = MFMA16(Al[nt], Bh[ot], accf[nt][ot]);
          }
      }
      {
        bf16x8 Bh[4], Bl[4];
        #pragma unroll
        for (int ot = 0; ot < 4; ++ot) {
          size_t wb = (size_t)(ot * 16 + q) * 512 + c0 + qt * 8;
          Bh[ot] = *(const bf16x8*)(wgh_ + wb);
          Bl[ot] = *(const bf16x8*)(wgl_ + wb);
        }
        #pragma unroll
        for (int nt = 0; nt < 2; ++nt)
          #pragma unroll
          for (int ot = 0; ot < 4; ++ot) {
            accg[nt][ot] = MFMA16(Ah[nt], Bh[ot], accg[nt][ot]);
            accg[nt][ot] = MFMA16(Ah[nt], Bl[ot], accg[nt][ot]);
            accg[nt][ot] = MFMA16(Al[nt], Bh[ot], accg[nt][ot]);
          }
      }
      if (cc < 15) {
        #pragma unroll
        for (int i = 0; i < 4; ++i) {
          int k = srow + i * 8;
          #pragma unroll
          for (int j = 0; j < 4; ++j) {
            float v = ((const float*)&st[i])[j];
            unsigned short h = f2bf(v);
            nh[scol + j][k] = h;
            nl[scol + j][k] = f2bf(v - bf2f(h));
          }
        }
      }
      __syncthreads();
    }
    // f epilogue: direct split write
    #pragma unroll
    for (int nt = 0; nt < 2; ++nt)
      #pragma unroll
      for (int ot = 0; ot < 4; ++ot)
        #pragma unroll
        for (int r = 0; r < 4; ++r) {
          int n = n0 + w * 32 + nt * 16 + qt * 4 + r;
          int oc = ot * 16 + q;
          float v = accf[nt][ot][r] + bf_[oc];
          unsigned short h = f2bf(v);
          size_t o = ((size_t)b * 4096 + n) * 64 + oc;
          fhi[o] = h;
          flo[o] = f2bf(v - bf2f(h));
        }
    // g epilogue: pool via LDS
    float (*pl)[66] = (float(*)[66])smem;
    #pragma unroll
    for (int nt = 0; nt < 2; ++nt)
      #pragma unroll
      for (int ot = 0; ot < 4; ++ot)
        #pragma unroll
        for (int r = 0; r < 4; ++r)
          pl[w * 32 + nt * 16 + qt * 4 + r][ot * 16 + q] = accg[nt][ot][r];
    __syncthreads();
    const int c = tid & 63;
    #pragma unroll
    for (int it = 0; it < 8; ++it) {
      int wp = (tid >> 6) + it * 4;
      float v = fmaxf(fmaxf(pl[2 * wp][c], pl[2 * wp + 1][c]),
                      fmaxf(pl[64 + 2 * wp][c], pl[65 + 2 * wp][c])) + bg_[c];
      unsigned short h = f2bf(v);
      size_t o = ((size_t)b * 1024 + hp * 32 + wp) * 64 + c;
      ghi[o] = h;
      glo[o] = f2bf(v - bf2f(h));
    }
  } else {
    // -------- v path (hi-only), oc half --------
    const int oc0 = (role - 1) * 128;
    f32x4 acc[2][8];
    #pragma unroll
    for (int nt = 0; nt < 2; ++nt)
      #pragma unroll
      for (int ot = 0; ot < 8; ++ot) acc[nt][ot] = (f32x4){0.f, 0.f, 0.f, 0.f};
    float4 st[4];
    #pragma unroll
    for (int i = 0; i < 4; ++i)
      st[i] = *(const float4*)&x[((size_t)(b * 512) + srow + i * 8) * 4096 + n0 + scol];
    {
      unsigned short (*ah)[40] = (unsigned short(*)[40])(smem);
      #pragma unroll
      for (int i = 0; i < 4; ++i) {
        int k = srow + i * 8;
        #pragma unroll
        for (int j = 0; j < 4; ++j)
          ah[scol + j][k] = f2bf(((const float*)&st[i])[j]);
      }
    }
    __syncthreads();
    for (int cc = 0; cc < 16; ++cc) {
      const int cur = cc & 1;
      unsigned short (*ah)[40] = (unsigned short(*)[40])(smem + cur * 10240);
      unsigned short (*nh)[40] = (unsigned short(*)[40])(smem + (cur ^ 1) * 10240);
      if (cc < 15) {
        #pragma unroll
        for (int i = 0; i < 4; ++i)
          st[i] = *(const float4*)&x[((size_t)(b * 512 + (cc + 1) * 32) + srow + i * 8) * 4096 + n0 + scol];
      }
      bf16x8 A_[2], B_[8];
      #pragma unroll
      for (int nt = 0; nt < 2; ++nt)
        A_[nt] = *(const bf16x8*)&ah[w * 32 + nt * 16 + q][qt * 8];
      #pragma unroll
      for (int ot = 0; ot < 8; ++ot)
        B_[ot] = *(const bf16x8*)(whb_ + (size_t)(oc0 + ot * 16 + q) * 512 + cc * 32 + qt * 8);
      #pragma unroll
      for (int nt = 0; nt < 2; ++nt)
        #pragma unroll
        for (int ot = 0; ot < 8; ++ot)
          acc[nt][ot] = MFMA16(A_[nt], B_[ot], acc[nt][ot]);
      if (cc < 15) {
        #pragma unroll
        for (int i = 0; i < 4; ++i) {
          int k = srow + i * 8;
          #pragma unroll
          for (int j = 0; j < 4; ++j)
            nh[scol + j][k] = f2bf(((const float*)&st[i])[j]);
        }
      }
      __syncthreads();
    }
    float (*pl)[65] = (float(*)[65])smem;
    #pragma unroll
    for (int oh = 0; oh < 2; ++oh) {
      if (oh) __syncthreads();
      #pragma unroll
      for (int nt = 0; nt < 2; ++nt)
        #pragma unroll
        for (int ot4 = 0; ot4 < 4; ++ot4)
          #pragma unroll
          for (int r = 0; r < 4; ++r)
            pl[w * 32 + nt * 16 + qt * 4 + r][ot4 * 16 + q] = acc[nt][oh * 4 + ot4][r];
      __syncthreads();
      const int wp = tid & 31;
      #pragma unroll
      for (int it = 0; it < 8; ++it) {
        int cc2 = (tid >> 5) + it * 8;
        float v = fmaxf(fmaxf(pl[2 * wp][cc2], pl[2 * wp + 1][cc2]),
                        fmaxf(pl[64 + 2 * wp][cc2], pl[65 + 2 * wp][cc2])) + bh_[oc0 + oh * 64 + cc2];
        vp[((size_t)(b * 256) + oc0 + oh * 64 + cc2) * 1024 + hp * 32 + wp] = f2bf(v);
      }
    }
  }
}

// ---------- fused attention: QB=32, online softmax over 2 m-chunks of 512 ----------

#define PROW 520

__global__ __launch_bounds__(256, 3)
void attn_mfma(const unsigned short* __restrict__ fhi, const unsigned short* __restrict__ flo,
               const unsigned short* __restrict__ ghi, const unsigned short* __restrict__ glo,
               const unsigned short* __restrict__ vp, unsigned short* __restrict__ oT)
{
  __shared__ unsigned short P[32 * PROW];          // 33,280 B
  __shared__ float redm[4][32], reds[4][32];
  __shared__ float rfrow[32], Srow[32];
  const int b = blockIdx.y, n0 = blockIdx.x * 32;
  const int tid = threadIdx.x, w = tid >> 6, lane = tid & 63;
  const int q32 = lane & 31, hl = lane >> 5;
  const int q16 = lane & 15, qt = lane >> 4;

  // f B-frags (32x32x16): col = q32, k-slices over c
  bf16x8 Fh[4], Fl[4];
  {
    size_t fb = ((size_t)b * 4096 + n0 + q32) * 64 + hl * 8;
    #pragma unroll
    for (int s = 0; s < 4; ++s) {
      Fh[s] = *(const bf16x8*)(fhi + fb + s * 16);
      Fl[s] = *(const bf16x8*)(flo + fb + s * 16);
    }
  }

  float M = -3.0e38f;
  f32x4 oacc[4][2];
  #pragma unroll
  for (int c4 = 0; c4 < 4; ++c4) {
    oacc[c4][0] = (f32x4){0.f, 0.f, 0.f, 0.f};
    oacc[c4][1] = (f32x4){0.f, 0.f, 0.f, 0.f};
  }

  #pragma unroll
  for (int mc = 0; mc < 2; ++mc) {
    // ---- s phase: wave owns m-range [mc*512 + w*128, +128), 4 tiles of 32 ----
    f32x16 sa[4] = {};
    const size_t g0 = ((size_t)b * 1024 + mc * 512 + w * 128 + q32) * 64 + hl * 8;
    #pragma unroll
    for (int t = 0; t < 4; ++t) {
      size_t gb = g0 + (size_t)t * 32 * 64;
      bf16x8 Gh[4], Gl[4];
      #pragma unroll
      for (int s = 0; s < 4; ++s) {
        Gh[s] = *(const bf16x8*)(ghi + gb + s * 16);
        Gl[s] = *(const bf16x8*)(glo + gb + s * 16);
      }
      #pragma unroll
      for (int s = 0; s < 4; ++s) {
        sa[t] = MFMA32(Gh[s], Fh[s], sa[t]);
        sa[t] = MFMA32(Gh[s], Fl[s], sa[t]);
        sa[t] = MFMA32(Gl[s], Fh[s], sa[t]);
      }
    }

    // ---- online softmax ----
    float mx = -3.0e38f;
    #pragma unroll
    for (int t = 0; t < 4; ++t)
      #pragma unroll
      for (int r = 0; r < 16; ++r) mx = fmaxf(mx, sa[t][r]);
    mx = fmaxf(mx, __shfl_xor(mx, 32));
    if (lane < 32) redm[w][lane] = mx;
    __syncthreads();                                           // A
    float gmx = fmaxf(fmaxf(redm[0][q32], redm[1][q32]), fmaxf(redm[2][q32], redm[3][q32]));
    float Mnew = fmaxf(M, gmx);
    float rf = __expf(M - Mnew);
    M = Mnew;
    float csum = 0.f;
    #pragma unroll
    for (int t = 0; t < 4; ++t)
      #pragma unroll
      for (int r = 0; r < 16; ++r) {
        float p = __expf(sa[t][r] - Mnew);
        sa[t][r] = p;
        csum += p;
      }
    csum += __shfl_xor(csum, 32);
    if (lane < 32) reds[w][lane] = csum;

    // P write: rows m = w*128 + t*32 + 8*j + 4*hl + i
    #pragma unroll
    for (int t = 0; t < 4; ++t)
      #pragma unroll
      for (int j = 0; j < 4; ++j) {
        uint2 pk;
        pk.x = (unsigned)f2bf(sa[t][4 * j + 0]) | ((unsigned)f2bf(sa[t][4 * j + 1]) << 16);
        pk.y = (unsigned)f2bf(sa[t][4 * j + 2]) | ((unsigned)f2bf(sa[t][4 * j + 3]) << 16);
        *(uint2*)&P[q32 * PROW + w * 128 + t * 32 + j * 8 + hl * 4] = pk;
      }
    __syncthreads();                                           // B
    float ct = reds[0][q32] + reds[1][q32] + reds[2][q32] + reds[3][q32];
    if (w == 0 && lane < 32) {
      Srow[lane] = (mc == 0) ? ct : Srow[lane] * rf + ct;
      rfrow[lane] = rf;
    }
    __syncthreads();                                           // B2

    // ---- PV over this chunk ----
    if (mc == 1) {
      float rf0 = rfrow[q16], rf1 = rfrow[16 + q16];
      #pragma unroll
      for (int c4 = 0; c4 < 4; ++c4) {
        oacc[c4][0] *= rf0;
        oacc[c4][1] *= rf1;
      }
    }
    const size_t v0 = ((size_t)b * 256 + w * 64 + q16) * 1024 + mc * 512 + qt * 8;
    bf16x8 va0, va1, va2, va3, vb0, vb1, vb2, vb3;

#define LOADVA(KS) { size_t vb_ = v0 + (size_t)(KS) * 32; \
  va0 = *(const bf16x8*)(vp + vb_);         va1 = *(const bf16x8*)(vp + vb_ + 16384); \
  va2 = *(const bf16x8*)(vp + vb_ + 32768); va3 = *(const bf16x8*)(vp + vb_ + 49152); }
#define LOADVB(KS) { size_t vb_ = v0 + (size_t)(KS) * 32; \
  vb0 = *(const bf16x8*)(vp + vb_);         vb1 = *(const bf16x8*)(vp + vb_ + 16384); \
  vb2 = *(const bf16x8*)(vp + vb_ + 32768); vb3 = *(const bf16x8*)(vp + vb_ + 49152); }
#define PVMFMA(KS, V0, V1, V2, V3) { \
  bf16x8 pb0 = *(const bf16x8*)(&P[q16 * PROW + (KS) * 32 + qt * 8]); \
  bf16x8 pb1 = *(const bf16x8*)(&P[(16 + q16) * PROW + (KS) * 32 + qt * 8]); \
  oacc[0][0] = MFMA16(V0, pb0, oacc[0][0]); oacc[1][0] = MFMA16(V1, pb0, oacc[1][0]); \
  oacc[2][0] = MFMA16(V2, pb0, oacc[2][0]); oacc[3][0] = MFMA16(V3, pb0, oacc[3][0]); \
  oacc[0][1] = MFMA16(V0, pb1, oacc[0][1]); oacc[1][1] = MFMA16(V1, pb1, oacc[1][1]); \
  oacc[2][1] = MFMA16(V2, pb1, oacc[2][1]); oacc[3][1] = MFMA16(V3, pb1, oacc[3][1]); }

    LOADVA(0)
    LOADVB(1)
    #pragma unroll
    for (int kp = 0; kp < 8; ++kp) {
      PVMFMA(2 * kp, va0, va1, va2, va3)
      if (2 * kp + 2 < 16) LOADVA(2 * kp + 2)
      PVMFMA(2 * kp + 1, vb0, vb1, vb2, vb3)
      if (2 * kp + 3 < 16) LOADVB(2 * kp + 3)
    }
  }

  // ---- epilogue ----
  const float rinv0 = 1.0f / Srow[q16];
  const float rinv1 = 1.0f / Srow[16 + q16];
  #pragma unroll
  for (int c4 = 0; c4 < 4; ++c4) {
    uint2 pk0, pk1;
    pk0.x = (unsigned)f2bf(oacc[c4][0][0] * rinv0) | ((unsigned)f2bf(oacc[c4][0][1] * rinv0) << 16);
    pk0.y = (unsigned)f2bf(oacc[c4][0][2] * rinv0) | ((unsigned)f2bf(oacc[c4][0][3] * rinv0) << 16);
    pk1.x = (unsigned)f2bf(oacc[c4][1][0] * rinv1) | ((unsigned)f2bf(oacc[c4][1][1] * rinv1) << 16);
    pk1.y = (unsigned)f2bf(oacc[c4][1][2] * rinv1) | ((unsigned)f2bf(oacc[c4][1][3] * rinv1) << 16);
    *(uint2*)(oT + ((size_t)b * 4096 + n0 + q16) * 256 + w * 64 + c4 * 16 + qt * 4) = pk0;
    *(uint2*)(oT + ((size_t)b * 4096 + n0 + 16 + q16) * 256 + w * 64 + c4 * 16 + qt * 4) = pk1;
  }
}

// ---------- final conv: 128n x 128oc, direct-fragment store, out = gamma*(oT.Wv + bv) + x ----------

__global__ __launch_bounds__(256)
void conv_final(const unsigned short* __restrict__ A, const unsigned short* __restrict__ W,
                const float* __restrict__ bias, float* __restrict__ out,
                const float* __restrict__ resid, const float* __restrict__ gamma_p)
{
  const int b = blockIdx.z, oc0 = blockIdx.y * 128, n0 = blockIdx.x * 128;
  const int tid = threadIdx.x, w = tid >> 6, lane = tid & 63, q = lane & 15, qt = lane >> 4;

  f32x4 acc[2][8];
  #pragma unroll
  for (int nt = 0; nt < 2; ++nt)
    #pragma unroll
    for (int ot = 0; ot < 8; ++ot) acc[nt][ot] = (f32x4){0.f, 0.f, 0.f, 0.f};

  const size_t a0 = ((size_t)b * 4096 + n0 + w * 32 + q) * 256 + qt * 8;
  #pragma unroll
  for (int ks = 0; ks < 8; ++ks) {
    bf16x8 A_[2], B_[8];
    #pragma unroll
    for (int nt = 0; nt < 2; ++nt)
      A_[nt] = *(const bf16x8*)(A + a0 + nt * 16 * 256 + ks * 32);
    #pragma unroll
    for (int ot = 0; ot < 8; ++ot)
      B_[ot] = *(const bf16x8*)(W + (size_t)(oc0 + ot * 16 + q) * 256 + ks * 32 + qt * 8);
    #pragma unroll
    for (int nt = 0; nt < 2; ++nt)
      #pragma unroll
      for (int ot = 0; ot < 8; ++ot)
        acc[nt][ot] = MFMA16(A_[nt], B_[ot], acc[nt][ot]);
  }

  const float gm = gamma_p[0];
  #pragma unroll
  for (int ot = 0; ot < 8; ++ot) {
    int oc = oc0 + ot * 16 + q;
    float bs = bias[oc];
    #pragma unroll
    for (int nt = 0; nt < 2; ++nt) {
      int n = n0 + w * 32 + nt * 16 + qt * 4;
      size_t o = ((size_t)(b * 512) + oc) * 4096 + n;
      float4 rs = *(const float4*)&resid[o];
      float4 ov;
      ov.x = gm * (acc[nt][ot][0] + bs) + rs.x;
      ov.y = gm * (acc[nt][ot][1] + bs) + rs.y;
      ov.z = gm * (acc[nt][ot][2] + bs) + rs.z;
      ov.w = gm * (acc[nt][ot][3] + bs) + rs.w;
      *(float4*)&out[o] = ov;
    }
  }
}

// ---------- launch ----------

extern "C" void kernel_launch(void* const* d_in, const int* in_sizes, int n_in,
                              void* d_out, int out_size, void* d_ws, size_t ws_size,
                              hipStream_t stream) {
  const float* x     = (const float*)d_in[0];
  const float* Wf    = (const float*)d_in[1];
  const float* bf    = (const float*)d_in[2];
  const float* Wg    = (const float*)d_in[3];
  const float* bg    = (const float*)d_in[4];
  const float* Wh    = (const float*)d_in[5];
  const float* bh    = (const float*)d_in[6];
  const float* Wv    = (const float*)d_in[7];
  const float* bv    = (const float*)d_in[8];
  const float* gamma = (const float*)d_in[9];
  float* out = (float*)d_out;
  char* w = (char*)d_ws;

  unsigned short* fhi = (unsigned short*)(w);                 // 4 MB  [8][4096][64]
  unsigned short* flo = (unsigned short*)(w + 4194304);       // 4 MB
  unsigned short* ghi = (unsigned short*)(w + 8388608);       // 1 MB  [8][1024][64]
  unsigned short* glo = (unsigned short*)(w + 9437184);       // 1 MB
  unsigned short* vp  = (unsigned short*)(w + 10485760);      // 4 MB  [8][256][1024]
  unsigned short* oT  = (unsigned short*)(w + 14680064);      // 16 MB [8][4096][256]
  unsigned short* wfh = (unsigned short*)(w + 31457280);      // 64 KB [64][512]
  unsigned short* wfl = (unsigned short*)(w + 31522816);
  unsigned short* wgh = (unsigned short*)(w + 31588352);
  unsigned short* wgl = (unsigned short*)(w + 31653888);
  unsigned short* whb = (unsigned short*)(w + 31719424);      // 256 KB [256][512]
  unsigned short* wvb = (unsigned short*)(w + 31981568);      // 256 KB [512][256]

  prep_k<<<1280, 256, 0, stream>>>(Wf, Wg, Wh, Wv, wfh, wfl, wgh, wgl, whb, wvb);

  conv_fgv<<<dim3(32, 3, 8), 256, 0, stream>>>(x, wfh, wfl, wgh, wgl, whb,
                                               bf, bg, bh, fhi, flo, ghi, glo, vp);

  attn_mfma<<<dim3(128, 8), 256, 0, stream>>>(fhi, flo, ghi, glo, vp, oT);

  conv_final<<<dim3(32, 4, 8), 256, 0, stream>>>(oT, wvb, bv, out, x, gamma);
}

// Round 6
// 255.267 us; speedup vs baseline: 1.1340x; 1.1340x over previous
//
#include <hip/hip_runtime.h>
#include <cstddef>

typedef __attribute__((ext_vector_type(4))) float f32x4;
typedef __attribute__((ext_vector_type(16))) float f32x16;
typedef __attribute__((ext_vector_type(8))) short bf16x8;

#define MFMA16(A, B, C) __builtin_amdgcn_mfma_f32_16x16x32_bf16(A, B, C, 0, 0, 0)
#define MFMA32(A, B, C) __builtin_amdgcn_mfma_f32_32x32x16_bf16(A, B, C, 0, 0, 0)

__device__ __forceinline__ unsigned short f2bf(float f) {
  unsigned u = __float_as_uint(f);
  u += 0x7fffu + ((u >> 16) & 1u);
  return (unsigned short)(u >> 16);
}
__device__ __forceinline__ float bf2f(unsigned short s) {
  return __uint_as_float(((unsigned)s) << 16);
}

__device__ __forceinline__ bf16x8 ldfrag(const unsigned short* p) {
  bf16x8 r;
  *(uint2*)&r = *(const uint2*)p;
  *((uint2*)&r + 1) = *(const uint2*)(p + 4);
  return r;
}

// ---------- fused weight prep ----------

__global__ void prep_k(const float* __restrict__ Wf, const float* __restrict__ Wg,
                       const float* __restrict__ Wh, const float* __restrict__ Wv,
                       unsigned short* __restrict__ wfh, unsigned short* __restrict__ wfl,
                       unsigned short* __restrict__ wgh, unsigned short* __restrict__ wgl,
                       unsigned short* __restrict__ whb, unsigned short* __restrict__ wvb) {
  int i = blockIdx.x * 256 + threadIdx.x;
  if (i < 32768) {
    float v = Wf[i]; unsigned short h = f2bf(v);
    wfh[i] = h; wfl[i] = f2bf(v - bf2f(h));
  } else if (i < 65536) {
    int j = i - 32768;
    float v = Wg[j]; unsigned short h = f2bf(v);
    wgh[j] = h; wgl[j] = f2bf(v - bf2f(h));
  } else if (i < 196608) {
    int j = i - 65536;
    whb[j] = f2bf(Wh[j]);
  } else if (i < 327680) {
    int j = i - 196608;
    wvb[j] = f2bf(Wv[j]);
  }
}

// ---------- fused f+g+v conv with bank-balanced transposed staging ----------
// LDS tile: [128 n][44 shorts] per plane (row stride 88 B -> uniform 4 dwords/bank).
// role 0 = f+g (hi+lo planes), role 1/2 = v oc-halves (hi plane only).

#define ROWS 44          // shorts per n-row
#define PLANE 5632       // shorts per plane (128*44)
#define PLANEB 11264     // bytes per plane

__device__ __forceinline__ void stage2(char* smem, int buf, int nloc, int kqb,
                                       const float vv[4][4]) {
  unsigned short* bh = (unsigned short*)(smem + buf * (2 * PLANEB));
  unsigned short* bl = bh + PLANE;
  #pragma unroll
  for (int i = 0; i < 4; ++i) {
    unsigned hs[4], ls[4];
    #pragma unroll
    for (int j = 0; j < 4; ++j) {
      float v = vv[i][j];
      unsigned short h = f2bf(v);
      hs[j] = h; ls[j] = f2bf(v - bf2f(h));
    }
    uint2 ph, pl2;
    ph.x = hs[0] | (hs[1] << 16); ph.y = hs[2] | (hs[3] << 16);
    pl2.x = ls[0] | (ls[1] << 16); pl2.y = ls[2] | (ls[3] << 16);
    *(uint2*)(bh + nloc * ROWS + (kqb + i) * 4) = ph;
    *(uint2*)(bl + nloc * ROWS + (kqb + i) * 4) = pl2;
  }
}

__device__ __forceinline__ void stage1(char* smem, int buf, int nloc, int kqb,
                                       const float vv[4][4]) {
  unsigned short* bh = (unsigned short*)(smem + buf * PLANEB);
  #pragma unroll
  for (int i = 0; i < 4; ++i) {
    unsigned hs[4];
    #pragma unroll
    for (int j = 0; j < 4; ++j) hs[j] = f2bf(vv[i][j]);
    uint2 ph;
    ph.x = hs[0] | (hs[1] << 16); ph.y = hs[2] | (hs[3] << 16);
    *(uint2*)(bh + nloc * ROWS + (kqb + i) * 4) = ph;
  }
}

__global__ __launch_bounds__(256)
void conv_fgv(const float* __restrict__ x,
              const unsigned short* __restrict__ wfh_, const unsigned short* __restrict__ wfl_,
              const unsigned short* __restrict__ wgh_, const unsigned short* __restrict__ wgl_,
              const unsigned short* __restrict__ whb_,
              const float* __restrict__ bf_, const float* __restrict__ bg_,
              const float* __restrict__ bh_,
              unsigned short* __restrict__ fhi, unsigned short* __restrict__ flo,
              unsigned short* __restrict__ ghi, unsigned short* __restrict__ glo,
              unsigned short* __restrict__ vp)
{
  __shared__ __align__(16) char smem[45056];
  const int role = blockIdx.y;
  const int b = blockIdx.z, hp = blockIdx.x, n0 = hp * 128;
  const int tid = threadIdx.x, w = tid >> 6, lane = tid & 63, q = lane & 15, qt = lane >> 4;
  const int nloc = tid & 127;
  const int kqb = (tid >> 7) * 4;
  const float* xbase = x + (size_t)(b * 512) * 4096 + n0 + nloc;
  float vv[4][4];

  if (role == 0) {
    // -------- f + g path (split bf16) --------
    f32x4 accf[2][4], accg[2][4];
    #pragma unroll
    for (int nt = 0; nt < 2; ++nt)
      #pragma unroll
      for (int ot = 0; ot < 4; ++ot) {
        accf[nt][ot] = (f32x4){0.f, 0.f, 0.f, 0.f};
        accg[nt][ot] = (f32x4){0.f, 0.f, 0.f, 0.f};
      }
    #pragma unroll
    for (int i = 0; i < 4; ++i)
      #pragma unroll
      for (int j = 0; j < 4; ++j)
        vv[i][j] = xbase[(size_t)((kqb + i) * 4 + j) * 4096];
    stage2(smem, 0, nloc, kqb, vv);
    __syncthreads();
    for (int cc = 0; cc < 16; ++cc) {
      const int cur = cc & 1;
      if (cc < 15) {
        #pragma unroll
        for (int i = 0; i < 4; ++i)
          #pragma unroll
          for (int j = 0; j < 4; ++j)
            vv[i][j] = xbase[(size_t)((cc + 1) * 32 + (kqb + i) * 4 + j) * 4096];
      }
      const unsigned short* bh = (const unsigned short*)(smem + cur * (2 * PLANEB));
      const unsigned short* bl = bh + PLANE;
      bf16x8 Ah[2], Al[2];
      #pragma unroll
      for (int nt = 0; nt < 2; ++nt) {
        const int row = w * 32 + nt * 16 + q;
        Ah[nt] = ldfrag(bh + row * ROWS + qt * 8);
        Al[nt] = ldfrag(bl + row * ROWS + qt * 8);
      }
      const int c0 = cc * 32;
      {
        bf16x8 Bh[4], Bl[4];
        #pragma unroll
        for (int ot = 0; ot < 4; ++ot) {
          size_t wb = (size_t)(ot * 16 + q) * 512 + c0 + qt * 8;
          Bh[ot] = *(const bf16x8*)(wfh_ + wb);
          Bl[ot] = *(const bf16x8*)(wfl_ + wb);
        }
        #pragma unroll
        for (int nt = 0; nt < 2; ++nt)
          #pragma unroll
          for (int ot = 0; ot < 4; ++ot) {
            accf[nt][ot] = MFMA16(Ah[nt], Bh[ot], accf[nt][ot]);
            accf[nt][ot] = MFMA16(Ah[nt], Bl[ot], accf[nt][ot]);
            accf[nt][ot] = MFMA16(Al[nt], Bh[ot], accf[nt][ot]);
          }
      }
      {
        bf16x8 Bh[4], Bl[4];
        #pragma unroll
        for (int ot = 0; ot < 4; ++ot) {
          size_t wb = (size_t)(ot * 16 + q) * 512 + c0 + qt * 8;
          Bh[ot] = *(const bf16x8*)(wgh_ + wb);
          Bl[ot] = *(const bf16x8*)(wgl_ + wb);
        }
        #pragma unroll
        for (int nt = 0; nt < 2; ++nt)
          #pragma unroll
          for (int ot = 0; ot < 4; ++ot) {
            accg[nt][ot] = MFMA16(Ah[nt], Bh[ot], accg[nt][ot]);
            accg[nt][ot] = MFMA16(Ah[nt], Bl[ot], accg[nt][ot]);
            accg[nt][ot] = MFMA16(Al[nt], Bh[ot], accg[nt][ot]);
          }
      }
      if (cc < 15) stage2(smem, cur ^ 1, nloc, kqb, vv);
      __syncthreads();
    }
    // f epilogue: direct split write
    #pragma unroll
    for (int nt = 0; nt < 2; ++nt)
      #pragma unroll
      for (int ot = 0; ot < 4; ++ot)
        #pragma unroll
        for (int r = 0; r < 4; ++r) {
          int n = n0 + w * 32 + nt * 16 + qt * 4 + r;
          int oc = ot * 16 + q;
          float v = accf[nt][ot][r] + bf_[oc];
          unsigned short h = f2bf(v);
          size_t o = ((size_t)b * 4096 + n) * 64 + oc;
          fhi[o] = h;
          flo[o] = f2bf(v - bf2f(h));
        }
    // g epilogue: pool via LDS
    float (*pl)[67] = (float(*)[67])smem;
    #pragma unroll
    for (int nt = 0; nt < 2; ++nt)
      #pragma unroll
      for (int ot = 0; ot < 4; ++ot)
        #pragma unroll
        for (int r = 0; r < 4; ++r)
          pl[w * 32 + nt * 16 + qt * 4 + r][ot * 16 + q] = accg[nt][ot][r];
    __syncthreads();
    const int c = tid & 63;
    #pragma unroll
    for (int it = 0; it < 8; ++it) {
      int wp = (tid >> 6) + it * 4;
      float v = fmaxf(fmaxf(pl[2 * wp][c], pl[2 * wp + 1][c]),
                      fmaxf(pl[64 + 2 * wp][c], pl[65 + 2 * wp][c])) + bg_[c];
      unsigned short h = f2bf(v);
      size_t o = ((size_t)b * 1024 + hp * 32 + wp) * 64 + c;
      ghi[o] = h;
      glo[o] = f2bf(v - bf2f(h));
    }
  } else {
    // -------- v path (hi-only), oc half --------
    const int oc0 = (role - 1) * 128;
    f32x4 acc[2][8];
    #pragma unroll
    for (int nt = 0; nt < 2; ++nt)
      #pragma unroll
      for (int ot = 0; ot < 8; ++ot) acc[nt][ot] = (f32x4){0.f, 0.f, 0.f, 0.f};
    #pragma unroll
    for (int i = 0; i < 4; ++i)
      #pragma unroll
      for (int j = 0; j < 4; ++j)
        vv[i][j] = xbase[(size_t)((kqb + i) * 4 + j) * 4096];
    stage1(smem, 0, nloc, kqb, vv);
    __syncthreads();
    for (int cc = 0; cc < 16; ++cc) {
      const int cur = cc & 1;
      if (cc < 15) {
        #pragma unroll
        for (int i = 0; i < 4; ++i)
          #pragma unroll
          for (int j = 0; j < 4; ++j)
            vv[i][j] = xbase[(size_t)((cc + 1) * 32 + (kqb + i) * 4 + j) * 4096];
      }
      const unsigned short* bh = (const unsigned short*)(smem + cur * PLANEB);
      bf16x8 A_[2], B_[8];
      #pragma unroll
      for (int nt = 0; nt < 2; ++nt) {
        const int row = w * 32 + nt * 16 + q;
        A_[nt] = ldfrag(bh + row * ROWS + qt * 8);
      }
      #pragma unroll
      for (int ot = 0; ot < 8; ++ot)
        B_[ot] = *(const bf16x8*)(whb_ + (size_t)(oc0 + ot * 16 + q) * 512 + cc * 32 + qt * 8);
      #pragma unroll
      for (int nt = 0; nt < 2; ++nt)
        #pragma unroll
        for (int ot = 0; ot < 8; ++ot)
          acc[nt][ot] = MFMA16(A_[nt], B_[ot], acc[nt][ot]);
      if (cc < 15) stage1(smem, cur ^ 1, nloc, kqb, vv);
      __syncthreads();
    }
    float (*pl)[67] = (float(*)[67])smem;
    #pragma unroll
    for (int oh = 0; oh < 2; ++oh) {
      if (oh) __syncthreads();
      #pragma unroll
      for (int nt = 0; nt < 2; ++nt)
        #pragma unroll
        for (int ot4 = 0; ot4 < 4; ++ot4)
          #pragma unroll
          for (int r = 0; r < 4; ++r)
            pl[w * 32 + nt * 16 + qt * 4 + r][ot4 * 16 + q] = acc[nt][oh * 4 + ot4][r];
      __syncthreads();
      const int wp = tid & 31;
      #pragma unroll
      for (int it = 0; it < 8; ++it) {
        int cc2 = (tid >> 5) + it * 8;
        float v = fmaxf(fmaxf(pl[2 * wp][cc2], pl[2 * wp + 1][cc2]),
                        fmaxf(pl[64 + 2 * wp][cc2], pl[65 + 2 * wp][cc2])) + bh_[oc0 + oh * 64 + cc2];
        vp[((size_t)(b * 256) + oc0 + oh * 64 + cc2) * 1024 + hp * 32 + wp] = f2bf(v);
      }
    }
  }
}

// ---------- fused attention: QB=32, online softmax over 2 m-chunks of 512 ----------

#define PROW 520

__global__ __launch_bounds__(256, 3)
void attn_mfma(const unsigned short* __restrict__ fhi, const unsigned short* __restrict__ flo,
               const unsigned short* __restrict__ ghi, const unsigned short* __restrict__ glo,
               const unsigned short* __restrict__ vp, unsigned short* __restrict__ oT)
{
  __shared__ unsigned short P[32 * PROW];          // 33,280 B
  __shared__ float redm[4][32], reds[4][32];
  __shared__ float rfrow[32], Srow[32];
  const int b = blockIdx.y, n0 = blockIdx.x * 32;
  const int tid = threadIdx.x, w = tid >> 6, lane = tid & 63;
  const int q32 = lane & 31, hl = lane >> 5;
  const int q16 = lane & 15, qt = lane >> 4;

  bf16x8 Fh[4], Fl[4];
  {
    size_t fb = ((size_t)b * 4096 + n0 + q32) * 64 + hl * 8;
    #pragma unroll
    for (int s = 0; s < 4; ++s) {
      Fh[s] = *(const bf16x8*)(fhi + fb + s * 16);
      Fl[s] = *(const bf16x8*)(flo + fb + s * 16);
    }
  }

  float M = -3.0e38f;
  f32x4 oacc[4][2];
  #pragma unroll
  for (int c4 = 0; c4 < 4; ++c4) {
    oacc[c4][0] = (f32x4){0.f, 0.f, 0.f, 0.f};
    oacc[c4][1] = (f32x4){0.f, 0.f, 0.f, 0.f};
  }

  #pragma unroll
  for (int mc = 0; mc < 2; ++mc) {
    f32x16 sa[4] = {};
    const size_t g0 = ((size_t)b * 1024 + mc * 512 + w * 128 + q32) * 64 + hl * 8;
    #pragma unroll
    for (int t = 0; t < 4; ++t) {
      size_t gb = g0 + (size_t)t * 32 * 64;
      bf16x8 Gh[4], Gl[4];
      #pragma unroll
      for (int s = 0; s < 4; ++s) {
        Gh[s] = *(const bf16x8*)(ghi + gb + s * 16);
        Gl[s] = *(const bf16x8*)(glo + gb + s * 16);
      }
      #pragma unroll
      for (int s = 0; s < 4; ++s) {
        sa[t] = MFMA32(Gh[s], Fh[s], sa[t]);
        sa[t] = MFMA32(Gh[s], Fl[s], sa[t]);
        sa[t] = MFMA32(Gl[s], Fh[s], sa[t]);
      }
    }

    float mx = -3.0e38f;
    #pragma unroll
    for (int t = 0; t < 4; ++t)
      #pragma unroll
      for (int r = 0; r < 16; ++r) mx = fmaxf(mx, sa[t][r]);
    mx = fmaxf(mx, __shfl_xor(mx, 32));
    if (lane < 32) redm[w][lane] = mx;
    __syncthreads();
    float gmx = fmaxf(fmaxf(redm[0][q32], redm[1][q32]), fmaxf(redm[2][q32], redm[3][q32]));
    float Mnew = fmaxf(M, gmx);
    float rf = __expf(M - Mnew);
    M = Mnew;
    float csum = 0.f;
    #pragma unroll
    for (int t = 0; t < 4; ++t)
      #pragma unroll
      for (int r = 0; r < 16; ++r) {
        float p = __expf(sa[t][r] - Mnew);
        sa[t][r] = p;
        csum += p;
      }
    csum += __shfl_xor(csum, 32);
    if (lane < 32) reds[w][lane] = csum;

    #pragma unroll
    for (int t = 0; t < 4; ++t)
      #pragma unroll
      for (int j = 0; j < 4; ++j) {
        uint2 pk;
        pk.x = (unsigned)f2bf(sa[t][4 * j + 0]) | ((unsigned)f2bf(sa[t][4 * j + 1]) << 16);
        pk.y = (unsigned)f2bf(sa[t][4 * j + 2]) | ((unsigned)f2bf(sa[t][4 * j + 3]) << 16);
        *(uint2*)&P[q32 * PROW + w * 128 + t * 32 + j * 8 + hl * 4] = pk;
      }
    __syncthreads();
    float ct = reds[0][q32] + reds[1][q32] + reds[2][q32] + reds[3][q32];
    if (w == 0 && lane < 32) {
      Srow[lane] = (mc == 0) ? ct : Srow[lane] * rf + ct;
      rfrow[lane] = rf;
    }
    __syncthreads();

    if (mc == 1) {
      float rf0 = rfrow[q16], rf1 = rfrow[16 + q16];
      #pragma unroll
      for (int c4 = 0; c4 < 4; ++c4) {
        oacc[c4][0] *= rf0;
        oacc[c4][1] *= rf1;
      }
    }
    const size_t v0 = ((size_t)b * 256 + w * 64 + q16) * 1024 + mc * 512 + qt * 8;
    bf16x8 va0, va1, va2, va3, vb0, vb1, vb2, vb3;

#define LOADVA(KS) { size_t vb_ = v0 + (size_t)(KS) * 32; \
  va0 = *(const bf16x8*)(vp + vb_);         va1 = *(const bf16x8*)(vp + vb_ + 16384); \
  va2 = *(const bf16x8*)(vp + vb_ + 32768); va3 = *(const bf16x8*)(vp + vb_ + 49152); }
#define LOADVB(KS) { size_t vb_ = v0 + (size_t)(KS) * 32; \
  vb0 = *(const bf16x8*)(vp + vb_);         vb1 = *(const bf16x8*)(vp + vb_ + 16384); \
  vb2 = *(const bf16x8*)(vp + vb_ + 32768); vb3 = *(const bf16x8*)(vp + vb_ + 49152); }
#define PVMFMA(KS, V0, V1, V2, V3) { \
  bf16x8 pb0 = *(const bf16x8*)(&P[q16 * PROW + (KS) * 32 + qt * 8]); \
  bf16x8 pb1 = *(const bf16x8*)(&P[(16 + q16) * PROW + (KS) * 32 + qt * 8]); \
  oacc[0][0] = MFMA16(V0, pb0, oacc[0][0]); oacc[1][0] = MFMA16(V1, pb0, oacc[1][0]); \
  oacc[2][0] = MFMA16(V2, pb0, oacc[2][0]); oacc[3][0] = MFMA16(V3, pb0, oacc[3][0]); \
  oacc[0][1] = MFMA16(V0, pb1, oacc[0][1]); oacc[1][1] = MFMA16(V1, pb1, oacc[1][1]); \
  oacc[2][1] = MFMA16(V2, pb1, oacc[2][1]); oacc[3][1] = MFMA16(V3, pb1, oacc[3][1]); }

    LOADVA(0)
    LOADVB(1)
    #pragma unroll
    for (int kp = 0; kp < 8; ++kp) {
      PVMFMA(2 * kp, va0, va1, va2, va3)
      if (2 * kp + 2 < 16) LOADVA(2 * kp + 2)
      PVMFMA(2 * kp + 1, vb0, vb1, vb2, vb3)
      if (2 * kp + 3 < 16) LOADVB(2 * kp + 3)
    }
  }

  const float rinv0 = 1.0f / Srow[q16];
  const float rinv1 = 1.0f / Srow[16 + q16];
  #pragma unroll
  for (int c4 = 0; c4 < 4; ++c4) {
    uint2 pk0, pk1;
    pk0.x = (unsigned)f2bf(oacc[c4][0][0] * rinv0) | ((unsigned)f2bf(oacc[c4][0][1] * rinv0) << 16);
    pk0.y = (unsigned)f2bf(oacc[c4][0][2] * rinv0) | ((unsigned)f2bf(oacc[c4][0][3] * rinv0) << 16);
    pk1.x = (unsigned)f2bf(oacc[c4][1][0] * rinv1) | ((unsigned)f2bf(oacc[c4][1][1] * rinv1) << 16);
    pk1.y = (unsigned)f2bf(oacc[c4][1][2] * rinv1) | ((unsigned)f2bf(oacc[c4][1][3] * rinv1) << 16);
    *(uint2*)(oT + ((size_t)b * 4096 + n0 + q16) * 256 + w * 64 + c4 * 16 + qt * 4) = pk0;
    *(uint2*)(oT + ((size_t)b * 4096 + n0 + 16 + q16) * 256 + w * 64 + c4 * 16 + qt * 4) = pk1;
  }
}

// ---------- final conv: 128n x 128oc, direct-fragment store, out = gamma*(oT.Wv + bv) + x ----------

__global__ __launch_bounds__(256)
void conv_final(const unsigned short* __restrict__ A, const unsigned short* __restrict__ W,
                const float* __restrict__ bias, float* __restrict__ out,
                const float* __restrict__ resid, const float* __restrict__ gamma_p)
{
  const int b = blockIdx.z, oc0 = blockIdx.y * 128, n0 = blockIdx.x * 128;
  const int tid = threadIdx.x, w = tid >> 6, lane = tid & 63, q = lane & 15, qt = lane >> 4;

  f32x4 acc[2][8];
  #pragma unroll
  for (int nt = 0; nt < 2; ++nt)
    #pragma unroll
    for (int ot = 0; ot < 8; ++ot) acc[nt][ot] = (f32x4){0.f, 0.f, 0.f, 0.f};

  const size_t a0 = ((size_t)b * 4096 + n0 + w * 32 + q) * 256 + qt * 8;
  #pragma unroll
  for (int ks = 0; ks < 8; ++ks) {
    bf16x8 A_[2], B_[8];
    #pragma unroll
    for (int nt = 0; nt < 2; ++nt)
      A_[nt] = *(const bf16x8*)(A + a0 + nt * 16 * 256 + ks * 32);
    #pragma unroll
    for (int ot = 0; ot < 8; ++ot)
      B_[ot] = *(const bf16x8*)(W + (size_t)(oc0 + ot * 16 + q) * 256 + ks * 32 + qt * 8);
    #pragma unroll
    for (int nt = 0; nt < 2; ++nt)
      #pragma unroll
      for (int ot = 0; ot < 8; ++ot)
        acc[nt][ot] = MFMA16(A_[nt], B_[ot], acc[nt][ot]);
  }

  const float gm = gamma_p[0];
  #pragma unroll
  for (int ot = 0; ot < 8; ++ot) {
    int oc = oc0 + ot * 16 + q;
    float bs = bias[oc];
    #pragma unroll
    for (int nt = 0; nt < 2; ++nt) {
      int n = n0 + w * 32 + nt * 16 + qt * 4;
      size_t o = ((size_t)(b * 512) + oc) * 4096 + n;
      float4 rs = *(const float4*)&resid[o];
      float4 ov;
      ov.x = gm * (acc[nt][ot][0] + bs) + rs.x;
      ov.y = gm * (acc[nt][ot][1] + bs) + rs.y;
      ov.z = gm * (acc[nt][ot][2] + bs) + rs.z;
      ov.w = gm * (acc[nt][ot][3] + bs) + rs.w;
      *(float4*)&out[o] = ov;
    }
  }
}

// ---------- launch ----------

extern "C" void kernel_launch(void* const* d_in, const int* in_sizes, int n_in,
                              void* d_out, int out_size, void* d_ws, size_t ws_size,
                              hipStream_t stream) {
  const float* x     = (const float*)d_in[0];
  const float* Wf    = (const float*)d_in[1];
  const float* bf    = (const float*)d_in[2];
  const float* Wg    = (const float*)d_in[3];
  const float* bg    = (const float*)d_in[4];
  const float* Wh    = (const float*)d_in[5];
  const float* bh    = (const float*)d_in[6];
  const float* Wv    = (const float*)d_in[7];
  const float* bv    = (const float*)d_in[8];
  const float* gamma = (const float*)d_in[9];
  float* out = (float*)d_out;
  char* w = (char*)d_ws;

  unsigned short* fhi = (unsigned short*)(w);                 // 4 MB  [8][4096][64]
  unsigned short* flo = (unsigned short*)(w + 4194304);       // 4 MB
  unsigned short* ghi = (unsigned short*)(w + 8388608);       // 1 MB  [8][1024][64]
  unsigned short* glo = (unsigned short*)(w + 9437184);       // 1 MB
  unsigned short* vp  = (unsigned short*)(w + 10485760);      // 4 MB  [8][256][1024]
  unsigned short* oT  = (unsigned short*)(w + 14680064);      // 16 MB [8][4096][256]
  unsigned short* wfh = (unsigned short*)(w + 31457280);      // 64 KB [64][512]
  unsigned short* wfl = (unsigned short*)(w + 31522816);
  unsigned short* wgh = (unsigned short*)(w + 31588352);
  unsigned short* wgl = (unsigned short*)(w + 31653888);
  unsigned short* whb = (unsigned short*)(w + 31719424);      // 256 KB [256][512]
  unsigned short* wvb = (unsigned short*)(w + 31981568);      // 256 KB [512][256]

  prep_k<<<1280, 256, 0, stream>>>(Wf, Wg, Wh, Wv, wfh, wfl, wgh, wgl, whb, wvb);

  conv_fgv<<<dim3(32, 3, 8), 256, 0, stream>>>(x, wfh, wfl, wgh, wgl, whb,
                                               bf, bg, bh, fhi, flo, ghi, glo, vp);

  attn_mfma<<<dim3(128, 8), 256, 0, stream>>>(fhi, flo, ghi, glo, vp, oT);

  conv_final<<<dim3(32, 4, 8), 256, 0, stream>>>(oT, wvb, bv, out, x, gamma);
}

// Round 7
// 186.338 us; speedup vs baseline: 1.5535x; 1.3699x over previous
//
#include <hip/hip_runtime.h>
#include <cstddef>

typedef __attribute__((ext_vector_type(4))) float f32x4;
typedef __attribute__((ext_vector_type(16))) float f32x16;
typedef __attribute__((ext_vector_type(8))) short bf16x8;

#define MFMA16(A, B, C) __builtin_amdgcn_mfma_f32_16x16x32_bf16(A, B, C, 0, 0, 0)
#define MFMA32(A, B, C) __builtin_amdgcn_mfma_f32_32x32x16_bf16(A, B, C, 0, 0, 0)

__device__ __forceinline__ unsigned short f2bf(float f) {
  unsigned u = __float_as_uint(f);
  u += 0x7fffu + ((u >> 16) & 1u);
  return (unsigned short)(u >> 16);
}
__device__ __forceinline__ float bf2f(unsigned short s) {
  return __uint_as_float(((unsigned)s) << 16);
}

__device__ __forceinline__ void cvt_split8(float4 a, float4 b, bf16x8* H, bf16x8* L) {
  float v[8] = {a.x, a.y, a.z, a.w, b.x, b.y, b.z, b.w};
  unsigned hh[4], ll[4];
  #pragma unroll
  for (int p = 0; p < 4; ++p) {
    unsigned short h0 = f2bf(v[2 * p]), h1 = f2bf(v[2 * p + 1]);
    hh[p] = (unsigned)h0 | ((unsigned)h1 << 16);
    unsigned short l0 = f2bf(v[2 * p] - bf2f(h0));
    unsigned short l1 = f2bf(v[2 * p + 1] - bf2f(h1));
    ll[p] = (unsigned)l0 | ((unsigned)l1 << 16);
  }
  uint4 uh; uh.x = hh[0]; uh.y = hh[1]; uh.z = hh[2]; uh.w = hh[3];
  uint4 ul; ul.x = ll[0]; ul.y = ll[1]; ul.z = ll[2]; ul.w = ll[3];
  *H = *(bf16x8*)&uh;
  *L = *(bf16x8*)&ul;
}

__device__ __forceinline__ bf16x8 cvt_hi8(float4 a, float4 b) {
  float v[8] = {a.x, a.y, a.z, a.w, b.x, b.y, b.z, b.w};
  unsigned hh[4];
  #pragma unroll
  for (int p = 0; p < 4; ++p)
    hh[p] = (unsigned)f2bf(v[2 * p]) | ((unsigned)f2bf(v[2 * p + 1]) << 16);
  uint4 uh; uh.x = hh[0]; uh.y = hh[1]; uh.z = hh[2]; uh.w = hh[3];
  return *(bf16x8*)&uh;
}

// ---------- weight prep: write all weights in fragment-major (FM) order ----------
// FM for a B-operand [OC][K]: fragment (oct, kt) = 64 slots (qt*16+q) x 8 elems j,
// elem = W[(oct*16+q)][kt*32+qt*8+j].  Linear idx i: j=i&7, slot=(i>>3)&63,
// kt=(i>>9)&(NKT-1), oct=i>>(9+log2 NKT).

__global__ void prep_k(const float* __restrict__ Wf, const float* __restrict__ Wg,
                       const float* __restrict__ Wh, const float* __restrict__ Wv,
                       unsigned short* __restrict__ wfh, unsigned short* __restrict__ wfl,
                       unsigned short* __restrict__ wgh, unsigned short* __restrict__ wgl,
                       unsigned short* __restrict__ whb, unsigned short* __restrict__ wvb) {
  int i = blockIdx.x * 256 + threadIdx.x;
  if (i < 65536) {  // wf (K=512, OC=64, NKT=16) then wg
    int ii = i & 32767;
    int j = ii & 7, slot = (ii >> 3) & 63, q = slot & 15, qt2 = slot >> 4;
    int kt = (ii >> 9) & 15, oct = ii >> 13;
    const float* src = (i < 32768) ? Wf : Wg;
    unsigned short* dh = (i < 32768) ? wfh : wgh;
    unsigned short* dl = (i < 32768) ? wfl : wgl;
    float v = src[(oct * 16 + q) * 512 + kt * 32 + qt2 * 8 + j];
    unsigned short h = f2bf(v);
    dh[ii] = h; dl[ii] = f2bf(v - bf2f(h));
  } else if (i < 196608) {  // wh: K=512, OC=256, NKT=16
    int ii = i - 65536;
    int j = ii & 7, slot = (ii >> 3) & 63, q = slot & 15, qt2 = slot >> 4;
    int kt = (ii >> 9) & 15, oct = ii >> 13;
    whb[ii] = f2bf(Wh[(oct * 16 + q) * 512 + kt * 32 + qt2 * 8 + j]);
  } else if (i < 327680) {  // wv: K=256, OC=512, NKT=8
    int ii = i - 196608;
    int j = ii & 7, slot = (ii >> 3) & 63, q = slot & 15, qt2 = slot >> 4;
    int kt = (ii >> 9) & 7, oct = ii >> 12;
    wvb[ii] = f2bf(Wv[(oct * 16 + q) * 256 + kt * 32 + qt2 * 8 + j]);
  }
}

// ---------- conv_all: 4 balanced roles (0=f, 1=g, 2/3=v-halves) ----------
// Unified fp32 LDS staging [128 n][33 k] dbuf (bank-uniform), split/cast in regs.
// Outputs written fragment-major for their consumers.

#define LOADX(CN) { _Pragma("unroll") \
  for (int t_ = 0; t_ < 16; ++t_) vv[t_] = xbase[(size_t)((CN) * 32 + kq + t_) * 4096]; }
#define STOREX(XS) { _Pragma("unroll") \
  for (int i_ = 0; i_ < 4; ++i_) { \
    float4 wv_; wv_.x = vv[4*i_]; wv_.y = vv[4*i_+1]; wv_.z = vv[4*i_+2]; wv_.w = vv[4*i_+3]; \
    *(float4*)&(XS)[nloc][kq + 4 * i_] = wv_; } }

__global__ __launch_bounds__(256)
void conv_all(const float* __restrict__ x,
              const unsigned short* __restrict__ wfh_, const unsigned short* __restrict__ wfl_,
              const unsigned short* __restrict__ wgh_, const unsigned short* __restrict__ wgl_,
              const unsigned short* __restrict__ whb_,
              const float* __restrict__ bf_, const float* __restrict__ bg_,
              const float* __restrict__ bh_,
              unsigned short* __restrict__ fhi, unsigned short* __restrict__ flo,
              unsigned short* __restrict__ ghi, unsigned short* __restrict__ glo,
              unsigned short* __restrict__ vp)
{
  __shared__ __align__(16) char smem[34304];
  float (*xsA)[33] = (float(*)[33])smem;
  float (*xsB)[33] = (float(*)[33])(smem + 16896);
  const int role = blockIdx.y;
  const int b = blockIdx.z, hp = blockIdx.x, n0 = hp * 128;
  const int tid = threadIdx.x, w = tid >> 6, lane = tid & 63, q = lane & 15, qt = lane >> 4;
  const int nloc = tid & 127;
  const int kq = (tid >> 7) * 16;
  const float* xbase = x + (size_t)(b * 512) * 4096 + n0 + nloc;
  float vv[16];

  if (role < 2) {
    // ---- f or g: split hi/lo MFMA, 64 oc ----
    const unsigned short* WH = (role == 0) ? wfh_ : wgh_;
    const unsigned short* WL = (role == 0) ? wfl_ : wgl_;
    f32x4 acc[2][4];
    #pragma unroll
    for (int nt = 0; nt < 2; ++nt)
      #pragma unroll
      for (int ot = 0; ot < 4; ++ot) acc[nt][ot] = (f32x4){0.f, 0.f, 0.f, 0.f};
    LOADX(0) STOREX(xsA)
    __syncthreads();
    for (int cc = 0; cc < 16; ++cc) {
      float (*cur)[33] = (cc & 1) ? xsB : xsA;
      float (*nxt)[33] = (cc & 1) ? xsA : xsB;
      if (cc < 15) LOADX(cc + 1)
      bf16x8 Ah[2], Al[2];
      #pragma unroll
      for (int nt = 0; nt < 2; ++nt) {
        int row = w * 32 + nt * 16 + q;
        float4 a0 = *(const float4*)&cur[row][qt * 8];
        float4 a1 = *(const float4*)&cur[row][qt * 8 + 4];
        cvt_split8(a0, a1, &Ah[nt], &Al[nt]);
      }
      bf16x8 Bh[4], Bl[4];
      #pragma unroll
      for (int ot = 0; ot < 4; ++ot) {
        size_t wb = ((size_t)(ot * 16 + cc) << 9) + lane * 8;
        Bh[ot] = *(const bf16x8*)(WH + wb);
        Bl[ot] = *(const bf16x8*)(WL + wb);
      }
      #pragma unroll
      for (int nt = 0; nt < 2; ++nt)
        #pragma unroll
        for (int ot = 0; ot < 4; ++ot) {
          acc[nt][ot] = MFMA16(Ah[nt], Bh[ot], acc[nt][ot]);
          acc[nt][ot] = MFMA16(Ah[nt], Bl[ot], acc[nt][ot]);
          acc[nt][ot] = MFMA16(Al[nt], Bh[ot], acc[nt][ot]);
        }
      if (cc < 15) STOREX(nxt)
      __syncthreads();
    }
    if (role == 0) {
      // f epilogue: FM for attn's MFMA32-B: frag (nt32 = hp*4+w, s=ot),
      // slot = (q>>3)*32 + (n&31), j = q&7
      #pragma unroll
      for (int nt = 0; nt < 2; ++nt)
        #pragma unroll
        for (int ot = 0; ot < 4; ++ot)
          #pragma unroll
          for (int r = 0; r < 4; ++r) {
            float v = acc[nt][ot][r] + bf_[ot * 16 + q];
            unsigned short h = f2bf(v);
            size_t o = (((size_t)(b * 128 + hp * 4 + w) * 4 + ot) * 64 +
                        (q >> 3) * 32 + nt * 16 + qt * 4 + r) * 8 + (q & 7);
            fhi[o] = h;
            flo[o] = f2bf(v - bf2f(h));
          }
    } else {
      // g epilogue: 2x2 pool via LDS, then FM for attn's MFMA32-A:
      // frag (mt = hp, s = c>>4), slot = ((c>>3)&1)*32 + wp, j = c&7
      float (*pl)[67] = (float(*)[67])smem;
      #pragma unroll
      for (int nt = 0; nt < 2; ++nt)
        #pragma unroll
        for (int ot = 0; ot < 4; ++ot)
          #pragma unroll
          for (int r = 0; r < 4; ++r)
            pl[w * 32 + nt * 16 + qt * 4 + r][ot * 16 + q] = acc[nt][ot][r];
      __syncthreads();
      const int c = tid & 63;
      #pragma unroll
      for (int it = 0; it < 8; ++it) {
        int wp = (tid >> 6) + it * 4;
        float v = fmaxf(fmaxf(pl[2 * wp][c], pl[2 * wp + 1][c]),
                        fmaxf(pl[64 + 2 * wp][c], pl[65 + 2 * wp][c])) + bg_[c];
        unsigned short h = f2bf(v);
        size_t o = (((size_t)(b * 32 + hp) * 4 + (c >> 4)) * 64 +
                    ((c >> 3) & 1) * 32 + wp) * 8 + (c & 7);
        ghi[o] = h;
        glo[o] = f2bf(v - bf2f(h));
      }
    }
  } else {
    // ---- v half: hi-only MFMA, 128 oc ----
    const int oct0 = (role - 2) * 8;
    f32x4 acc[2][8];
    #pragma unroll
    for (int nt = 0; nt < 2; ++nt)
      #pragma unroll
      for (int ot = 0; ot < 8; ++ot) acc[nt][ot] = (f32x4){0.f, 0.f, 0.f, 0.f};
    LOADX(0) STOREX(xsA)
    __syncthreads();
    for (int cc = 0; cc < 16; ++cc) {
      float (*cur)[33] = (cc & 1) ? xsB : xsA;
      float (*nxt)[33] = (cc & 1) ? xsA : xsB;
      if (cc < 15) LOADX(cc + 1)
      bf16x8 A_[2], B_[8];
      #pragma unroll
      for (int nt = 0; nt < 2; ++nt) {
        int row = w * 32 + nt * 16 + q;
        float4 a0 = *(const float4*)&cur[row][qt * 8];
        float4 a1 = *(const float4*)&cur[row][qt * 8 + 4];
        A_[nt] = cvt_hi8(a0, a1);
      }
      #pragma unroll
      for (int ot = 0; ot < 8; ++ot)
        B_[ot] = *(const bf16x8*)(whb_ + ((size_t)((oct0 + ot) * 16 + cc) << 9) + lane * 8);
      #pragma unroll
      for (int nt = 0; nt < 2; ++nt)
        #pragma unroll
        for (int ot = 0; ot < 8; ++ot)
          acc[nt][ot] = MFMA16(A_[nt], B_[ot], acc[nt][ot]);
      if (cc < 15) STOREX(nxt)
      __syncthreads();
    }
    // pool epilogue -> FM for attn PV's MFMA16-A:
    // frag (cvt = cv>>4, ks = hp), slot = (wp>>3)*16 + (cv&15), j = wp&7
    float (*pl)[67] = (float(*)[67])smem;
    #pragma unroll
    for (int oh = 0; oh < 2; ++oh) {
      if (oh) __syncthreads();
      #pragma unroll
      for (int nt = 0; nt < 2; ++nt)
        #pragma unroll
        for (int ot4 = 0; ot4 < 4; ++ot4)
          #pragma unroll
          for (int r = 0; r < 4; ++r)
            pl[w * 32 + nt * 16 + qt * 4 + r][ot4 * 16 + q] = acc[nt][oh * 4 + ot4][r];
      __syncthreads();
      const int wp = tid & 31;
      #pragma unroll
      for (int it = 0; it < 8; ++it) {
        int cc2 = (tid >> 5) + it * 8;
        int cv = (role - 2) * 128 + oh * 64 + cc2;
        float v = fmaxf(fmaxf(pl[2 * wp][cc2], pl[2 * wp + 1][cc2]),
                        fmaxf(pl[64 + 2 * wp][cc2], pl[65 + 2 * wp][cc2])) + bh_[cv];
        size_t o = (((size_t)(b * 16 + (cv >> 4)) * 32 + hp) * 64 +
                    (wp >> 3) * 16 + (cv & 15)) * 8 + (wp & 7);
        vp[o] = f2bf(v);
      }
    }
  }
}

// ---------- fused attention: QB=32, online softmax over 4 m-chunks of 256 ----------
// All global operands fragment-major -> every wave load is one contiguous 1 KB.

#define PROW 264

__global__ __launch_bounds__(256, 5)
void attn_mfma(const unsigned short* __restrict__ f_, const unsigned short* __restrict__ fl_,
               const unsigned short* __restrict__ g_, const unsigned short* __restrict__ gl_,
               const unsigned short* __restrict__ vp, unsigned short* __restrict__ oT)
{
  __shared__ __align__(16) unsigned short P[32 * PROW];   // 16,896 B
  __shared__ float redm[4][32], reds[4][32];
  __shared__ float rfrow[32], Srow[32];
  const int b = blockIdx.y, bx = blockIdx.x;
  const int tid = threadIdx.x, w = tid >> 6, lane = tid & 63;
  const int q32 = lane & 31;
  const int q16 = lane & 15, qt = lane >> 4;

  bf16x8 Fh[4], Fl[4];
  {
    size_t fb = ((size_t)(b * 128 + bx) << 11) + lane * 8;
    #pragma unroll
    for (int s = 0; s < 4; ++s) {
      Fh[s] = *(const bf16x8*)(f_ + fb + (s << 9));
      Fl[s] = *(const bf16x8*)(fl_ + fb + (s << 9));
    }
  }

  float M = -3.0e38f;
  f32x4 oacc[4][2];
  #pragma unroll
  for (int c4 = 0; c4 < 4; ++c4) {
    oacc[c4][0] = (f32x4){0.f, 0.f, 0.f, 0.f};
    oacc[c4][1] = (f32x4){0.f, 0.f, 0.f, 0.f};
  }
  const size_t vroot = ((size_t)(b * 16 + w * 4) * 32) * 512 + lane * 8;

  #pragma unroll 1
  for (int mc = 0; mc < 4; ++mc) {
    // ---- s phase: wave owns 64 m (2 tiles of 32) ----
    f32x16 sa[2] = {};
    #pragma unroll
    for (int t = 0; t < 2; ++t) {
      size_t gb = ((size_t)(b * 32 + mc * 8 + w * 2 + t) << 11) + lane * 8;
      bf16x8 Gh[4], Gl[4];
      #pragma unroll
      for (int s = 0; s < 4; ++s) {
        Gh[s] = *(const bf16x8*)(g_ + gb + (s << 9));
        Gl[s] = *(const bf16x8*)(gl_ + gb + (s << 9));
      }
      #pragma unroll
      for (int s = 0; s < 4; ++s) {
        sa[t] = MFMA32(Gh[s], Fh[s], sa[t]);
        sa[t] = MFMA32(Gh[s], Fl[s], sa[t]);
        sa[t] = MFMA32(Gl[s], Fh[s], sa[t]);
      }
    }

    // ---- online softmax ----
    float mx = -3.0e38f;
    #pragma unroll
    for (int t = 0; t < 2; ++t)
      #pragma unroll
      for (int r = 0; r < 16; ++r) mx = fmaxf(mx, sa[t][r]);
    mx = fmaxf(mx, __shfl_xor(mx, 32));
    if (lane < 32) redm[w][lane] = mx;
    __syncthreads();
    float gmx = fmaxf(fmaxf(redm[0][q32], redm[1][q32]), fmaxf(redm[2][q32], redm[3][q32]));
    float Mnew = fmaxf(M, gmx);
    float rf = __expf(M - Mnew);
    M = Mnew;
    float csum = 0.f;
    #pragma unroll
    for (int t = 0; t < 2; ++t)
      #pragma unroll
      for (int r = 0; r < 16; ++r) {
        float p = __expf(sa[t][r] - Mnew);
        sa[t][r] = p;
        csum += p;
      }
    csum += __shfl_xor(csum, 32);
    if (lane < 32) reds[w][lane] = csum;

    // P write: col q32, rows m_local = w*64 + t*32 + j*8 + (lane>>5)*4 + i
    #pragma unroll
    for (int t = 0; t < 2; ++t)
      #pragma unroll
      for (int j = 0; j < 4; ++j) {
        uint2 pk;
        pk.x = (unsigned)f2bf(sa[t][4 * j + 0]) | ((unsigned)f2bf(sa[t][4 * j + 1]) << 16);
        pk.y = (unsigned)f2bf(sa[t][4 * j + 2]) | ((unsigned)f2bf(sa[t][4 * j + 3]) << 16);
        *(uint2*)&P[q32 * PROW + w * 64 + t * 32 + j * 8 + (lane >> 5) * 4] = pk;
      }
    __syncthreads();
    float ct_ = reds[0][q32] + reds[1][q32] + reds[2][q32] + reds[3][q32];
    if (w == 0 && lane < 32) {
      Srow[lane] = (mc == 0) ? ct_ : Srow[lane] * rf + ct_;
      rfrow[lane] = rf;
    }
    __syncthreads();

    // ---- PV over this chunk ----
    if (mc > 0) {
      float rf0 = rfrow[q16], rf1 = rfrow[16 + q16];
      #pragma unroll
      for (int c4 = 0; c4 < 4; ++c4) {
        oacc[c4][0] *= rf0;
        oacc[c4][1] *= rf1;
      }
    }
    bf16x8 va0, va1, va2, va3, vb0, vb1, vb2, vb3;

#define VLD(C4, KS) (*(const bf16x8*)(vp + vroot + ((size_t)((C4) * 32 + mc * 8 + (KS)) << 9)))
#define LOADVA(KS) { va0 = VLD(0, KS); va1 = VLD(1, KS); va2 = VLD(2, KS); va3 = VLD(3, KS); }
#define LOADVB(KS) { vb0 = VLD(0, KS); vb1 = VLD(1, KS); vb2 = VLD(2, KS); vb3 = VLD(3, KS); }
#define PVMFMA(KS, V0, V1, V2, V3) { \
  bf16x8 pb0 = *(const bf16x8*)&P[q16 * PROW + (KS) * 32 + qt * 8]; \
  bf16x8 pb1 = *(const bf16x8*)&P[(16 + q16) * PROW + (KS) * 32 + qt * 8]; \
  oacc[0][0] = MFMA16(V0, pb0, oacc[0][0]); oacc[1][0] = MFMA16(V1, pb0, oacc[1][0]); \
  oacc[2][0] = MFMA16(V2, pb0, oacc[2][0]); oacc[3][0] = MFMA16(V3, pb0, oacc[3][0]); \
  oacc[0][1] = MFMA16(V0, pb1, oacc[0][1]); oacc[1][1] = MFMA16(V1, pb1, oacc[1][1]); \
  oacc[2][1] = MFMA16(V2, pb1, oacc[2][1]); oacc[3][1] = MFMA16(V3, pb1, oacc[3][1]); }

    LOADVA(0)
    LOADVB(1)
    #pragma unroll
    for (int kp = 0; kp < 4; ++kp) {
      PVMFMA(2 * kp, va0, va1, va2, va3)
      if (2 * kp + 2 < 8) LOADVA(2 * kp + 2)
      PVMFMA(2 * kp + 1, vb0, vb1, vb2, vb3)
      if (2 * kp + 3 < 8) LOADVB(2 * kp + 3)
    }
  }

  // ---- epilogue: oT fragment-major for conv_final's MFMA16-A ----
  const float rinv0 = 1.0f / Srow[q16];
  const float rinv1 = 1.0f / Srow[16 + q16];
  #pragma unroll
  for (int c4 = 0; c4 < 4; ++c4) {
    int ct = w * 4 + c4;
    int kt = ct >> 1;
    int qtp = (ct & 1) * 2 + (qt >> 1);
    int jo = (qt & 1) * 4;
    uint2 pk0, pk1;
    pk0.x = (unsigned)f2bf(oacc[c4][0][0] * rinv0) | ((unsigned)f2bf(oacc[c4][0][1] * rinv0) << 16);
    pk0.y = (unsigned)f2bf(oacc[c4][0][2] * rinv0) | ((unsigned)f2bf(oacc[c4][0][3] * rinv0) << 16);
    pk1.x = (unsigned)f2bf(oacc[c4][1][0] * rinv1) | ((unsigned)f2bf(oacc[c4][1][1] * rinv1) << 16);
    pk1.y = (unsigned)f2bf(oacc[c4][1][2] * rinv1) | ((unsigned)f2bf(oacc[c4][1][3] * rinv1) << 16);
    size_t o0 = (((size_t)(b * 256 + bx * 2) * 8 + kt) * 64 + qtp * 16 + q16) * 8 + jo;
    *(uint2*)(oT + o0) = pk0;
    *(uint2*)(oT + o0 + 4096) = pk1;
  }
}

// ---------- final conv: FM A (oT) and FM W, out = gamma*(oT.Wv + bv) + x ----------

__global__ __launch_bounds__(256)
void conv_final(const unsigned short* __restrict__ A, const unsigned short* __restrict__ W,
                const float* __restrict__ bias, float* __restrict__ out,
                const float* __restrict__ resid, const float* __restrict__ gamma_p)
{
  const int b = blockIdx.z, oc0 = blockIdx.y * 128, n0 = blockIdx.x * 128;
  const int tid = threadIdx.x, w = tid >> 6, lane = tid & 63, q = lane & 15, qt = lane >> 4;

  f32x4 acc[2][8];
  #pragma unroll
  for (int nt = 0; nt < 2; ++nt)
    #pragma unroll
    for (int ot = 0; ot < 8; ++ot) acc[nt][ot] = (f32x4){0.f, 0.f, 0.f, 0.f};

  #pragma unroll
  for (int ks = 0; ks < 8; ++ks) {
    bf16x8 A_[2], B_[8];
    #pragma unroll
    for (int nt = 0; nt < 2; ++nt)
      A_[nt] = *(const bf16x8*)(A + (((size_t)(b * 256 + (n0 >> 4) + w * 2 + nt) * 8 + ks) << 9) + lane * 8);
    #pragma unroll
    for (int ot = 0; ot < 8; ++ot)
      B_[ot] = *(const bf16x8*)(W + (((size_t)((oc0 >> 4) + ot) * 8 + ks) << 9) + lane * 8);
    #pragma unroll
    for (int nt = 0; nt < 2; ++nt)
      #pragma unroll
      for (int ot = 0; ot < 8; ++ot)
        acc[nt][ot] = MFMA16(A_[nt], B_[ot], acc[nt][ot]);
  }

  const float gm = gamma_p[0];
  #pragma unroll
  for (int ot = 0; ot < 8; ++ot) {
    int oc = oc0 + ot * 16 + q;
    float bs = bias[oc];
    #pragma unroll
    for (int nt = 0; nt < 2; ++nt) {
      int n = n0 + w * 32 + nt * 16 + qt * 4;
      size_t o = ((size_t)(b * 512) + oc) * 4096 + n;
      float4 rs = *(const float4*)&resid[o];
      float4 ov;
      ov.x = gm * (acc[nt][ot][0] + bs) + rs.x;
      ov.y = gm * (acc[nt][ot][1] + bs) + rs.y;
      ov.z = gm * (acc[nt][ot][2] + bs) + rs.z;
      ov.w = gm * (acc[nt][ot][3] + bs) + rs.w;
      *(float4*)&out[o] = ov;
    }
  }
}

// ---------- launch ----------

extern "C" void kernel_launch(void* const* d_in, const int* in_sizes, int n_in,
                              void* d_out, int out_size, void* d_ws, size_t ws_size,
                              hipStream_t stream) {
  const float* x     = (const float*)d_in[0];
  const float* Wf    = (const float*)d_in[1];
  const float* bf    = (const float*)d_in[2];
  const float* Wg    = (const float*)d_in[3];
  const float* bg    = (const float*)d_in[4];
  const float* Wh    = (const float*)d_in[5];
  const float* bh    = (const float*)d_in[6];
  const float* Wv    = (const float*)d_in[7];
  const float* bv    = (const float*)d_in[8];
  const float* gamma = (const float*)d_in[9];
  float* out = (float*)d_out;
  char* w = (char*)d_ws;

  unsigned short* fhi = (unsigned short*)(w);                 // 4 MB  FM [8][128][4][512]
  unsigned short* flo = (unsigned short*)(w + 4194304);       // 4 MB
  unsigned short* ghi = (unsigned short*)(w + 8388608);       // 1 MB  FM [8][32][4][512]
  unsigned short* glo = (unsigned short*)(w + 9437184);       // 1 MB
  unsigned short* vp  = (unsigned short*)(w + 10485760);      // 4 MB  FM [8][16][32][512]
  unsigned short* oT  = (unsigned short*)(w + 14680064);      // 16 MB FM [8][256][8][512]
  unsigned short* wfh = (unsigned short*)(w + 31457280);      // 64 KB FM
  unsigned short* wfl = (unsigned short*)(w + 31522816);
  unsigned short* wgh = (unsigned short*)(w + 31588352);
  unsigned short* wgl = (unsigned short*)(w + 31653888);
  unsigned short* whb = (unsigned short*)(w + 31719424);      // 256 KB FM
  unsigned short* wvb = (unsigned short*)(w + 31981568);      // 256 KB FM

  prep_k<<<1280, 256, 0, stream>>>(Wf, Wg, Wh, Wv, wfh, wfl, wgh, wgl, whb, wvb);

  conv_all<<<dim3(32, 4, 8), 256, 0, stream>>>(x, wfh, wfl, wgh, wgl, whb,
                                               bf, bg, bh, fhi, flo, ghi, glo, vp);

  attn_mfma<<<dim3(128, 8), 256, 0, stream>>>(fhi, flo, ghi, glo, vp, oT);

  conv_final<<<dim3(32, 4, 8), 256, 0, stream>>>(oT, wvb, bv, out, x, gamma);
}

// Round 8
// 136.925 us; speedup vs baseline: 2.1141x; 1.3609x over previous
//
#include <hip/hip_runtime.h>
#include <cstddef>

typedef __attribute__((ext_vector_type(4))) float f32x4;
typedef __attribute__((ext_vector_type(16))) float f32x16;
typedef __attribute__((ext_vector_type(8))) short bf16x8;

#define MFMA16(A, B, C) __builtin_amdgcn_mfma_f32_16x16x32_bf16(A, B, C, 0, 0, 0)
#define MFMA32(A, B, C) __builtin_amdgcn_mfma_f32_32x32x16_bf16(A, B, C, 0, 0, 0)

__device__ __forceinline__ unsigned short f2bf(float f) {
  unsigned u = __float_as_uint(f);
  u += 0x7fffu + ((u >> 16) & 1u);
  return (unsigned short)(u >> 16);
}
__device__ __forceinline__ float bf2f(unsigned short s) {
  return __uint_as_float(((unsigned)s) << 16);
}

__device__ __forceinline__ void cvt_split8(float4 a, float4 b, bf16x8* H, bf16x8* L) {
  float v[8] = {a.x, a.y, a.z, a.w, b.x, b.y, b.z, b.w};
  unsigned hh[4], ll[4];
  #pragma unroll
  for (int p = 0; p < 4; ++p) {
    unsigned short h0 = f2bf(v[2 * p]), h1 = f2bf(v[2 * p + 1]);
    hh[p] = (unsigned)h0 | ((unsigned)h1 << 16);
    unsigned short l0 = f2bf(v[2 * p] - bf2f(h0));
    unsigned short l1 = f2bf(v[2 * p + 1] - bf2f(h1));
    ll[p] = (unsigned)l0 | ((unsigned)l1 << 16);
  }
  uint4 uh; uh.x = hh[0]; uh.y = hh[1]; uh.z = hh[2]; uh.w = hh[3];
  uint4 ul; ul.x = ll[0]; ul.y = ll[1]; ul.z = ll[2]; ul.w = ll[3];
  *H = *(bf16x8*)&uh;
  *L = *(bf16x8*)&ul;
}

__device__ __forceinline__ bf16x8 cvt_hi8(float4 a, float4 b) {
  float v[8] = {a.x, a.y, a.z, a.w, b.x, b.y, b.z, b.w};
  unsigned hh[4];
  #pragma unroll
  for (int p = 0; p < 4; ++p)
    hh[p] = (unsigned)f2bf(v[2 * p]) | ((unsigned)f2bf(v[2 * p + 1]) << 16);
  uint4 uh; uh.x = hh[0]; uh.y = hh[1]; uh.z = hh[2]; uh.w = hh[3];
  return *(bf16x8*)&uh;
}

// ---------- weight prep: fragment-major (FM) ----------

__global__ void prep_k(const float* __restrict__ Wf, const float* __restrict__ Wg,
                       const float* __restrict__ Wh, const float* __restrict__ Wv,
                       unsigned short* __restrict__ wfh, unsigned short* __restrict__ wfl,
                       unsigned short* __restrict__ wgh, unsigned short* __restrict__ wgl,
                       unsigned short* __restrict__ whb, unsigned short* __restrict__ wvb) {
  int i = blockIdx.x * 256 + threadIdx.x;
  if (i < 65536) {
    int ii = i & 32767;
    int j = ii & 7, slot = (ii >> 3) & 63, q = slot & 15, qt2 = slot >> 4;
    int kt = (ii >> 9) & 15, oct = ii >> 13;
    const float* src = (i < 32768) ? Wf : Wg;
    unsigned short* dh = (i < 32768) ? wfh : wgh;
    unsigned short* dl = (i < 32768) ? wfl : wgl;
    float v = src[(oct * 16 + q) * 512 + kt * 32 + qt2 * 8 + j];
    unsigned short h = f2bf(v);
    dh[ii] = h; dl[ii] = f2bf(v - bf2f(h));
  } else if (i < 196608) {
    int ii = i - 65536;
    int j = ii & 7, slot = (ii >> 3) & 63, q = slot & 15, qt2 = slot >> 4;
    int kt = (ii >> 9) & 15, oct = ii >> 13;
    whb[ii] = f2bf(Wh[(oct * 16 + q) * 512 + kt * 32 + qt2 * 8 + j]);
  } else if (i < 327680) {
    int ii = i - 196608;
    int j = ii & 7, slot = (ii >> 3) & 63, q = slot & 15, qt2 = slot >> 4;
    int kt = (ii >> 9) & 7, oct = ii >> 12;
    wvb[ii] = f2bf(Wv[(oct * 16 + q) * 256 + kt * 32 + qt2 * 8 + j]);
  }
}

// ---------- conv_all: 2 balanced roles (0 = f+g fused split, 1 = v 256oc) ----------
// fp32 LDS staging [128][33] dbuf, one cvt per fragment serving all weight sets.

#define LOADX(CN) { _Pragma("unroll") \
  for (int t_ = 0; t_ < 16; ++t_) vv[t_] = xbase[(size_t)((CN) * 32 + kq + t_) * 4096]; }
#define STOREX(XS) { _Pragma("unroll") \
  for (int i_ = 0; i_ < 4; ++i_) { \
    float4 wv_; wv_.x = vv[4*i_]; wv_.y = vv[4*i_+1]; wv_.z = vv[4*i_+2]; wv_.w = vv[4*i_+3]; \
    *(float4*)&(XS)[nloc][kq + 4 * i_] = wv_; } }

__global__ __launch_bounds__(256, 2)
void conv_all(const float* __restrict__ x,
              const unsigned short* __restrict__ wfh_, const unsigned short* __restrict__ wfl_,
              const unsigned short* __restrict__ wgh_, const unsigned short* __restrict__ wgl_,
              const unsigned short* __restrict__ whb_,
              const float* __restrict__ bf_, const float* __restrict__ bg_,
              const float* __restrict__ bh_,
              unsigned short* __restrict__ fhi, unsigned short* __restrict__ flo,
              unsigned short* __restrict__ ghi, unsigned short* __restrict__ glo,
              unsigned short* __restrict__ vp)
{
  __shared__ __align__(16) char smem[34304];
  float (*xsA)[33] = (float(*)[33])smem;
  float (*xsB)[33] = (float(*)[33])(smem + 16896);
  const int role = blockIdx.y;
  const int b = blockIdx.z, hp = blockIdx.x, n0 = hp * 128;
  const int tid = threadIdx.x, w = tid >> 6, lane = tid & 63, q = lane & 15, qt = lane >> 4;
  const int nloc = tid & 127;
  const int kq = (tid >> 7) * 16;
  const float* xbase = x + (size_t)(b * 512) * 4096 + n0 + nloc;
  float vv[16];

  if (role == 0) {
    // ---- f + g fused: one split-cvt feeds both ----
    f32x4 accf[2][4], accg[2][4];
    #pragma unroll
    for (int nt = 0; nt < 2; ++nt)
      #pragma unroll
      for (int ot = 0; ot < 4; ++ot) {
        accf[nt][ot] = (f32x4){0.f, 0.f, 0.f, 0.f};
        accg[nt][ot] = (f32x4){0.f, 0.f, 0.f, 0.f};
      }
    LOADX(0) STOREX(xsA)
    __syncthreads();
    for (int cc = 0; cc < 16; ++cc) {
      float (*cur)[33] = (cc & 1) ? xsB : xsA;
      float (*nxt)[33] = (cc & 1) ? xsA : xsB;
      if (cc < 15) LOADX(cc + 1)
      bf16x8 Ah[2], Al[2];
      #pragma unroll
      for (int nt = 0; nt < 2; ++nt) {
        int row = w * 32 + nt * 16 + q;
        float4 a0 = *(const float4*)&cur[row][qt * 8];
        float4 a1 = *(const float4*)&cur[row][qt * 8 + 4];
        cvt_split8(a0, a1, &Ah[nt], &Al[nt]);
      }
      {
        bf16x8 Bh[4], Bl[4];
        #pragma unroll
        for (int ot = 0; ot < 4; ++ot) {
          size_t wb = ((size_t)(ot * 16 + cc) << 9) + lane * 8;
          Bh[ot] = *(const bf16x8*)(wfh_ + wb);
          Bl[ot] = *(const bf16x8*)(wfl_ + wb);
        }
        #pragma unroll
        for (int nt = 0; nt < 2; ++nt)
          #pragma unroll
          for (int ot = 0; ot < 4; ++ot) {
            accf[nt][ot] = MFMA16(Ah[nt], Bh[ot], accf[nt][ot]);
            accf[nt][ot] = MFMA16(Ah[nt], Bl[ot], accf[nt][ot]);
            accf[nt][ot] = MFMA16(Al[nt], Bh[ot], accf[nt][ot]);
          }
      }
      {
        bf16x8 Bh[4], Bl[4];
        #pragma unroll
        for (int ot = 0; ot < 4; ++ot) {
          size_t wb = ((size_t)(ot * 16 + cc) << 9) + lane * 8;
          Bh[ot] = *(const bf16x8*)(wgh_ + wb);
          Bl[ot] = *(const bf16x8*)(wgl_ + wb);
        }
        #pragma unroll
        for (int nt = 0; nt < 2; ++nt)
          #pragma unroll
          for (int ot = 0; ot < 4; ++ot) {
            accg[nt][ot] = MFMA16(Ah[nt], Bh[ot], accg[nt][ot]);
            accg[nt][ot] = MFMA16(Ah[nt], Bl[ot], accg[nt][ot]);
            accg[nt][ot] = MFMA16(Al[nt], Bh[ot], accg[nt][ot]);
          }
      }
      if (cc < 15) STOREX(nxt)
      __syncthreads();
    }
    // f epilogue: FM for attn MFMA32-B
    #pragma unroll
    for (int nt = 0; nt < 2; ++nt)
      #pragma unroll
      for (int ot = 0; ot < 4; ++ot)
        #pragma unroll
        for (int r = 0; r < 4; ++r) {
          float v = accf[nt][ot][r] + bf_[ot * 16 + q];
          unsigned short h = f2bf(v);
          size_t o = (((size_t)(b * 128 + hp * 4 + w) * 4 + ot) * 64 +
                      (q >> 3) * 32 + nt * 16 + qt * 4 + r) * 8 + (q & 7);
          fhi[o] = h;
          flo[o] = f2bf(v - bf2f(h));
        }
    // g epilogue: pool via LDS -> FM for attn MFMA32-A
    float (*pl)[67] = (float(*)[67])smem;
    #pragma unroll
    for (int nt = 0; nt < 2; ++nt)
      #pragma unroll
      for (int ot = 0; ot < 4; ++ot)
        #pragma unroll
        for (int r = 0; r < 4; ++r)
          pl[w * 32 + nt * 16 + qt * 4 + r][ot * 16 + q] = accg[nt][ot][r];
    __syncthreads();
    const int c = tid & 63;
    #pragma unroll
    for (int it = 0; it < 8; ++it) {
      int wp = (tid >> 6) + it * 4;
      float v = fmaxf(fmaxf(pl[2 * wp][c], pl[2 * wp + 1][c]),
                      fmaxf(pl[64 + 2 * wp][c], pl[65 + 2 * wp][c])) + bg_[c];
      unsigned short h = f2bf(v);
      size_t o = (((size_t)(b * 32 + hp) * 4 + (c >> 4)) * 64 +
                  ((c >> 3) & 1) * 32 + wp) * 8 + (c & 7);
      ghi[o] = h;
      glo[o] = f2bf(v - bf2f(h));
    }
  } else {
    // ---- v: all 256 oc, hi-only ----
    f32x4 acc[2][16];
    #pragma unroll
    for (int nt = 0; nt < 2; ++nt)
      #pragma unroll
      for (int ot = 0; ot < 16; ++ot) acc[nt][ot] = (f32x4){0.f, 0.f, 0.f, 0.f};
    LOADX(0) STOREX(xsA)
    __syncthreads();
    for (int cc = 0; cc < 16; ++cc) {
      float (*cur)[33] = (cc & 1) ? xsB : xsA;
      float (*nxt)[33] = (cc & 1) ? xsA : xsB;
      if (cc < 15) LOADX(cc + 1)
      bf16x8 A_[2];
      #pragma unroll
      for (int nt = 0; nt < 2; ++nt) {
        int row = w * 32 + nt * 16 + q;
        float4 a0 = *(const float4*)&cur[row][qt * 8];
        float4 a1 = *(const float4*)&cur[row][qt * 8 + 4];
        A_[nt] = cvt_hi8(a0, a1);
      }
      #pragma unroll
      for (int oh = 0; oh < 2; ++oh) {
        bf16x8 B_[8];
        #pragma unroll
        for (int ot = 0; ot < 8; ++ot)
          B_[ot] = *(const bf16x8*)(whb_ + ((size_t)((oh * 8 + ot) * 16 + cc) << 9) + lane * 8);
        #pragma unroll
        for (int nt = 0; nt < 2; ++nt)
          #pragma unroll
          for (int ot = 0; ot < 8; ++ot)
            acc[nt][oh * 8 + ot] = MFMA16(A_[nt], B_[ot], acc[nt][oh * 8 + ot]);
      }
      if (cc < 15) STOREX(nxt)
      __syncthreads();
    }
    // pool epilogue -> FM for attn PV MFMA16-A (4 phases of 64 oc)
    float (*pl)[67] = (float(*)[67])smem;
    #pragma unroll
    for (int oh = 0; oh < 4; ++oh) {
      if (oh) __syncthreads();
      #pragma unroll
      for (int nt = 0; nt < 2; ++nt)
        #pragma unroll
        for (int ot4 = 0; ot4 < 4; ++ot4)
          #pragma unroll
          for (int r = 0; r < 4; ++r)
            pl[w * 32 + nt * 16 + qt * 4 + r][ot4 * 16 + q] = acc[nt][oh * 4 + ot4][r];
      __syncthreads();
      const int wp = tid & 31;
      #pragma unroll
      for (int it = 0; it < 8; ++it) {
        int cc2 = (tid >> 5) + it * 8;
        int cv = oh * 64 + cc2;
        float v = fmaxf(fmaxf(pl[2 * wp][cc2], pl[2 * wp + 1][cc2]),
                        fmaxf(pl[64 + 2 * wp][cc2], pl[65 + 2 * wp][cc2])) + bh_[cv];
        size_t o = (((size_t)(b * 16 + (cv >> 4)) * 32 + hp) * 64 +
                    (wp >> 3) * 16 + (cv & 15)) * 8 + (wp & 7);
        vp[o] = f2bf(v);
      }
    }
  }
}

// ---------- fused attention: QB=32, online softmax over 4 m-chunks of 256 ----------

#define PROW 264

__global__ __launch_bounds__(256, 4)
void attn_mfma(const unsigned short* __restrict__ f_, const unsigned short* __restrict__ fl_,
               const unsigned short* __restrict__ g_, const unsigned short* __restrict__ gl_,
               const unsigned short* __restrict__ vp, unsigned short* __restrict__ oT)
{
  __shared__ __align__(16) unsigned short P[32 * PROW];   // 16,896 B
  __shared__ float redm[4][32], reds[4][32];
  __shared__ float rfrow[32], Srow[32];
  const int b = blockIdx.y, bx = blockIdx.x;
  const int tid = threadIdx.x, w = tid >> 6, lane = tid & 63;
  const int q32 = lane & 31;
  const int q16 = lane & 15, qt = lane >> 4;

  bf16x8 Fh[4], Fl[4];
  {
    size_t fb = ((size_t)(b * 128 + bx) << 11) + lane * 8;
    #pragma unroll
    for (int s = 0; s < 4; ++s) {
      Fh[s] = *(const bf16x8*)(f_ + fb + (s << 9));
      Fl[s] = *(const bf16x8*)(fl_ + fb + (s << 9));
    }
  }

  float M = -3.0e38f;
  f32x4 oacc[4][2];
  #pragma unroll
  for (int c4 = 0; c4 < 4; ++c4) {
    oacc[c4][0] = (f32x4){0.f, 0.f, 0.f, 0.f};
    oacc[c4][1] = (f32x4){0.f, 0.f, 0.f, 0.f};
  }
  const size_t vroot = ((size_t)(b * 16 + w * 4) * 32) * 512 + lane * 8;

#define VLD(C4, KS) (*(const bf16x8*)(vp + vroot + ((size_t)((C4) * 32 + mc * 8 + (KS)) << 9)))
#define LOADVA(KS) { va0 = VLD(0, KS); va1 = VLD(1, KS); va2 = VLD(2, KS); va3 = VLD(3, KS); }
#define LOADVB(KS) { vb0 = VLD(0, KS); vb1 = VLD(1, KS); vb2 = VLD(2, KS); vb3 = VLD(3, KS); }
#define PVMFMA(KS, V0, V1, V2, V3) { \
  bf16x8 pb0 = *(const bf16x8*)&P[q16 * PROW + (KS) * 32 + qt * 8]; \
  bf16x8 pb1 = *(const bf16x8*)&P[(16 + q16) * PROW + (KS) * 32 + qt * 8]; \
  oacc[0][0] = MFMA16(V0, pb0, oacc[0][0]); oacc[1][0] = MFMA16(V1, pb0, oacc[1][0]); \
  oacc[2][0] = MFMA16(V2, pb0, oacc[2][0]); oacc[3][0] = MFMA16(V3, pb0, oacc[3][0]); \
  oacc[0][1] = MFMA16(V0, pb1, oacc[0][1]); oacc[1][1] = MFMA16(V1, pb1, oacc[1][1]); \
  oacc[2][1] = MFMA16(V2, pb1, oacc[2][1]); oacc[3][1] = MFMA16(V3, pb1, oacc[3][1]); }

  #pragma unroll 1
  for (int mc = 0; mc < 4; ++mc) {
    // ---- s phase ----
    f32x16 sa[2] = {};
    #pragma unroll
    for (int t = 0; t < 2; ++t) {
      size_t gb = ((size_t)(b * 32 + mc * 8 + w * 2 + t) << 11) + lane * 8;
      bf16x8 Gh[4], Gl[4];
      #pragma unroll
      for (int s = 0; s < 4; ++s) {
        Gh[s] = *(const bf16x8*)(g_ + gb + (s << 9));
        Gl[s] = *(const bf16x8*)(gl_ + gb + (s << 9));
      }
      #pragma unroll
      for (int s = 0; s < 4; ++s) {
        sa[t] = MFMA32(Gh[s], Fh[s], sa[t]);
        sa[t] = MFMA32(Gh[s], Fl[s], sa[t]);
        sa[t] = MFMA32(Gl[s], Fh[s], sa[t]);
      }
    }

    // hoisted first PV v-loads: independent of softmax, latency hides under it
    bf16x8 va0, va1, va2, va3, vb0, vb1, vb2, vb3;
    LOADVA(0)

    // ---- online softmax ----
    float mx = -3.0e38f;
    #pragma unroll
    for (int t = 0; t < 2; ++t)
      #pragma unroll
      for (int r = 0; r < 16; ++r) mx = fmaxf(mx, sa[t][r]);
    mx = fmaxf(mx, __shfl_xor(mx, 32));
    if (lane < 32) redm[w][lane] = mx;
    __syncthreads();
    float gmx = fmaxf(fmaxf(redm[0][q32], redm[1][q32]), fmaxf(redm[2][q32], redm[3][q32]));
    float Mnew = fmaxf(M, gmx);
    float rf = __expf(M - Mnew);
    M = Mnew;
    float csum = 0.f;
    #pragma unroll
    for (int t = 0; t < 2; ++t)
      #pragma unroll
      for (int r = 0; r < 16; ++r) {
        float p = __expf(sa[t][r] - Mnew);
        sa[t][r] = p;
        csum += p;
      }
    csum += __shfl_xor(csum, 32);
    if (lane < 32) reds[w][lane] = csum;

    #pragma unroll
    for (int t = 0; t < 2; ++t)
      #pragma unroll
      for (int j = 0; j < 4; ++j) {
        uint2 pk;
        pk.x = (unsigned)f2bf(sa[t][4 * j + 0]) | ((unsigned)f2bf(sa[t][4 * j + 1]) << 16);
        pk.y = (unsigned)f2bf(sa[t][4 * j + 2]) | ((unsigned)f2bf(sa[t][4 * j + 3]) << 16);
        *(uint2*)&P[q32 * PROW + w * 64 + t * 32 + j * 8 + (lane >> 5) * 4] = pk;
      }
    __syncthreads();
    float ct_ = reds[0][q32] + reds[1][q32] + reds[2][q32] + reds[3][q32];
    if (w == 0 && lane < 32) {
      Srow[lane] = (mc == 0) ? ct_ : Srow[lane] * rf + ct_;
      rfrow[lane] = rf;
    }
    __syncthreads();

    // ---- PV over this chunk ----
    if (mc > 0) {
      float rf0 = rfrow[q16], rf1 = rfrow[16 + q16];
      #pragma unroll
      for (int c4 = 0; c4 < 4; ++c4) {
        oacc[c4][0] *= rf0;
        oacc[c4][1] *= rf1;
      }
    }
    LOADVB(1)
    #pragma unroll
    for (int kp = 0; kp < 4; ++kp) {
      PVMFMA(2 * kp, va0, va1, va2, va3)
      if (2 * kp + 2 < 8) LOADVA(2 * kp + 2)
      PVMFMA(2 * kp + 1, vb0, vb1, vb2, vb3)
      if (2 * kp + 3 < 8) LOADVB(2 * kp + 3)
    }
  }

  // ---- epilogue: oT fragment-major for conv_final ----
  const float rinv0 = 1.0f / Srow[q16];
  const float rinv1 = 1.0f / Srow[16 + q16];
  #pragma unroll
  for (int c4 = 0; c4 < 4; ++c4) {
    int ct = w * 4 + c4;
    int kt = ct >> 1;
    int qtp = (ct & 1) * 2 + (qt >> 1);
    int jo = (qt & 1) * 4;
    uint2 pk0, pk1;
    pk0.x = (unsigned)f2bf(oacc[c4][0][0] * rinv0) | ((unsigned)f2bf(oacc[c4][0][1] * rinv0) << 16);
    pk0.y = (unsigned)f2bf(oacc[c4][0][2] * rinv0) | ((unsigned)f2bf(oacc[c4][0][3] * rinv0) << 16);
    pk1.x = (unsigned)f2bf(oacc[c4][1][0] * rinv1) | ((unsigned)f2bf(oacc[c4][1][1] * rinv1) << 16);
    pk1.y = (unsigned)f2bf(oacc[c4][1][2] * rinv1) | ((unsigned)f2bf(oacc[c4][1][3] * rinv1) << 16);
    size_t o0 = (((size_t)(b * 256 + bx * 2) * 8 + kt) * 64 + qtp * 16 + q16) * 8 + jo;
    *(uint2*)(oT + o0) = pk0;
    *(uint2*)(oT + o0 + 4096) = pk1;
  }
}

// ---------- final conv: FM A (oT) and FM W, out = gamma*(oT.Wv + bv) + x ----------

__global__ __launch_bounds__(256)
void conv_final(const unsigned short* __restrict__ A, const unsigned short* __restrict__ W,
                const float* __restrict__ bias, float* __restrict__ out,
                const float* __restrict__ resid, const float* __restrict__ gamma_p)
{
  const int b = blockIdx.z, oc0 = blockIdx.y * 128, n0 = blockIdx.x * 128;
  const int tid = threadIdx.x, w = tid >> 6, lane = tid & 63, q = lane & 15, qt = lane >> 4;

  f32x4 acc[2][8];
  #pragma unroll
  for (int nt = 0; nt < 2; ++nt)
    #pragma unroll
    for (int ot = 0; ot < 8; ++ot) acc[nt][ot] = (f32x4){0.f, 0.f, 0.f, 0.f};

  #pragma unroll
  for (int ks = 0; ks < 8; ++ks) {
    bf16x8 A_[2], B_[8];
    #pragma unroll
    for (int nt = 0; nt < 2; ++nt)
      A_[nt] = *(const bf16x8*)(A + (((size_t)(b * 256 + (n0 >> 4) + w * 2 + nt) * 8 + ks) << 9) + lane * 8);
    #pragma unroll
    for (int ot = 0; ot < 8; ++ot)
      B_[ot] = *(const bf16x8*)(W + (((size_t)((oc0 >> 4) + ot) * 8 + ks) << 9) + lane * 8);
    #pragma unroll
    for (int nt = 0; nt < 2; ++nt)
      #pragma unroll
      for (int ot = 0; ot < 8; ++ot)
        acc[nt][ot] = MFMA16(A_[nt], B_[ot], acc[nt][ot]);
  }

  const float gm = gamma_p[0];
  #pragma unroll
  for (int ot = 0; ot < 8; ++ot) {
    int oc = oc0 + ot * 16 + q;
    float bs = bias[oc];
    #pragma unroll
    for (int nt = 0; nt < 2; ++nt) {
      int n = n0 + w * 32 + nt * 16 + qt * 4;
      size_t o = ((size_t)(b * 512) + oc) * 4096 + n;
      float4 rs = *(const float4*)&resid[o];
      float4 ov;
      ov.x = gm * (acc[nt][ot][0] + bs) + rs.x;
      ov.y = gm * (acc[nt][ot][1] + bs) + rs.y;
      ov.z = gm * (acc[nt][ot][2] + bs) + rs.z;
      ov.w = gm * (acc[nt][ot][3] + bs) + rs.w;
      *(float4*)&out[o] = ov;
    }
  }
}

// ---------- launch ----------

extern "C" void kernel_launch(void* const* d_in, const int* in_sizes, int n_in,
                              void* d_out, int out_size, void* d_ws, size_t ws_size,
                              hipStream_t stream) {
  const float* x     = (const float*)d_in[0];
  const float* Wf    = (const float*)d_in[1];
  const float* bf    = (const float*)d_in[2];
  const float* Wg    = (const float*)d_in[3];
  const float* bg    = (const float*)d_in[4];
  const float* Wh    = (const float*)d_in[5];
  const float* bh    = (const float*)d_in[6];
  const float* Wv    = (const float*)d_in[7];
  const float* bv    = (const float*)d_in[8];
  const float* gamma = (const float*)d_in[9];
  float* out = (float*)d_out;
  char* w = (char*)d_ws;

  unsigned short* fhi = (unsigned short*)(w);                 // 4 MB  FM [8][128][4][512]
  unsigned short* flo = (unsigned short*)(w + 4194304);       // 4 MB
  unsigned short* ghi = (unsigned short*)(w + 8388608);       // 1 MB  FM [8][32][4][512]
  unsigned short* glo = (unsigned short*)(w + 9437184);       // 1 MB
  unsigned short* vp  = (unsigned short*)(w + 10485760);      // 4 MB  FM [8][16][32][512]
  unsigned short* oT  = (unsigned short*)(w + 14680064);      // 16 MB FM [8][256][8][512]
  unsigned short* wfh = (unsigned short*)(w + 31457280);      // 64 KB FM
  unsigned short* wfl = (unsigned short*)(w + 31522816);
  unsigned short* wgh = (unsigned short*)(w + 31588352);
  unsigned short* wgl = (unsigned short*)(w + 31653888);
  unsigned short* whb = (unsigned short*)(w + 31719424);      // 256 KB FM
  unsigned short* wvb = (unsigned short*)(w + 31981568);      // 256 KB FM

  prep_k<<<1280, 256, 0, stream>>>(Wf, Wg, Wh, Wv, wfh, wfl, wgh, wgl, whb, wvb);

  conv_all<<<dim3(32, 2, 8), 256, 0, stream>>>(x, wfh, wfl, wgh, wgl, whb,
                                               bf, bg, bh, fhi, flo, ghi, glo, vp);

  attn_mfma<<<dim3(128, 8), 256, 0, stream>>>(fhi, flo, ghi, glo, vp, oT);

  conv_final<<<dim3(32, 4, 8), 256, 0, stream>>>(oT, wvb, bv, out, x, gamma);
}

// Round 9
// 115.896 us; speedup vs baseline: 2.4976x; 1.1815x over previous
//
#include <hip/hip_runtime.h>
#include <cstddef>

typedef __attribute__((ext_vector_type(4))) float f32x4;
typedef __attribute__((ext_vector_type(16))) float f32x16;
typedef __attribute__((ext_vector_type(8))) short bf16x8;

#define MFMA16(A, B, C) __builtin_amdgcn_mfma_f32_16x16x32_bf16(A, B, C, 0, 0, 0)
#define MFMA32(A, B, C) __builtin_amdgcn_mfma_f32_32x32x16_bf16(A, B, C, 0, 0, 0)

__device__ __forceinline__ unsigned short f2bf(float f) {
  unsigned u = __float_as_uint(f);
  u += 0x7fffu + ((u >> 16) & 1u);
  return (unsigned short)(u >> 16);
}
__device__ __forceinline__ float bf2f(unsigned short s) {
  return __uint_as_float(((unsigned)s) << 16);
}

__device__ __forceinline__ void cvt_split8(float4 a, float4 b, bf16x8* H, bf16x8* L) {
  float v[8] = {a.x, a.y, a.z, a.w, b.x, b.y, b.z, b.w};
  unsigned hh[4], ll[4];
  #pragma unroll
  for (int p = 0; p < 4; ++p) {
    unsigned short h0 = f2bf(v[2 * p]), h1 = f2bf(v[2 * p + 1]);
    hh[p] = (unsigned)h0 | ((unsigned)h1 << 16);
    unsigned short l0 = f2bf(v[2 * p] - bf2f(h0));
    unsigned short l1 = f2bf(v[2 * p + 1] - bf2f(h1));
    ll[p] = (unsigned)l0 | ((unsigned)l1 << 16);
  }
  uint4 uh; uh.x = hh[0]; uh.y = hh[1]; uh.z = hh[2]; uh.w = hh[3];
  uint4 ul; ul.x = ll[0]; ul.y = ll[1]; ul.z = ll[2]; ul.w = ll[3];
  *H = *(bf16x8*)&uh;
  *L = *(bf16x8*)&ul;
}

__device__ __forceinline__ bf16x8 cvt_hi8(float4 a, float4 b) {
  float v[8] = {a.x, a.y, a.z, a.w, b.x, b.y, b.z, b.w};
  unsigned hh[4];
  #pragma unroll
  for (int p = 0; p < 4; ++p)
    hh[p] = (unsigned)f2bf(v[2 * p]) | ((unsigned)f2bf(v[2 * p + 1]) << 16);
  uint4 uh; uh.x = hh[0]; uh.y = hh[1]; uh.z = hh[2]; uh.w = hh[3];
  return *(bf16x8*)&uh;
}

// ---------- weight prep: fragment-major (FM) ----------

__global__ void prep_k(const float* __restrict__ Wf, const float* __restrict__ Wg,
                       const float* __restrict__ Wh, const float* __restrict__ Wv,
                       unsigned short* __restrict__ wfh, unsigned short* __restrict__ wfl,
                       unsigned short* __restrict__ wgh, unsigned short* __restrict__ wgl,
                       unsigned short* __restrict__ whb, unsigned short* __restrict__ wvb) {
  int i = blockIdx.x * 256 + threadIdx.x;
  if (i < 65536) {
    int ii = i & 32767;
    int j = ii & 7, slot = (ii >> 3) & 63, q = slot & 15, qt2 = slot >> 4;
    int kt = (ii >> 9) & 15, oct = ii >> 13;
    const float* src = (i < 32768) ? Wf : Wg;
    unsigned short* dh = (i < 32768) ? wfh : wgh;
    unsigned short* dl = (i < 32768) ? wfl : wgl;
    float v = src[(oct * 16 + q) * 512 + kt * 32 + qt2 * 8 + j];
    unsigned short h = f2bf(v);
    dh[ii] = h; dl[ii] = f2bf(v - bf2f(h));
  } else if (i < 196608) {
    int ii = i - 65536;
    int j = ii & 7, slot = (ii >> 3) & 63, q = slot & 15, qt2 = slot >> 4;
    int kt = (ii >> 9) & 15, oct = ii >> 13;
    whb[ii] = f2bf(Wh[(oct * 16 + q) * 512 + kt * 32 + qt2 * 8 + j]);
  } else if (i < 327680) {
    int ii = i - 196608;
    int j = ii & 7, slot = (ii >> 3) & 63, q = slot & 15, qt2 = slot >> 4;
    int kt = (ii >> 9) & 7, oct = ii >> 12;
    wvb[ii] = f2bf(Wv[(oct * 16 + q) * 256 + kt * 32 + qt2 * 8 + j]);
  }
}

// ---------- conv_all: 2 roles (0 = f+g fused split, 1 = v 256oc), XCD-local b ----------

#define LOADX(CN) { _Pragma("unroll") \
  for (int t_ = 0; t_ < 16; ++t_) vv[t_] = xbase[(size_t)((CN) * 32 + kq + t_) * 4096]; }
#define STOREX(XS) { _Pragma("unroll") \
  for (int i_ = 0; i_ < 4; ++i_) { \
    float4 wv_; wv_.x = vv[4*i_]; wv_.y = vv[4*i_+1]; wv_.z = vv[4*i_+2]; wv_.w = vv[4*i_+3]; \
    *(float4*)&(XS)[nloc][kq + 4 * i_] = wv_; } }

__global__ __launch_bounds__(256, 2)
void conv_all(const float* __restrict__ x,
              const unsigned short* __restrict__ wfh_, const unsigned short* __restrict__ wfl_,
              const unsigned short* __restrict__ wgh_, const unsigned short* __restrict__ wgl_,
              const unsigned short* __restrict__ whb_,
              const float* __restrict__ bf_, const float* __restrict__ bg_,
              const float* __restrict__ bh_,
              unsigned short* __restrict__ fhi, unsigned short* __restrict__ flo,
              unsigned short* __restrict__ ghi, unsigned short* __restrict__ glo,
              unsigned short* __restrict__ vp)
{
  __shared__ __align__(16) char smem[34304];
  float (*xsA)[33] = (float(*)[33])smem;
  float (*xsB)[33] = (float(*)[33])(smem + 16896);
  const int bid = blockIdx.x;
  const int b = bid & 7;
  const int idx = bid >> 3;
  const int role = idx & 1;
  const int hp = idx >> 1;
  const int n0 = hp * 128;
  const int tid = threadIdx.x, w = tid >> 6, lane = tid & 63, q = lane & 15, qt = lane >> 4;
  const int nloc = tid & 127;
  const int kq = (tid >> 7) * 16;
  const float* xbase = x + (size_t)(b * 512) * 4096 + n0 + nloc;
  float vv[16];

  if (role == 0) {
    f32x4 accf[2][4], accg[2][4];
    #pragma unroll
    for (int nt = 0; nt < 2; ++nt)
      #pragma unroll
      for (int ot = 0; ot < 4; ++ot) {
        accf[nt][ot] = (f32x4){0.f, 0.f, 0.f, 0.f};
        accg[nt][ot] = (f32x4){0.f, 0.f, 0.f, 0.f};
      }
    LOADX(0) STOREX(xsA)
    __syncthreads();
    for (int cc = 0; cc < 16; ++cc) {
      float (*cur)[33] = (cc & 1) ? xsB : xsA;
      float (*nxt)[33] = (cc & 1) ? xsA : xsB;
      if (cc < 15) LOADX(cc + 1)
      bf16x8 Ah[2], Al[2];
      #pragma unroll
      for (int nt = 0; nt < 2; ++nt) {
        int row = w * 32 + nt * 16 + q;
        float4 a0 = *(const float4*)&cur[row][qt * 8];
        float4 a1 = *(const float4*)&cur[row][qt * 8 + 4];
        cvt_split8(a0, a1, &Ah[nt], &Al[nt]);
      }
      {
        bf16x8 Bh[4], Bl[4];
        #pragma unroll
        for (int ot = 0; ot < 4; ++ot) {
          size_t wb = ((size_t)(ot * 16 + cc) << 9) + lane * 8;
          Bh[ot] = *(const bf16x8*)(wfh_ + wb);
          Bl[ot] = *(const bf16x8*)(wfl_ + wb);
        }
        #pragma unroll
        for (int nt = 0; nt < 2; ++nt)
          #pragma unroll
          for (int ot = 0; ot < 4; ++ot) {
            accf[nt][ot] = MFMA16(Ah[nt], Bh[ot], accf[nt][ot]);
            accf[nt][ot] = MFMA16(Ah[nt], Bl[ot], accf[nt][ot]);
            accf[nt][ot] = MFMA16(Al[nt], Bh[ot], accf[nt][ot]);
          }
      }
      {
        bf16x8 Bh[4], Bl[4];
        #pragma unroll
        for (int ot = 0; ot < 4; ++ot) {
          size_t wb = ((size_t)(ot * 16 + cc) << 9) + lane * 8;
          Bh[ot] = *(const bf16x8*)(wgh_ + wb);
          Bl[ot] = *(const bf16x8*)(wgl_ + wb);
        }
        #pragma unroll
        for (int nt = 0; nt < 2; ++nt)
          #pragma unroll
          for (int ot = 0; ot < 4; ++ot) {
            accg[nt][ot] = MFMA16(Ah[nt], Bh[ot], accg[nt][ot]);
            accg[nt][ot] = MFMA16(Ah[nt], Bl[ot], accg[nt][ot]);
            accg[nt][ot] = MFMA16(Al[nt], Bh[ot], accg[nt][ot]);
          }
      }
      if (cc < 15) STOREX(nxt)
      __syncthreads();
    }
    #pragma unroll
    for (int nt = 0; nt < 2; ++nt)
      #pragma unroll
      for (int ot = 0; ot < 4; ++ot)
        #pragma unroll
        for (int r = 0; r < 4; ++r) {
          float v = accf[nt][ot][r] + bf_[ot * 16 + q];
          unsigned short h = f2bf(v);
          size_t o = (((size_t)(b * 128 + hp * 4 + w) * 4 + ot) * 64 +
                      (q >> 3) * 32 + nt * 16 + qt * 4 + r) * 8 + (q & 7);
          fhi[o] = h;
          flo[o] = f2bf(v - bf2f(h));
        }
    float (*pl)[67] = (float(*)[67])smem;
    #pragma unroll
    for (int nt = 0; nt < 2; ++nt)
      #pragma unroll
      for (int ot = 0; ot < 4; ++ot)
        #pragma unroll
        for (int r = 0; r < 4; ++r)
          pl[w * 32 + nt * 16 + qt * 4 + r][ot * 16 + q] = accg[nt][ot][r];
    __syncthreads();
    const int c = tid & 63;
    #pragma unroll
    for (int it = 0; it < 8; ++it) {
      int wp = (tid >> 6) + it * 4;
      float v = fmaxf(fmaxf(pl[2 * wp][c], pl[2 * wp + 1][c]),
                      fmaxf(pl[64 + 2 * wp][c], pl[65 + 2 * wp][c])) + bg_[c];
      unsigned short h = f2bf(v);
      size_t o = (((size_t)(b * 32 + hp) * 4 + (c >> 4)) * 64 +
                  ((c >> 3) & 1) * 32 + wp) * 8 + (c & 7);
      ghi[o] = h;
      glo[o] = f2bf(v - bf2f(h));
    }
  } else {
    f32x4 acc[2][16];
    #pragma unroll
    for (int nt = 0; nt < 2; ++nt)
      #pragma unroll
      for (int ot = 0; ot < 16; ++ot) acc[nt][ot] = (f32x4){0.f, 0.f, 0.f, 0.f};
    LOADX(0) STOREX(xsA)
    __syncthreads();
    for (int cc = 0; cc < 16; ++cc) {
      float (*cur)[33] = (cc & 1) ? xsB : xsA;
      float (*nxt)[33] = (cc & 1) ? xsA : xsB;
      if (cc < 15) LOADX(cc + 1)
      bf16x8 A_[2];
      #pragma unroll
      for (int nt = 0; nt < 2; ++nt) {
        int row = w * 32 + nt * 16 + q;
        float4 a0 = *(const float4*)&cur[row][qt * 8];
        float4 a1 = *(const float4*)&cur[row][qt * 8 + 4];
        A_[nt] = cvt_hi8(a0, a1);
      }
      #pragma unroll
      for (int oh = 0; oh < 2; ++oh) {
        bf16x8 B_[8];
        #pragma unroll
        for (int ot = 0; ot < 8; ++ot)
          B_[ot] = *(const bf16x8*)(whb_ + ((size_t)((oh * 8 + ot) * 16 + cc) << 9) + lane * 8);
        #pragma unroll
        for (int nt = 0; nt < 2; ++nt)
          #pragma unroll
          for (int ot = 0; ot < 8; ++ot)
            acc[nt][oh * 8 + ot] = MFMA16(A_[nt], B_[ot], acc[nt][oh * 8 + ot]);
      }
      if (cc < 15) STOREX(nxt)
      __syncthreads();
    }
    float (*pl)[67] = (float(*)[67])smem;
    #pragma unroll
    for (int oh = 0; oh < 4; ++oh) {
      if (oh) __syncthreads();
      #pragma unroll
      for (int nt = 0; nt < 2; ++nt)
        #pragma unroll
        for (int ot4 = 0; ot4 < 4; ++ot4)
          #pragma unroll
          for (int r = 0; r < 4; ++r)
            pl[w * 32 + nt * 16 + qt * 4 + r][ot4 * 16 + q] = acc[nt][oh * 4 + ot4][r];
      __syncthreads();
      const int wp = tid & 31;
      #pragma unroll
      for (int it = 0; it < 8; ++it) {
        int cc2 = (tid >> 5) + it * 8;
        int cv = oh * 64 + cc2;
        float v = fmaxf(fmaxf(pl[2 * wp][cc2], pl[2 * wp + 1][cc2]),
                        fmaxf(pl[64 + 2 * wp][cc2], pl[65 + 2 * wp][cc2])) + bh_[cv];
        size_t o = (((size_t)(b * 16 + (cv >> 4)) * 32 + hp) * 64 +
                    (wp >> 3) * 16 + (cv & 15)) * 8 + (wp & 7);
        vp[o] = f2bf(v);
      }
    }
  }
}

// ---------- fused attention: QB=64, 4 m-chunks of 256, XCD-local b ----------

#define PROW 264

__global__ __launch_bounds__(256, 2)
void attn_mfma(const unsigned short* __restrict__ f_, const unsigned short* __restrict__ fl_,
               const unsigned short* __restrict__ g_, const unsigned short* __restrict__ gl_,
               const unsigned short* __restrict__ vp, unsigned short* __restrict__ oT)
{
  __shared__ __align__(16) unsigned short PB[64 * PROW];    // 33,792 B (P, then obuf)
  __shared__ float redm[4][2][32], reds[4][2][32];
  __shared__ float rfrow[64], Srow[64];
  const int b = blockIdx.x & 7, bx = blockIdx.x >> 3;
  const int tid = threadIdx.x, w = tid >> 6, lane = tid & 63;
  const int q32 = lane & 31, hl = lane >> 5;
  const int q16 = lane & 15, qt = lane >> 4;

  // f B-frags for both 32-q tiles (held in regs, shared by all m)
  bf16x8 Fh[2][4], Fl[2][4];
  #pragma unroll
  for (int qt2 = 0; qt2 < 2; ++qt2) {
    size_t fb = ((size_t)(b * 128 + bx * 2 + qt2) << 11) + lane * 8;
    #pragma unroll
    for (int s = 0; s < 4; ++s) {
      Fh[qt2][s] = *(const bf16x8*)(f_ + fb + (s << 9));
      Fl[qt2][s] = *(const bf16x8*)(fl_ + fb + (s << 9));
    }
  }

  float M0 = -3.0e38f, M1 = -3.0e38f;
  f32x4 oacc[4][4];       // [c4][qsub]
  #pragma unroll
  for (int c4 = 0; c4 < 4; ++c4)
    #pragma unroll
    for (int qs = 0; qs < 4; ++qs) oacc[c4][qs] = (f32x4){0.f, 0.f, 0.f, 0.f};
  const size_t vroot = ((size_t)(b * 16 + w * 4) * 32) * 512 + lane * 8;

#define VLD(C4, KS) (*(const bf16x8*)(vp + vroot + ((size_t)((C4) * 32 + mc * 8 + (KS)) << 9)))
#define LOADVA(KS) { va0 = VLD(0, KS); va1 = VLD(1, KS); va2 = VLD(2, KS); va3 = VLD(3, KS); }
#define LOADVB(KS) { vb0 = VLD(0, KS); vb1 = VLD(1, KS); vb2 = VLD(2, KS); vb3 = VLD(3, KS); }
#define PVMFMA(KS, V0, V1, V2, V3) { \
  bf16x8 pb0 = *(const bf16x8*)&PB[q16 * PROW + (KS) * 32 + qt * 8]; \
  bf16x8 pb1 = *(const bf16x8*)&PB[(16 + q16) * PROW + (KS) * 32 + qt * 8]; \
  bf16x8 pb2 = *(const bf16x8*)&PB[(32 + q16) * PROW + (KS) * 32 + qt * 8]; \
  bf16x8 pb3 = *(const bf16x8*)&PB[(48 + q16) * PROW + (KS) * 32 + qt * 8]; \
  oacc[0][0] = MFMA16(V0, pb0, oacc[0][0]); oacc[1][0] = MFMA16(V1, pb0, oacc[1][0]); \
  oacc[2][0] = MFMA16(V2, pb0, oacc[2][0]); oacc[3][0] = MFMA16(V3, pb0, oacc[3][0]); \
  oacc[0][1] = MFMA16(V0, pb1, oacc[0][1]); oacc[1][1] = MFMA16(V1, pb1, oacc[1][1]); \
  oacc[2][1] = MFMA16(V2, pb1, oacc[2][1]); oacc[3][1] = MFMA16(V3, pb1, oacc[3][1]); \
  oacc[0][2] = MFMA16(V0, pb2, oacc[0][2]); oacc[1][2] = MFMA16(V1, pb2, oacc[1][2]); \
  oacc[2][2] = MFMA16(V2, pb2, oacc[2][2]); oacc[3][2] = MFMA16(V3, pb2, oacc[3][2]); \
  oacc[0][3] = MFMA16(V0, pb3, oacc[0][3]); oacc[1][3] = MFMA16(V1, pb3, oacc[1][3]); \
  oacc[2][3] = MFMA16(V2, pb3, oacc[2][3]); oacc[3][3] = MFMA16(V3, pb3, oacc[3][3]); }

  #pragma unroll 1
  for (int mc = 0; mc < 4; ++mc) {
    // ---- s phase: 2 m-tiles x 2 q-tiles ----
    f32x16 sa0t0 = {}, sa0t1 = {}, sa1t0 = {}, sa1t1 = {};   // sa[qt2][t]
    #pragma unroll
    for (int t = 0; t < 2; ++t) {
      size_t gb = ((size_t)(b * 32 + mc * 8 + w * 2 + t) << 11) + lane * 8;
      bf16x8 Gh[4], Gl[4];
      #pragma unroll
      for (int s = 0; s < 4; ++s) {
        Gh[s] = *(const bf16x8*)(g_ + gb + (s << 9));
        Gl[s] = *(const bf16x8*)(gl_ + gb + (s << 9));
      }
      f32x16* s0 = t ? &sa0t1 : &sa0t0;
      f32x16* s1 = t ? &sa1t1 : &sa1t0;
      #pragma unroll
      for (int s = 0; s < 4; ++s) {
        *s0 = MFMA32(Gh[s], Fh[0][s], *s0);
        *s0 = MFMA32(Gh[s], Fl[0][s], *s0);
        *s0 = MFMA32(Gl[s], Fh[0][s], *s0);
        *s1 = MFMA32(Gh[s], Fh[1][s], *s1);
        *s1 = MFMA32(Gh[s], Fl[1][s], *s1);
        *s1 = MFMA32(Gl[s], Fh[1][s], *s1);
      }
    }

    bf16x8 va0, va1, va2, va3, vb0, vb1, vb2, vb3;
    LOADVA(0)   // hoisted: independent of softmax

    // ---- online softmax (per q-tile) ----
    float mx0 = -3.0e38f, mx1 = -3.0e38f;
    #pragma unroll
    for (int r = 0; r < 16; ++r) {
      mx0 = fmaxf(mx0, fmaxf(sa0t0[r], sa0t1[r]));
      mx1 = fmaxf(mx1, fmaxf(sa1t0[r], sa1t1[r]));
    }
    mx0 = fmaxf(mx0, __shfl_xor(mx0, 32));
    mx1 = fmaxf(mx1, __shfl_xor(mx1, 32));
    if (lane < 32) { redm[w][0][lane] = mx0; redm[w][1][lane] = mx1; }
    __syncthreads();
    float gmx0 = fmaxf(fmaxf(redm[0][0][q32], redm[1][0][q32]), fmaxf(redm[2][0][q32], redm[3][0][q32]));
    float gmx1 = fmaxf(fmaxf(redm[0][1][q32], redm[1][1][q32]), fmaxf(redm[2][1][q32], redm[3][1][q32]));
    float Mn0 = fmaxf(M0, gmx0), Mn1 = fmaxf(M1, gmx1);
    float rf0 = __expf(M0 - Mn0), rf1 = __expf(M1 - Mn1);
    M0 = Mn0; M1 = Mn1;
    float cs0 = 0.f, cs1 = 0.f;
    #pragma unroll
    for (int r = 0; r < 16; ++r) {
      float p;
      p = __expf(sa0t0[r] - Mn0); sa0t0[r] = p; cs0 += p;
      p = __expf(sa0t1[r] - Mn0); sa0t1[r] = p; cs0 += p;
      p = __expf(sa1t0[r] - Mn1); sa1t0[r] = p; cs1 += p;
      p = __expf(sa1t1[r] - Mn1); sa1t1[r] = p; cs1 += p;
    }
    cs0 += __shfl_xor(cs0, 32);
    cs1 += __shfl_xor(cs1, 32);
    if (lane < 32) { reds[w][0][lane] = cs0; reds[w][1][lane] = cs1; }

    // P writes: row = qt2*32+q32, m_local = w*64 + t*32 + j*8 + hl*4
    #pragma unroll
    for (int j = 0; j < 4; ++j) {
      uint2 pk;
      pk.x = (unsigned)f2bf(sa0t0[4*j+0]) | ((unsigned)f2bf(sa0t0[4*j+1]) << 16);
      pk.y = (unsigned)f2bf(sa0t0[4*j+2]) | ((unsigned)f2bf(sa0t0[4*j+3]) << 16);
      *(uint2*)&PB[q32 * PROW + w * 64 + j * 8 + hl * 4] = pk;
      pk.x = (unsigned)f2bf(sa0t1[4*j+0]) | ((unsigned)f2bf(sa0t1[4*j+1]) << 16);
      pk.y = (unsigned)f2bf(sa0t1[4*j+2]) | ((unsigned)f2bf(sa0t1[4*j+3]) << 16);
      *(uint2*)&PB[q32 * PROW + w * 64 + 32 + j * 8 + hl * 4] = pk;
      pk.x = (unsigned)f2bf(sa1t0[4*j+0]) | ((unsigned)f2bf(sa1t0[4*j+1]) << 16);
      pk.y = (unsigned)f2bf(sa1t0[4*j+2]) | ((unsigned)f2bf(sa1t0[4*j+3]) << 16);
      *(uint2*)&PB[(32 + q32) * PROW + w * 64 + j * 8 + hl * 4] = pk;
      pk.x = (unsigned)f2bf(sa1t1[4*j+0]) | ((unsigned)f2bf(sa1t1[4*j+1]) << 16);
      pk.y = (unsigned)f2bf(sa1t1[4*j+2]) | ((unsigned)f2bf(sa1t1[4*j+3]) << 16);
      *(uint2*)&PB[(32 + q32) * PROW + w * 64 + 32 + j * 8 + hl * 4] = pk;
    }
    __syncthreads();
    float ct0 = reds[0][0][q32] + reds[1][0][q32] + reds[2][0][q32] + reds[3][0][q32];
    float ct1 = reds[0][1][q32] + reds[1][1][q32] + reds[2][1][q32] + reds[3][1][q32];
    if (w == 0 && lane < 32) {
      Srow[lane]      = (mc == 0) ? ct0 : Srow[lane]      * rf0 + ct0;
      Srow[32 + lane] = (mc == 0) ? ct1 : Srow[32 + lane] * rf1 + ct1;
      rfrow[lane] = rf0; rfrow[32 + lane] = rf1;
    }
    __syncthreads();

    // ---- PV over this chunk ----
    if (mc > 0) {
      float rfq[4];
      #pragma unroll
      for (int qs = 0; qs < 4; ++qs) rfq[qs] = rfrow[qs * 16 + q16];
      #pragma unroll
      for (int c4 = 0; c4 < 4; ++c4)
        #pragma unroll
        for (int qs = 0; qs < 4; ++qs) oacc[c4][qs] *= rfq[qs];
    }
    LOADVB(1)
    #pragma unroll
    for (int kp = 0; kp < 4; ++kp) {
      PVMFMA(2 * kp, va0, va1, va2, va3)
      if (2 * kp + 2 < 8) LOADVA(2 * kp + 2)
      PVMFMA(2 * kp + 1, vb0, vb1, vb2, vb3)
      if (2 * kp + 3 < 8) LOADVB(2 * kp + 3)
    }
  }

  // ---- epilogue: stage into PB (obuf[n 64][cv 256], stride PROW), then 16B/lane block write ----
  __syncthreads();
  float rinv[4];
  #pragma unroll
  for (int qs = 0; qs < 4; ++qs) rinv[qs] = 1.0f / Srow[qs * 16 + q16];
  #pragma unroll
  for (int c4 = 0; c4 < 4; ++c4)
    #pragma unroll
    for (int qs = 0; qs < 4; ++qs) {
      uint2 pk;
      pk.x = (unsigned)f2bf(oacc[c4][qs][0] * rinv[qs]) | ((unsigned)f2bf(oacc[c4][qs][1] * rinv[qs]) << 16);
      pk.y = (unsigned)f2bf(oacc[c4][qs][2] * rinv[qs]) | ((unsigned)f2bf(oacc[c4][qs][3] * rinv[qs]) << 16);
      *(uint2*)&PB[(qs * 16 + q16) * PROW + w * 64 + c4 * 16 + qt * 4] = pk;
    }
  __syncthreads();
  const size_t obase = (size_t)(b * 256 + bx * 4) * 4096;
  #pragma unroll
  for (int it = 0; it < 8; ++it) {
    int u = it * 256 + tid;      // 16B unit
    int so = u * 8;              // shorts
    int ntl = so >> 12;
    int rem = so & 4095;
    int ks = rem >> 9;
    int slot = (rem >> 3) & 63;
    int qq = slot & 15, cg = slot >> 4;
    uint4 val = *(const uint4*)&PB[(ntl * 16 + qq) * PROW + ks * 32 + cg * 8];
    *(uint4*)(oT + obase + so) = val;
  }
}

// ---------- final conv: FM A (oT) and FM W, XCD-local b ----------

__global__ __launch_bounds__(256)
void conv_final(const unsigned short* __restrict__ A, const unsigned short* __restrict__ W,
                const float* __restrict__ bias, float* __restrict__ out,
                const float* __restrict__ resid, const float* __restrict__ gamma_p)
{
  const int bid = blockIdx.x;
  const int b = bid & 7;
  const int idx = bid >> 3;
  const int n0 = (idx & 31) * 128;
  const int oc0 = (idx >> 5) * 128;
  const int tid = threadIdx.x, w = tid >> 6, lane = tid & 63, q = lane & 15, qt = lane >> 4;

  f32x4 acc[2][8];
  #pragma unroll
  for (int nt = 0; nt < 2; ++nt)
    #pragma unroll
    for (int ot = 0; ot < 8; ++ot) acc[nt][ot] = (f32x4){0.f, 0.f, 0.f, 0.f};

  #pragma unroll
  for (int ks = 0; ks < 8; ++ks) {
    bf16x8 A_[2], B_[8];
    #pragma unroll
    for (int nt = 0; nt < 2; ++nt)
      A_[nt] = *(const bf16x8*)(A + (((size_t)(b * 256 + (n0 >> 4) + w * 2 + nt) * 8 + ks) << 9) + lane * 8);
    #pragma unroll
    for (int ot = 0; ot < 8; ++ot)
      B_[ot] = *(const bf16x8*)(W + (((size_t)((oc0 >> 4) + ot) * 8 + ks) << 9) + lane * 8);
    #pragma unroll
    for (int nt = 0; nt < 2; ++nt)
      #pragma unroll
      for (int ot = 0; ot < 8; ++ot)
        acc[nt][ot] = MFMA16(A_[nt], B_[ot], acc[nt][ot]);
  }

  const float gm = gamma_p[0];
  #pragma unroll
  for (int ot = 0; ot < 8; ++ot) {
    int oc = oc0 + ot * 16 + q;
    float bs = bias[oc];
    #pragma unroll
    for (int nt = 0; nt < 2; ++nt) {
      int n = n0 + w * 32 + nt * 16 + qt * 4;
      size_t o = ((size_t)(b * 512) + oc) * 4096 + n;
      float4 rs = *(const float4*)&resid[o];
      float4 ov;
      ov.x = gm * (acc[nt][ot][0] + bs) + rs.x;
      ov.y = gm * (acc[nt][ot][1] + bs) + rs.y;
      ov.z = gm * (acc[nt][ot][2] + bs) + rs.z;
      ov.w = gm * (acc[nt][ot][3] + bs) + rs.w;
      *(float4*)&out[o] = ov;
    }
  }
}

// ---------- launch ----------

extern "C" void kernel_launch(void* const* d_in, const int* in_sizes, int n_in,
                              void* d_out, int out_size, void* d_ws, size_t ws_size,
                              hipStream_t stream) {
  const float* x     = (const float*)d_in[0];
  const float* Wf    = (const float*)d_in[1];
  const float* bf    = (const float*)d_in[2];
  const float* Wg    = (const float*)d_in[3];
  const float* bg    = (const float*)d_in[4];
  const float* Wh    = (const float*)d_in[5];
  const float* bh    = (const float*)d_in[6];
  const float* Wv    = (const float*)d_in[7];
  const float* bv    = (const float*)d_in[8];
  const float* gamma = (const float*)d_in[9];
  float* out = (float*)d_out;
  char* w = (char*)d_ws;

  unsigned short* fhi = (unsigned short*)(w);                 // 4 MB  FM [8][128][4][512]
  unsigned short* flo = (unsigned short*)(w + 4194304);       // 4 MB
  unsigned short* ghi = (unsigned short*)(w + 8388608);       // 1 MB  FM [8][32][4][512]
  unsigned short* glo = (unsigned short*)(w + 9437184);       // 1 MB
  unsigned short* vp  = (unsigned short*)(w + 10485760);      // 4 MB  FM [8][16][32][512]
  unsigned short* oT  = (unsigned short*)(w + 14680064);      // 16 MB FM [8][256][8][512]
  unsigned short* wfh = (unsigned short*)(w + 31457280);      // 64 KB FM
  unsigned short* wfl = (unsigned short*)(w + 31522816);
  unsigned short* wgh = (unsigned short*)(w + 31588352);
  unsigned short* wgl = (unsigned short*)(w + 31653888);
  unsigned short* whb = (unsigned short*)(w + 31719424);      // 256 KB FM
  unsigned short* wvb = (unsigned short*)(w + 31981568);      // 256 KB FM

  prep_k<<<1280, 256, 0, stream>>>(Wf, Wg, Wh, Wv, wfh, wfl, wgh, wgl, whb, wvb);

  conv_all<<<512, 256, 0, stream>>>(x, wfh, wfl, wgh, wgl, whb,
                                    bf, bg, bh, fhi, flo, ghi, glo, vp);

  attn_mfma<<<512, 256, 0, stream>>>(fhi, flo, ghi, glo, vp, oT);

  conv_final<<<1024, 256, 0, stream>>>(oT, wvb, bv, out, x, gamma);
}

// Round 10
// 111.748 us; speedup vs baseline: 2.5903x; 1.0371x over previous
//
#include <hip/hip_runtime.h>
#include <cstddef>

typedef __attribute__((ext_vector_type(4))) float f32x4;
typedef __attribute__((ext_vector_type(16))) float f32x16;
typedef __attribute__((ext_vector_type(8))) short bf16x8;

#define MFMA16(A, B, C) __builtin_amdgcn_mfma_f32_16x16x32_bf16(A, B, C, 0, 0, 0)
#define MFMA32(A, B, C) __builtin_amdgcn_mfma_f32_32x32x16_bf16(A, B, C, 0, 0, 0)

__device__ __forceinline__ unsigned short f2bf(float f) {
  unsigned u = __float_as_uint(f);
  u += 0x7fffu + ((u >> 16) & 1u);
  return (unsigned short)(u >> 16);
}
__device__ __forceinline__ float bf2f(unsigned short s) {
  return __uint_as_float(((unsigned)s) << 16);
}

__device__ __forceinline__ void cvt_split8(float4 a, float4 b, bf16x8* H, bf16x8* L) {
  float v[8] = {a.x, a.y, a.z, a.w, b.x, b.y, b.z, b.w};
  unsigned hh[4], ll[4];
  #pragma unroll
  for (int p = 0; p < 4; ++p) {
    unsigned short h0 = f2bf(v[2 * p]), h1 = f2bf(v[2 * p + 1]);
    hh[p] = (unsigned)h0 | ((unsigned)h1 << 16);
    unsigned short l0 = f2bf(v[2 * p] - bf2f(h0));
    unsigned short l1 = f2bf(v[2 * p + 1] - bf2f(h1));
    ll[p] = (unsigned)l0 | ((unsigned)l1 << 16);
  }
  uint4 uh; uh.x = hh[0]; uh.y = hh[1]; uh.z = hh[2]; uh.w = hh[3];
  uint4 ul; ul.x = ll[0]; ul.y = ll[1]; ul.z = ll[2]; ul.w = ll[3];
  *H = *(bf16x8*)&uh;
  *L = *(bf16x8*)&ul;
}

__device__ __forceinline__ bf16x8 cvt_hi8(float4 a, float4 b) {
  float v[8] = {a.x, a.y, a.z, a.w, b.x, b.y, b.z, b.w};
  unsigned hh[4];
  #pragma unroll
  for (int p = 0; p < 4; ++p)
    hh[p] = (unsigned)f2bf(v[2 * p]) | ((unsigned)f2bf(v[2 * p + 1]) << 16);
  uint4 uh; uh.x = hh[0]; uh.y = hh[1]; uh.z = hh[2]; uh.w = hh[3];
  return *(bf16x8*)&uh;
}

// ---------- weight prep: fragment-major (FM) ----------

__global__ void prep_k(const float* __restrict__ Wf, const float* __restrict__ Wg,
                       const float* __restrict__ Wh, const float* __restrict__ Wv,
                       unsigned short* __restrict__ wfh, unsigned short* __restrict__ wfl,
                       unsigned short* __restrict__ wgh, unsigned short* __restrict__ wgl,
                       unsigned short* __restrict__ whb, unsigned short* __restrict__ wvb) {
  int i = blockIdx.x * 256 + threadIdx.x;
  if (i < 65536) {
    int ii = i & 32767;
    int j = ii & 7, slot = (ii >> 3) & 63, q = slot & 15, qt2 = slot >> 4;
    int kt = (ii >> 9) & 15, oct = ii >> 13;
    const float* src = (i < 32768) ? Wf : Wg;
    unsigned short* dh = (i < 32768) ? wfh : wgh;
    unsigned short* dl = (i < 32768) ? wfl : wgl;
    float v = src[(oct * 16 + q) * 512 + kt * 32 + qt2 * 8 + j];
    unsigned short h = f2bf(v);
    dh[ii] = h; dl[ii] = f2bf(v - bf2f(h));
  } else if (i < 196608) {
    int ii = i - 65536;
    int j = ii & 7, slot = (ii >> 3) & 63, q = slot & 15, qt2 = slot >> 4;
    int kt = (ii >> 9) & 15, oct = ii >> 13;
    whb[ii] = f2bf(Wh[(oct * 16 + q) * 512 + kt * 32 + qt2 * 8 + j]);
  } else if (i < 327680) {
    int ii = i - 196608;
    int j = ii & 7, slot = (ii >> 3) & 63, q = slot & 15, qt2 = slot >> 4;
    int kt = (ii >> 9) & 7, oct = ii >> 12;
    wvb[ii] = f2bf(Wv[(oct * 16 + q) * 256 + kt * 32 + qt2 * 8 + j]);
  }
}

// ---------- conv_all: 2 roles (0 = f+g fused split, 1 = v 256oc), XCD-local b ----------
// K-chunk = 64 (8 chunks): dbuf LDS [2][128][65] fp32 (66.5 KB), prefetch cover ~1 chunk.

#define LOADX64(CN) { _Pragma("unroll") \
  for (int t_ = 0; t_ < 32; ++t_) vv[t_] = xbase[(size_t)((CN) * 64 + kq + t_) * 4096]; }
#define STOREX64(BUF) { _Pragma("unroll") \
  for (int i_ = 0; i_ < 8; ++i_) { \
    float4 wv_; wv_.x = vv[4*i_]; wv_.y = vv[4*i_+1]; wv_.z = vv[4*i_+2]; wv_.w = vv[4*i_+3]; \
    *(float4*)&xs[BUF][nloc][kq + 4 * i_] = wv_; } }

__global__ __launch_bounds__(256, 2)
void conv_all(const float* __restrict__ x,
              const unsigned short* __restrict__ wfh_, const unsigned short* __restrict__ wfl_,
              const unsigned short* __restrict__ wgh_, const unsigned short* __restrict__ wgl_,
              const unsigned short* __restrict__ whb_,
              const float* __restrict__ bf_, const float* __restrict__ bg_,
              const float* __restrict__ bh_,
              unsigned short* __restrict__ fhi, unsigned short* __restrict__ flo,
              unsigned short* __restrict__ ghi, unsigned short* __restrict__ glo,
              unsigned short* __restrict__ vp)
{
  __shared__ __align__(16) float xs[2][128][65];    // 66,560 B
  const int bid = blockIdx.x;
  const int b = bid & 7;
  const int idx = bid >> 3;
  const int role = idx & 1;
  const int hp = idx >> 1;
  const int n0 = hp * 128;
  const int tid = threadIdx.x, w = tid >> 6, lane = tid & 63, q = lane & 15, qt = lane >> 4;
  const int nloc = tid & 127;
  const int kq = (tid >> 7) * 32;
  const float* xbase = x + (size_t)(b * 512) * 4096 + n0 + nloc;
  float vv[32];

  if (role == 0) {
    f32x4 accf[2][4], accg[2][4];
    #pragma unroll
    for (int nt = 0; nt < 2; ++nt)
      #pragma unroll
      for (int ot = 0; ot < 4; ++ot) {
        accf[nt][ot] = (f32x4){0.f, 0.f, 0.f, 0.f};
        accg[nt][ot] = (f32x4){0.f, 0.f, 0.f, 0.f};
      }
    LOADX64(0) STOREX64(0)
    __syncthreads();
    for (int cc = 0; cc < 8; ++cc) {
      const int cur = cc & 1;
      if (cc < 7) LOADX64(cc + 1)
      #pragma unroll
      for (int kh = 0; kh < 2; ++kh) {
        const int kt = cc * 2 + kh;
        bf16x8 Ah[2], Al[2];
        #pragma unroll
        for (int nt = 0; nt < 2; ++nt) {
          int row = w * 32 + nt * 16 + q;
          float4 a0 = *(const float4*)&xs[cur][row][kh * 32 + qt * 8];
          float4 a1 = *(const float4*)&xs[cur][row][kh * 32 + qt * 8 + 4];
          cvt_split8(a0, a1, &Ah[nt], &Al[nt]);
        }
        {
          bf16x8 Bh[4], Bl[4];
          #pragma unroll
          for (int ot = 0; ot < 4; ++ot) {
            size_t wb = ((size_t)(ot * 16 + kt) << 9) + lane * 8;
            Bh[ot] = *(const bf16x8*)(wfh_ + wb);
            Bl[ot] = *(const bf16x8*)(wfl_ + wb);
          }
          #pragma unroll
          for (int nt = 0; nt < 2; ++nt)
            #pragma unroll
            for (int ot = 0; ot < 4; ++ot) {
              accf[nt][ot] = MFMA16(Ah[nt], Bh[ot], accf[nt][ot]);
              accf[nt][ot] = MFMA16(Ah[nt], Bl[ot], accf[nt][ot]);
              accf[nt][ot] = MFMA16(Al[nt], Bh[ot], accf[nt][ot]);
            }
        }
        {
          bf16x8 Bh[4], Bl[4];
          #pragma unroll
          for (int ot = 0; ot < 4; ++ot) {
            size_t wb = ((size_t)(ot * 16 + kt) << 9) + lane * 8;
            Bh[ot] = *(const bf16x8*)(wgh_ + wb);
            Bl[ot] = *(const bf16x8*)(wgl_ + wb);
          }
          #pragma unroll
          for (int nt = 0; nt < 2; ++nt)
            #pragma unroll
            for (int ot = 0; ot < 4; ++ot) {
              accg[nt][ot] = MFMA16(Ah[nt], Bh[ot], accg[nt][ot]);
              accg[nt][ot] = MFMA16(Ah[nt], Bl[ot], accg[nt][ot]);
              accg[nt][ot] = MFMA16(Al[nt], Bh[ot], accg[nt][ot]);
            }
        }
      }
      if (cc < 7) STOREX64(cur ^ 1)
      __syncthreads();
    }
    // f epilogue: FM for attn MFMA32-B
    #pragma unroll
    for (int nt = 0; nt < 2; ++nt)
      #pragma unroll
      for (int ot = 0; ot < 4; ++ot)
        #pragma unroll
        for (int r = 0; r < 4; ++r) {
          float v = accf[nt][ot][r] + bf_[ot * 16 + q];
          unsigned short h = f2bf(v);
          size_t o = (((size_t)(b * 128 + hp * 4 + w) * 4 + ot) * 64 +
                      (q >> 3) * 32 + nt * 16 + qt * 4 + r) * 8 + (q & 7);
          fhi[o] = h;
          flo[o] = f2bf(v - bf2f(h));
        }
    // g epilogue: pool via LDS -> FM for attn MFMA32-A
    float (*pl)[67] = (float(*)[67])&xs[0][0][0];
    #pragma unroll
    for (int nt = 0; nt < 2; ++nt)
      #pragma unroll
      for (int ot = 0; ot < 4; ++ot)
        #pragma unroll
        for (int r = 0; r < 4; ++r)
          pl[w * 32 + nt * 16 + qt * 4 + r][ot * 16 + q] = accg[nt][ot][r];
    __syncthreads();
    const int c = tid & 63;
    #pragma unroll
    for (int it = 0; it < 8; ++it) {
      int wp = (tid >> 6) + it * 4;
      float v = fmaxf(fmaxf(pl[2 * wp][c], pl[2 * wp + 1][c]),
                      fmaxf(pl[64 + 2 * wp][c], pl[65 + 2 * wp][c])) + bg_[c];
      unsigned short h = f2bf(v);
      size_t o = (((size_t)(b * 32 + hp) * 4 + (c >> 4)) * 64 +
                  ((c >> 3) & 1) * 32 + wp) * 8 + (c & 7);
      ghi[o] = h;
      glo[o] = f2bf(v - bf2f(h));
    }
  } else {
    f32x4 acc[2][16];
    #pragma unroll
    for (int nt = 0; nt < 2; ++nt)
      #pragma unroll
      for (int ot = 0; ot < 16; ++ot) acc[nt][ot] = (f32x4){0.f, 0.f, 0.f, 0.f};
    LOADX64(0) STOREX64(0)
    __syncthreads();
    for (int cc = 0; cc < 8; ++cc) {
      const int cur = cc & 1;
      if (cc < 7) LOADX64(cc + 1)
      #pragma unroll
      for (int kh = 0; kh < 2; ++kh) {
        const int kt = cc * 2 + kh;
        bf16x8 A_[2];
        #pragma unroll
        for (int nt = 0; nt < 2; ++nt) {
          int row = w * 32 + nt * 16 + q;
          float4 a0 = *(const float4*)&xs[cur][row][kh * 32 + qt * 8];
          float4 a1 = *(const float4*)&xs[cur][row][kh * 32 + qt * 8 + 4];
          A_[nt] = cvt_hi8(a0, a1);
        }
        #pragma unroll
        for (int oh = 0; oh < 2; ++oh) {
          bf16x8 B_[8];
          #pragma unroll
          for (int ot = 0; ot < 8; ++ot)
            B_[ot] = *(const bf16x8*)(whb_ + ((size_t)((oh * 8 + ot) * 16 + kt) << 9) + lane * 8);
          #pragma unroll
          for (int nt = 0; nt < 2; ++nt)
            #pragma unroll
            for (int ot = 0; ot < 8; ++ot)
              acc[nt][oh * 8 + ot] = MFMA16(A_[nt], B_[ot], acc[nt][oh * 8 + ot]);
        }
      }
      if (cc < 7) STOREX64(cur ^ 1)
      __syncthreads();
    }
    float (*pl)[67] = (float(*)[67])&xs[0][0][0];
    #pragma unroll
    for (int oh = 0; oh < 4; ++oh) {
      if (oh) __syncthreads();
      #pragma unroll
      for (int nt = 0; nt < 2; ++nt)
        #pragma unroll
        for (int ot4 = 0; ot4 < 4; ++ot4)
          #pragma unroll
          for (int r = 0; r < 4; ++r)
            pl[w * 32 + nt * 16 + qt * 4 + r][ot4 * 16 + q] = acc[nt][oh * 4 + ot4][r];
      __syncthreads();
      const int wp = tid & 31;
      #pragma unroll
      for (int it = 0; it < 8; ++it) {
        int cc2 = (tid >> 5) + it * 8;
        int cv = oh * 64 + cc2;
        float v = fmaxf(fmaxf(pl[2 * wp][cc2], pl[2 * wp + 1][cc2]),
                        fmaxf(pl[64 + 2 * wp][cc2], pl[65 + 2 * wp][cc2])) + bh_[cv];
        size_t o = (((size_t)(b * 16 + (cv >> 4)) * 32 + hp) * 64 +
                    (wp >> 3) * 16 + (cv & 15)) * 8 + (wp & 7);
        vp[o] = f2bf(v);
      }
    }
  }
}

// ---------- fused attention: QB=64, 4 m-chunks of 256, XCD-local b, setprio ----------

#define PROW 264

__global__ __launch_bounds__(256, 2)
void attn_mfma(const unsigned short* __restrict__ f_, const unsigned short* __restrict__ fl_,
               const unsigned short* __restrict__ g_, const unsigned short* __restrict__ gl_,
               const unsigned short* __restrict__ vp, unsigned short* __restrict__ oT)
{
  __shared__ __align__(16) unsigned short PB[64 * PROW];    // 33,792 B (P, then obuf)
  __shared__ float redm[4][2][32], reds[4][2][32];
  __shared__ float rfrow[64], Srow[64];
  const int b = blockIdx.x & 7, bx = blockIdx.x >> 3;
  const int tid = threadIdx.x, w = tid >> 6, lane = tid & 63;
  const int q32 = lane & 31, hl = lane >> 5;
  const int q16 = lane & 15, qt = lane >> 4;

  bf16x8 Fh[2][4], Fl[2][4];
  #pragma unroll
  for (int qt2 = 0; qt2 < 2; ++qt2) {
    size_t fb = ((size_t)(b * 128 + bx * 2 + qt2) << 11) + lane * 8;
    #pragma unroll
    for (int s = 0; s < 4; ++s) {
      Fh[qt2][s] = *(const bf16x8*)(f_ + fb + (s << 9));
      Fl[qt2][s] = *(const bf16x8*)(fl_ + fb + (s << 9));
    }
  }

  float M0 = -3.0e38f, M1 = -3.0e38f;
  f32x4 oacc[4][4];       // [c4][qsub]
  #pragma unroll
  for (int c4 = 0; c4 < 4; ++c4)
    #pragma unroll
    for (int qs = 0; qs < 4; ++qs) oacc[c4][qs] = (f32x4){0.f, 0.f, 0.f, 0.f};
  const size_t vroot = ((size_t)(b * 16 + w * 4) * 32) * 512 + lane * 8;

#define VLD(C4, KS) (*(const bf16x8*)(vp + vroot + ((size_t)((C4) * 32 + mc * 8 + (KS)) << 9)))
#define LOADVA(KS) { va0 = VLD(0, KS); va1 = VLD(1, KS); va2 = VLD(2, KS); va3 = VLD(3, KS); }
#define LOADVB(KS) { vb0 = VLD(0, KS); vb1 = VLD(1, KS); vb2 = VLD(2, KS); vb3 = VLD(3, KS); }
#define PVMFMA(KS, V0, V1, V2, V3) { \
  bf16x8 pb0 = *(const bf16x8*)&PB[q16 * PROW + (KS) * 32 + qt * 8]; \
  bf16x8 pb1 = *(const bf16x8*)&PB[(16 + q16) * PROW + (KS) * 32 + qt * 8]; \
  bf16x8 pb2 = *(const bf16x8*)&PB[(32 + q16) * PROW + (KS) * 32 + qt * 8]; \
  bf16x8 pb3 = *(const bf16x8*)&PB[(48 + q16) * PROW + (KS) * 32 + qt * 8]; \
  oacc[0][0] = MFMA16(V0, pb0, oacc[0][0]); oacc[1][0] = MFMA16(V1, pb0, oacc[1][0]); \
  oacc[2][0] = MFMA16(V2, pb0, oacc[2][0]); oacc[3][0] = MFMA16(V3, pb0, oacc[3][0]); \
  oacc[0][1] = MFMA16(V0, pb1, oacc[0][1]); oacc[1][1] = MFMA16(V1, pb1, oacc[1][1]); \
  oacc[2][1] = MFMA16(V2, pb1, oacc[2][1]); oacc[3][1] = MFMA16(V3, pb1, oacc[3][1]); \
  oacc[0][2] = MFMA16(V0, pb2, oacc[0][2]); oacc[1][2] = MFMA16(V1, pb2, oacc[1][2]); \
  oacc[2][2] = MFMA16(V2, pb2, oacc[2][2]); oacc[3][2] = MFMA16(V3, pb2, oacc[3][2]); \
  oacc[0][3] = MFMA16(V0, pb3, oacc[0][3]); oacc[1][3] = MFMA16(V1, pb3, oacc[1][3]); \
  oacc[2][3] = MFMA16(V2, pb3, oacc[2][3]); oacc[3][3] = MFMA16(V3, pb3, oacc[3][3]); }

  #pragma unroll 1
  for (int mc = 0; mc < 4; ++mc) {
    // ---- s phase: 2 m-tiles x 2 q-tiles ----
    f32x16 sa0t0 = {}, sa0t1 = {}, sa1t0 = {}, sa1t1 = {};
    __builtin_amdgcn_s_setprio(1);
    #pragma unroll
    for (int t = 0; t < 2; ++t) {
      size_t gb = ((size_t)(b * 32 + mc * 8 + w * 2 + t) << 11) + lane * 8;
      bf16x8 Gh[4], Gl[4];
      #pragma unroll
      for (int s = 0; s < 4; ++s) {
        Gh[s] = *(const bf16x8*)(g_ + gb + (s << 9));
        Gl[s] = *(const bf16x8*)(gl_ + gb + (s << 9));
      }
      f32x16* s0 = t ? &sa0t1 : &sa0t0;
      f32x16* s1 = t ? &sa1t1 : &sa1t0;
      #pragma unroll
      for (int s = 0; s < 4; ++s) {
        *s0 = MFMA32(Gh[s], Fh[0][s], *s0);
        *s0 = MFMA32(Gh[s], Fl[0][s], *s0);
        *s0 = MFMA32(Gl[s], Fh[0][s], *s0);
        *s1 = MFMA32(Gh[s], Fh[1][s], *s1);
        *s1 = MFMA32(Gh[s], Fl[1][s], *s1);
        *s1 = MFMA32(Gl[s], Fh[1][s], *s1);
      }
    }
    __builtin_amdgcn_s_setprio(0);

    bf16x8 va0, va1, va2, va3, vb0, vb1, vb2, vb3;
    LOADVA(0)   // hoisted: independent of softmax

    // ---- online softmax (per q-tile) ----
    float mx0 = -3.0e38f, mx1 = -3.0e38f;
    #pragma unroll
    for (int r = 0; r < 16; ++r) {
      mx0 = fmaxf(mx0, fmaxf(sa0t0[r], sa0t1[r]));
      mx1 = fmaxf(mx1, fmaxf(sa1t0[r], sa1t1[r]));
    }
    mx0 = fmaxf(mx0, __shfl_xor(mx0, 32));
    mx1 = fmaxf(mx1, __shfl_xor(mx1, 32));
    if (lane < 32) { redm[w][0][lane] = mx0; redm[w][1][lane] = mx1; }
    __syncthreads();
    float gmx0 = fmaxf(fmaxf(redm[0][0][q32], redm[1][0][q32]), fmaxf(redm[2][0][q32], redm[3][0][q32]));
    float gmx1 = fmaxf(fmaxf(redm[0][1][q32], redm[1][1][q32]), fmaxf(redm[2][1][q32], redm[3][1][q32]));
    float Mn0 = fmaxf(M0, gmx0), Mn1 = fmaxf(M1, gmx1);
    float rf0 = __expf(M0 - Mn0), rf1 = __expf(M1 - Mn1);
    M0 = Mn0; M1 = Mn1;
    float cs0 = 0.f, cs1 = 0.f;
    #pragma unroll
    for (int r = 0; r < 16; ++r) {
      float p;
      p = __expf(sa0t0[r] - Mn0); sa0t0[r] = p; cs0 += p;
      p = __expf(sa0t1[r] - Mn0); sa0t1[r] = p; cs0 += p;
      p = __expf(sa1t0[r] - Mn1); sa1t0[r] = p; cs1 += p;
      p = __expf(sa1t1[r] - Mn1); sa1t1[r] = p; cs1 += p;
    }
    cs0 += __shfl_xor(cs0, 32);
    cs1 += __shfl_xor(cs1, 32);
    if (lane < 32) { reds[w][0][lane] = cs0; reds[w][1][lane] = cs1; }

    #pragma unroll
    for (int j = 0; j < 4; ++j) {
      uint2 pk;
      pk.x = (unsigned)f2bf(sa0t0[4*j+0]) | ((unsigned)f2bf(sa0t0[4*j+1]) << 16);
      pk.y = (unsigned)f2bf(sa0t0[4*j+2]) | ((unsigned)f2bf(sa0t0[4*j+3]) << 16);
      *(uint2*)&PB[q32 * PROW + w * 64 + j * 8 + hl * 4] = pk;
      pk.x = (unsigned)f2bf(sa0t1[4*j+0]) | ((unsigned)f2bf(sa0t1[4*j+1]) << 16);
      pk.y = (unsigned)f2bf(sa0t1[4*j+2]) | ((unsigned)f2bf(sa0t1[4*j+3]) << 16);
      *(uint2*)&PB[q32 * PROW + w * 64 + 32 + j * 8 + hl * 4] = pk;
      pk.x = (unsigned)f2bf(sa1t0[4*j+0]) | ((unsigned)f2bf(sa1t0[4*j+1]) << 16);
      pk.y = (unsigned)f2bf(sa1t0[4*j+2]) | ((unsigned)f2bf(sa1t0[4*j+3]) << 16);
      *(uint2*)&PB[(32 + q32) * PROW + w * 64 + j * 8 + hl * 4] = pk;
      pk.x = (unsigned)f2bf(sa1t1[4*j+0]) | ((unsigned)f2bf(sa1t1[4*j+1]) << 16);
      pk.y = (unsigned)f2bf(sa1t1[4*j+2]) | ((unsigned)f2bf(sa1t1[4*j+3]) << 16);
      *(uint2*)&PB[(32 + q32) * PROW + w * 64 + 32 + j * 8 + hl * 4] = pk;
    }
    __syncthreads();
    float ct0 = reds[0][0][q32] + reds[1][0][q32] + reds[2][0][q32] + reds[3][0][q32];
    float ct1 = reds[0][1][q32] + reds[1][1][q32] + reds[2][1][q32] + reds[3][1][q32];
    if (w == 0 && lane < 32) {
      Srow[lane]      = (mc == 0) ? ct0 : Srow[lane]      * rf0 + ct0;
      Srow[32 + lane] = (mc == 0) ? ct1 : Srow[32 + lane] * rf1 + ct1;
      rfrow[lane] = rf0; rfrow[32 + lane] = rf1;
    }
    __syncthreads();

    // ---- PV over this chunk ----
    if (mc > 0) {
      float rfq[4];
      #pragma unroll
      for (int qs = 0; qs < 4; ++qs) rfq[qs] = rfrow[qs * 16 + q16];
      #pragma unroll
      for (int c4 = 0; c4 < 4; ++c4)
        #pragma unroll
        for (int qs = 0; qs < 4; ++qs) oacc[c4][qs] *= rfq[qs];
    }
    LOADVB(1)
    __builtin_amdgcn_s_setprio(1);
    #pragma unroll
    for (int kp = 0; kp < 4; ++kp) {
      PVMFMA(2 * kp, va0, va1, va2, va3)
      if (2 * kp + 2 < 8) LOADVA(2 * kp + 2)
      PVMFMA(2 * kp + 1, vb0, vb1, vb2, vb3)
      if (2 * kp + 3 < 8) LOADVB(2 * kp + 3)
    }
    __builtin_amdgcn_s_setprio(0);
  }

  // ---- epilogue: stage into PB (obuf[n 64][cv 256], stride PROW), then 16B/lane block write ----
  __syncthreads();
  float rinv[4];
  #pragma unroll
  for (int qs = 0; qs < 4; ++qs) rinv[qs] = 1.0f / Srow[qs * 16 + q16];
  #pragma unroll
  for (int c4 = 0; c4 < 4; ++c4)
    #pragma unroll
    for (int qs = 0; qs < 4; ++qs) {
      uint2 pk;
      pk.x = (unsigned)f2bf(oacc[c4][qs][0] * rinv[qs]) | ((unsigned)f2bf(oacc[c4][qs][1] * rinv[qs]) << 16);
      pk.y = (unsigned)f2bf(oacc[c4][qs][2] * rinv[qs]) | ((unsigned)f2bf(oacc[c4][qs][3] * rinv[qs]) << 16);
      *(uint2*)&PB[(qs * 16 + q16) * PROW + w * 64 + c4 * 16 + qt * 4] = pk;
    }
  __syncthreads();
  const size_t obase = (size_t)(b * 256 + bx * 4) * 4096;
  #pragma unroll
  for (int it = 0; it < 8; ++it) {
    int u = it * 256 + tid;      // 16B unit
    int so = u * 8;              // shorts
    int ntl = so >> 12;
    int rem = so & 4095;
    int ks = rem >> 9;
    int slot = (rem >> 3) & 63;
    int qq = slot & 15, cg = slot >> 4;
    uint4 val = *(const uint4*)&PB[(ntl * 16 + qq) * PROW + ks * 32 + cg * 8];
    *(uint4*)(oT + obase + so) = val;
  }
}

// ---------- final conv: FM A (oT) and FM W, XCD-local b ----------

__global__ __launch_bounds__(256)
void conv_final(const unsigned short* __restrict__ A, const unsigned short* __restrict__ W,
                const float* __restrict__ bias, float* __restrict__ out,
                const float* __restrict__ resid, const float* __restrict__ gamma_p)
{
  const int bid = blockIdx.x;
  const int b = bid & 7;
  const int idx = bid >> 3;
  const int n0 = (idx & 31) * 128;
  const int oc0 = (idx >> 5) * 128;
  const int tid = threadIdx.x, w = tid >> 6, lane = tid & 63, q = lane & 15, qt = lane >> 4;

  f32x4 acc[2][8];
  #pragma unroll
  for (int nt = 0; nt < 2; ++nt)
    #pragma unroll
    for (int ot = 0; ot < 8; ++ot) acc[nt][ot] = (f32x4){0.f, 0.f, 0.f, 0.f};

  #pragma unroll
  for (int ks = 0; ks < 8; ++ks) {
    bf16x8 A_[2], B_[8];
    #pragma unroll
    for (int nt = 0; nt < 2; ++nt)
      A_[nt] = *(const bf16x8*)(A + (((size_t)(b * 256 + (n0 >> 4) + w * 2 + nt) * 8 + ks) << 9) + lane * 8);
    #pragma unroll
    for (int ot = 0; ot < 8; ++ot)
      B_[ot] = *(const bf16x8*)(W + (((size_t)((oc0 >> 4) + ot) * 8 + ks) << 9) + lane * 8);
    #pragma unroll
    for (int nt = 0; nt < 2; ++nt)
      #pragma unroll
      for (int ot = 0; ot < 8; ++ot)
        acc[nt][ot] = MFMA16(A_[nt], B_[ot], acc[nt][ot]);
  }

  const float gm = gamma_p[0];
  #pragma unroll
  for (int ot = 0; ot < 8; ++ot) {
    int oc = oc0 + ot * 16 + q;
    float bs = bias[oc];
    #pragma unroll
    for (int nt = 0; nt < 2; ++nt) {
      int n = n0 + w * 32 + nt * 16 + qt * 4;
      size_t o = ((size_t)(b * 512) + oc) * 4096 + n;
      float4 rs = *(const float4*)&resid[o];
      float4 ov;
      ov.x = gm * (acc[nt][ot][0] + bs) + rs.x;
      ov.y = gm * (acc[nt][ot][1] + bs) + rs.y;
      ov.z = gm * (acc[nt][ot][2] + bs) + rs.z;
      ov.w = gm * (acc[nt][ot][3] + bs) + rs.w;
      *(float4*)&out[o] = ov;
    }
  }
}

// ---------- launch ----------

extern "C" void kernel_launch(void* const* d_in, const int* in_sizes, int n_in,
                              void* d_out, int out_size, void* d_ws, size_t ws_size,
                              hipStream_t stream) {
  const float* x     = (const float*)d_in[0];
  const float* Wf    = (const float*)d_in[1];
  const float* bf    = (const float*)d_in[2];
  const float* Wg    = (const float*)d_in[3];
  const float* bg    = (const float*)d_in[4];
  const float* Wh    = (const float*)d_in[5];
  const float* bh    = (const float*)d_in[6];
  const float* Wv    = (const float*)d_in[7];
  const float* bv    = (const float*)d_in[8];
  const float* gamma = (const float*)d_in[9];
  float* out = (float*)d_out;
  char* w = (char*)d_ws;

  unsigned short* fhi = (unsigned short*)(w);                 // 4 MB  FM [8][128][4][512]
  unsigned short* flo = (unsigned short*)(w + 4194304);       // 4 MB
  unsigned short* ghi = (unsigned short*)(w + 8388608);       // 1 MB  FM [8][32][4][512]
  unsigned short* glo = (unsigned short*)(w + 9437184);       // 1 MB
  unsigned short* vp  = (unsigned short*)(w + 10485760);      // 4 MB  FM [8][16][32][512]
  unsigned short* oT  = (unsigned short*)(w + 14680064);      // 16 MB FM [8][256][8][512]
  unsigned short* wfh = (unsigned short*)(w + 31457280);      // 64 KB FM
  unsigned short* wfl = (unsigned short*)(w + 31522816);
  unsigned short* wgh = (unsigned short*)(w + 31588352);
  unsigned short* wgl = (unsigned short*)(w + 31653888);
  unsigned short* whb = (unsigned short*)(w + 31719424);      // 256 KB FM
  unsigned short* wvb = (unsigned short*)(w + 31981568);      // 256 KB FM

  prep_k<<<1280, 256, 0, stream>>>(Wf, Wg, Wh, Wv, wfh, wfl, wgh, wgl, whb, wvb);

  conv_all<<<512, 256, 0, stream>>>(x, wfh, wfl, wgh, wgl, whb,
                                    bf, bg, bh, fhi, flo, ghi, glo, vp);

  attn_mfma<<<512, 256, 0, stream>>>(fhi, flo, ghi, glo, vp, oT);

  conv_final<<<1024, 256, 0, stream>>>(oT, wvb, bv, out, x, gamma);
}

// Round 11
// 111.682 us; speedup vs baseline: 2.5919x; 1.0006x over previous
//
#include <hip/hip_runtime.h>
#include <cstddef>

typedef __attribute__((ext_vector_type(4))) float f32x4;
typedef __attribute__((ext_vector_type(16))) float f32x16;
typedef __attribute__((ext_vector_type(8))) short bf16x8;

#define MFMA16(A, B, C) __builtin_amdgcn_mfma_f32_16x16x32_bf16(A, B, C, 0, 0, 0)
#define MFMA32(A, B, C) __builtin_amdgcn_mfma_f32_32x32x16_bf16(A, B, C, 0, 0, 0)

__device__ __forceinline__ unsigned short f2bf(float f) {
  unsigned u = __float_as_uint(f);
  u += 0x7fffu + ((u >> 16) & 1u);
  return (unsigned short)(u >> 16);
}
__device__ __forceinline__ float bf2f(unsigned short s) {
  return __uint_as_float(((unsigned)s) << 16);
}

__device__ __forceinline__ bf16x8 ldfrag(const unsigned short* p) {
  bf16x8 r;
  *(uint2*)&r = *(const uint2*)p;
  *((uint2*)&r + 1) = *(const uint2*)(p + 4);
  return r;
}

// ---------- weight prep: fragment-major (FM) ----------

__global__ void prep_k(const float* __restrict__ Wf, const float* __restrict__ Wg,
                       const float* __restrict__ Wh, const float* __restrict__ Wv,
                       unsigned short* __restrict__ wfh, unsigned short* __restrict__ wfl,
                       unsigned short* __restrict__ wgh, unsigned short* __restrict__ wgl,
                       unsigned short* __restrict__ whb, unsigned short* __restrict__ wvb) {
  int i = blockIdx.x * 256 + threadIdx.x;
  if (i < 65536) {
    int ii = i & 32767;
    int j = ii & 7, slot = (ii >> 3) & 63, q = slot & 15, qt2 = slot >> 4;
    int kt = (ii >> 9) & 15, oct = ii >> 13;
    const float* src = (i < 32768) ? Wf : Wg;
    unsigned short* dh = (i < 32768) ? wfh : wgh;
    unsigned short* dl = (i < 32768) ? wfl : wgl;
    float v = src[(oct * 16 + q) * 512 + kt * 32 + qt2 * 8 + j];
    unsigned short h = f2bf(v);
    dh[ii] = h; dl[ii] = f2bf(v - bf2f(h));
  } else if (i < 196608) {
    int ii = i - 65536;
    int j = ii & 7, slot = (ii >> 3) & 63, q = slot & 15, qt2 = slot >> 4;
    int kt = (ii >> 9) & 15, oct = ii >> 13;
    whb[ii] = f2bf(Wh[(oct * 16 + q) * 512 + kt * 32 + qt2 * 8 + j]);
  } else if (i < 327680) {
    int ii = i - 196608;
    int j = ii & 7, slot = (ii >> 3) & 63, q = slot & 15, qt2 = slot >> 4;
    int kt = (ii >> 9) & 7, oct = ii >> 12;
    wvb[ii] = f2bf(Wv[(oct * 16 + q) * 256 + kt * 32 + qt2 * 8 + j]);
  }
}

// ---------- conv_all: 2 roles (0 = f+g fused split, 1 = v 256oc), XCD-local b ----------
// Staging: pre-split bf16 hi/lo planes in LDS (cvt at STAGE time, off the MFMA path).
// sbuf[buf][hi/lo][128 n][68 k-shorts] -> 69,632 B.

#define SP 68

#define LOADX64(CN) { _Pragma("unroll") \
  for (int t_ = 0; t_ < 32; ++t_) vv[t_] = xbase[(size_t)((CN) * 64 + kq + t_) * 4096]; }

#define CVTSTORE2(BUF) { _Pragma("unroll") \
  for (int i_ = 0; i_ < 8; ++i_) { \
    unsigned short h0 = f2bf(vv[4*i_]),   h1 = f2bf(vv[4*i_+1]); \
    unsigned short h2 = f2bf(vv[4*i_+2]), h3 = f2bf(vv[4*i_+3]); \
    uint2 ph, pl2; \
    ph.x = (unsigned)h0 | ((unsigned)h1 << 16); \
    ph.y = (unsigned)h2 | ((unsigned)h3 << 16); \
    pl2.x = (unsigned)f2bf(vv[4*i_]   - bf2f(h0)) | ((unsigned)f2bf(vv[4*i_+1] - bf2f(h1)) << 16); \
    pl2.y = (unsigned)f2bf(vv[4*i_+2] - bf2f(h2)) | ((unsigned)f2bf(vv[4*i_+3] - bf2f(h3)) << 16); \
    *(uint2*)&sbuf[BUF][0][nloc][kq + 4*i_] = ph; \
    *(uint2*)&sbuf[BUF][1][nloc][kq + 4*i_] = pl2; } }

#define CVTSTORE1(BUF) { _Pragma("unroll") \
  for (int i_ = 0; i_ < 8; ++i_) { \
    uint2 ph; \
    ph.x = (unsigned)f2bf(vv[4*i_])   | ((unsigned)f2bf(vv[4*i_+1]) << 16); \
    ph.y = (unsigned)f2bf(vv[4*i_+2]) | ((unsigned)f2bf(vv[4*i_+3]) << 16); \
    *(uint2*)&sbuf[BUF][0][nloc][kq + 4*i_] = ph; } }

__global__ __launch_bounds__(256, 2)
void conv_all(const float* __restrict__ x,
              const unsigned short* __restrict__ wfh_, const unsigned short* __restrict__ wfl_,
              const unsigned short* __restrict__ wgh_, const unsigned short* __restrict__ wgl_,
              const unsigned short* __restrict__ whb_,
              const float* __restrict__ bf_, const float* __restrict__ bg_,
              const float* __restrict__ bh_,
              unsigned short* __restrict__ fhi, unsigned short* __restrict__ flo,
              unsigned short* __restrict__ ghi, unsigned short* __restrict__ glo,
              unsigned short* __restrict__ vp)
{
  __shared__ __align__(16) unsigned short sbuf[2][2][128][SP];   // 69,632 B
  const int bid = blockIdx.x;
  const int b = bid & 7;
  const int idx = bid >> 3;
  const int role = idx & 1;
  const int hp = idx >> 1;
  const int n0 = hp * 128;
  const int tid = threadIdx.x, w = tid >> 6, lane = tid & 63, q = lane & 15, qt = lane >> 4;
  const int nloc = tid & 127;
  const int kq = (tid >> 7) * 32;
  const float* xbase = x + (size_t)(b * 512) * 4096 + n0 + nloc;
  float vv[32];

  if (role == 0) {
    f32x4 accf[2][4], accg[2][4];
    #pragma unroll
    for (int nt = 0; nt < 2; ++nt)
      #pragma unroll
      for (int ot = 0; ot < 4; ++ot) {
        accf[nt][ot] = (f32x4){0.f, 0.f, 0.f, 0.f};
        accg[nt][ot] = (f32x4){0.f, 0.f, 0.f, 0.f};
      }
    LOADX64(0) CVTSTORE2(0)
    __syncthreads();
    for (int cc = 0; cc < 8; ++cc) {
      const int cur = cc & 1;
      if (cc < 7) LOADX64(cc + 1)
      #pragma unroll
      for (int kh = 0; kh < 2; ++kh) {
        const int kt = cc * 2 + kh;
        bf16x8 Ah[2], Al[2];
        #pragma unroll
        for (int nt = 0; nt < 2; ++nt) {
          int row = w * 32 + nt * 16 + q;
          Ah[nt] = ldfrag(&sbuf[cur][0][row][kh * 32 + qt * 8]);
          Al[nt] = ldfrag(&sbuf[cur][1][row][kh * 32 + qt * 8]);
        }
        {
          bf16x8 Bh[4], Bl[4];
          #pragma unroll
          for (int ot = 0; ot < 4; ++ot) {
            size_t wb = ((size_t)(ot * 16 + kt) << 9) + lane * 8;
            Bh[ot] = *(const bf16x8*)(wfh_ + wb);
            Bl[ot] = *(const bf16x8*)(wfl_ + wb);
          }
          #pragma unroll
          for (int nt = 0; nt < 2; ++nt)
            #pragma unroll
            for (int ot = 0; ot < 4; ++ot) {
              accf[nt][ot] = MFMA16(Ah[nt], Bh[ot], accf[nt][ot]);
              accf[nt][ot] = MFMA16(Ah[nt], Bl[ot], accf[nt][ot]);
              accf[nt][ot] = MFMA16(Al[nt], Bh[ot], accf[nt][ot]);
            }
        }
        {
          bf16x8 Bh[4], Bl[4];
          #pragma unroll
          for (int ot = 0; ot < 4; ++ot) {
            size_t wb = ((size_t)(ot * 16 + kt) << 9) + lane * 8;
            Bh[ot] = *(const bf16x8*)(wgh_ + wb);
            Bl[ot] = *(const bf16x8*)(wgl_ + wb);
          }
          #pragma unroll
          for (int nt = 0; nt < 2; ++nt)
            #pragma unroll
            for (int ot = 0; ot < 4; ++ot) {
              accg[nt][ot] = MFMA16(Ah[nt], Bh[ot], accg[nt][ot]);
              accg[nt][ot] = MFMA16(Ah[nt], Bl[ot], accg[nt][ot]);
              accg[nt][ot] = MFMA16(Al[nt], Bh[ot], accg[nt][ot]);
            }
        }
      }
      if (cc < 7) CVTSTORE2(cur ^ 1)
      __syncthreads();
    }
    // f epilogue: FM for attn MFMA32-B
    #pragma unroll
    for (int nt = 0; nt < 2; ++nt)
      #pragma unroll
      for (int ot = 0; ot < 4; ++ot)
        #pragma unroll
        for (int r = 0; r < 4; ++r) {
          float v = accf[nt][ot][r] + bf_[ot * 16 + q];
          unsigned short h = f2bf(v);
          size_t o = (((size_t)(b * 128 + hp * 4 + w) * 4 + ot) * 64 +
                      (q >> 3) * 32 + nt * 16 + qt * 4 + r) * 8 + (q & 7);
          fhi[o] = h;
          flo[o] = f2bf(v - bf2f(h));
        }
    // g epilogue: pool via LDS -> FM for attn MFMA32-A
    float (*pl)[67] = (float(*)[67])&sbuf[0][0][0][0];
    __syncthreads();
    #pragma unroll
    for (int nt = 0; nt < 2; ++nt)
      #pragma unroll
      for (int ot = 0; ot < 4; ++ot)
        #pragma unroll
        for (int r = 0; r < 4; ++r)
          pl[w * 32 + nt * 16 + qt * 4 + r][ot * 16 + q] = accg[nt][ot][r];
    __syncthreads();
    const int c = tid & 63;
    #pragma unroll
    for (int it = 0; it < 8; ++it) {
      int wp = (tid >> 6) + it * 4;
      float v = fmaxf(fmaxf(pl[2 * wp][c], pl[2 * wp + 1][c]),
                      fmaxf(pl[64 + 2 * wp][c], pl[65 + 2 * wp][c])) + bg_[c];
      unsigned short h = f2bf(v);
      size_t o = (((size_t)(b * 32 + hp) * 4 + (c >> 4)) * 64 +
                  ((c >> 3) & 1) * 32 + wp) * 8 + (c & 7);
      ghi[o] = h;
      glo[o] = f2bf(v - bf2f(h));
    }
  } else {
    f32x4 acc[2][16];
    #pragma unroll
    for (int nt = 0; nt < 2; ++nt)
      #pragma unroll
      for (int ot = 0; ot < 16; ++ot) acc[nt][ot] = (f32x4){0.f, 0.f, 0.f, 0.f};
    LOADX64(0) CVTSTORE1(0)
    __syncthreads();
    for (int cc = 0; cc < 8; ++cc) {
      const int cur = cc & 1;
      if (cc < 7) LOADX64(cc + 1)
      #pragma unroll
      for (int kh = 0; kh < 2; ++kh) {
        const int kt = cc * 2 + kh;
        bf16x8 A_[2];
        #pragma unroll
        for (int nt = 0; nt < 2; ++nt) {
          int row = w * 32 + nt * 16 + q;
          A_[nt] = ldfrag(&sbuf[cur][0][row][kh * 32 + qt * 8]);
        }
        #pragma unroll
        for (int oh = 0; oh < 2; ++oh) {
          bf16x8 B_[8];
          #pragma unroll
          for (int ot = 0; ot < 8; ++ot)
            B_[ot] = *(const bf16x8*)(whb_ + ((size_t)((oh * 8 + ot) * 16 + kt) << 9) + lane * 8);
          #pragma unroll
          for (int nt = 0; nt < 2; ++nt)
            #pragma unroll
            for (int ot = 0; ot < 8; ++ot)
              acc[nt][oh * 8 + ot] = MFMA16(A_[nt], B_[ot], acc[nt][oh * 8 + ot]);
        }
      }
      if (cc < 7) CVTSTORE1(cur ^ 1)
      __syncthreads();
    }
    float (*pl)[67] = (float(*)[67])&sbuf[0][0][0][0];
    __syncthreads();
    #pragma unroll
    for (int oh = 0; oh < 4; ++oh) {
      if (oh) __syncthreads();
      #pragma unroll
      for (int nt = 0; nt < 2; ++nt)
        #pragma unroll
        for (int ot4 = 0; ot4 < 4; ++ot4)
          #pragma unroll
          for (int r = 0; r < 4; ++r)
            pl[w * 32 + nt * 16 + qt * 4 + r][ot4 * 16 + q] = acc[nt][oh * 4 + ot4][r];
      __syncthreads();
      const int wp = tid & 31;
      #pragma unroll
      for (int it = 0; it < 8; ++it) {
        int cc2 = (tid >> 5) + it * 8;
        int cv = oh * 64 + cc2;
        float v = fmaxf(fmaxf(pl[2 * wp][cc2], pl[2 * wp + 1][cc2]),
                        fmaxf(pl[64 + 2 * wp][cc2], pl[65 + 2 * wp][cc2])) + bh_[cv];
        size_t o = (((size_t)(b * 16 + (cv >> 4)) * 32 + hp) * 64 +
                    (wp >> 3) * 16 + (cv & 15)) * 8 + (wp & 7);
        vp[o] = f2bf(v);
      }
    }
  }
}

// ---------- fused attention: QB=64, 4 m-chunks of 256, XCD-local b, setprio ----------

#define PROW 264

__global__ __launch_bounds__(256, 2)
void attn_mfma(const unsigned short* __restrict__ f_, const unsigned short* __restrict__ fl_,
               const unsigned short* __restrict__ g_, const unsigned short* __restrict__ gl_,
               const unsigned short* __restrict__ vp, unsigned short* __restrict__ oT)
{
  __shared__ __align__(16) unsigned short PB[64 * PROW];    // 33,792 B (P, then obuf)
  __shared__ float redm[4][2][32], reds[4][2][32];
  __shared__ float rfrow[64], Srow[64];
  const int b = blockIdx.x & 7, bx = blockIdx.x >> 3;
  const int tid = threadIdx.x, w = tid >> 6, lane = tid & 63;
  const int q32 = lane & 31, hl = lane >> 5;
  const int q16 = lane & 15, qt = lane >> 4;

  bf16x8 Fh[2][4], Fl[2][4];
  #pragma unroll
  for (int qt2 = 0; qt2 < 2; ++qt2) {
    size_t fb = ((size_t)(b * 128 + bx * 2 + qt2) << 11) + lane * 8;
    #pragma unroll
    for (int s = 0; s < 4; ++s) {
      Fh[qt2][s] = *(const bf16x8*)(f_ + fb + (s << 9));
      Fl[qt2][s] = *(const bf16x8*)(fl_ + fb + (s << 9));
    }
  }

  float M0 = -3.0e38f, M1 = -3.0e38f;
  f32x4 oacc[4][4];       // [c4][qsub]
  #pragma unroll
  for (int c4 = 0; c4 < 4; ++c4)
    #pragma unroll
    for (int qs = 0; qs < 4; ++qs) oacc[c4][qs] = (f32x4){0.f, 0.f, 0.f, 0.f};
  const size_t vroot = ((size_t)(b * 16 + w * 4) * 32) * 512 + lane * 8;

#define VLD(C4, KS) (*(const bf16x8*)(vp + vroot + ((size_t)((C4) * 32 + mc * 8 + (KS)) << 9)))
#define LOADVA(KS) { va0 = VLD(0, KS); va1 = VLD(1, KS); va2 = VLD(2, KS); va3 = VLD(3, KS); }
#define LOADVB(KS) { vb0 = VLD(0, KS); vb1 = VLD(1, KS); vb2 = VLD(2, KS); vb3 = VLD(3, KS); }
#define PVMFMA(KS, V0, V1, V2, V3) { \
  bf16x8 pb0 = *(const bf16x8*)&PB[q16 * PROW + (KS) * 32 + qt * 8]; \
  bf16x8 pb1 = *(const bf16x8*)&PB[(16 + q16) * PROW + (KS) * 32 + qt * 8]; \
  bf16x8 pb2 = *(const bf16x8*)&PB[(32 + q16) * PROW + (KS) * 32 + qt * 8]; \
  bf16x8 pb3 = *(const bf16x8*)&PB[(48 + q16) * PROW + (KS) * 32 + qt * 8]; \
  oacc[0][0] = MFMA16(V0, pb0, oacc[0][0]); oacc[1][0] = MFMA16(V1, pb0, oacc[1][0]); \
  oacc[2][0] = MFMA16(V2, pb0, oacc[2][0]); oacc[3][0] = MFMA16(V3, pb0, oacc[3][0]); \
  oacc[0][1] = MFMA16(V0, pb1, oacc[0][1]); oacc[1][1] = MFMA16(V1, pb1, oacc[1][1]); \
  oacc[2][1] = MFMA16(V2, pb1, oacc[2][1]); oacc[3][1] = MFMA16(V3, pb1, oacc[3][1]); \
  oacc[0][2] = MFMA16(V0, pb2, oacc[0][2]); oacc[1][2] = MFMA16(V1, pb2, oacc[1][2]); \
  oacc[2][2] = MFMA16(V2, pb2, oacc[2][2]); oacc[3][2] = MFMA16(V3, pb2, oacc[3][2]); \
  oacc[0][3] = MFMA16(V0, pb3, oacc[0][3]); oacc[1][3] = MFMA16(V1, pb3, oacc[1][3]); \
  oacc[2][3] = MFMA16(V2, pb3, oacc[2][3]); oacc[3][3] = MFMA16(V3, pb3, oacc[3][3]); }

  #pragma unroll 1
  for (int mc = 0; mc < 4; ++mc) {
    // ---- s phase: 2 m-tiles x 2 q-tiles ----
    f32x16 sa0t0 = {}, sa0t1 = {}, sa1t0 = {}, sa1t1 = {};
    __builtin_amdgcn_s_setprio(1);
    #pragma unroll
    for (int t = 0; t < 2; ++t) {
      size_t gb = ((size_t)(b * 32 + mc * 8 + w * 2 + t) << 11) + lane * 8;
      bf16x8 Gh[4], Gl[4];
      #pragma unroll
      for (int s = 0; s < 4; ++s) {
        Gh[s] = *(const bf16x8*)(g_ + gb + (s << 9));
        Gl[s] = *(const bf16x8*)(gl_ + gb + (s << 9));
      }
      f32x16* s0 = t ? &sa0t1 : &sa0t0;
      f32x16* s1 = t ? &sa1t1 : &sa1t0;
      #pragma unroll
      for (int s = 0; s < 4; ++s) {
        *s0 = MFMA32(Gh[s], Fh[0][s], *s0);
        *s0 = MFMA32(Gh[s], Fl[0][s], *s0);
        *s0 = MFMA32(Gl[s], Fh[0][s], *s0);
        *s1 = MFMA32(Gh[s], Fh[1][s], *s1);
        *s1 = MFMA32(Gh[s], Fl[1][s], *s1);
        *s1 = MFMA32(Gl[s], Fh[1][s], *s1);
      }
    }
    __builtin_amdgcn_s_setprio(0);

    bf16x8 va0, va1, va2, va3, vb0, vb1, vb2, vb3;
    LOADVA(0)   // hoisted: independent of softmax

    // ---- online softmax (per q-tile) ----
    float mx0 = -3.0e38f, mx1 = -3.0e38f;
    #pragma unroll
    for (int r = 0; r < 16; ++r) {
      mx0 = fmaxf(mx0, fmaxf(sa0t0[r], sa0t1[r]));
      mx1 = fmaxf(mx1, fmaxf(sa1t0[r], sa1t1[r]));
    }
    mx0 = fmaxf(mx0, __shfl_xor(mx0, 32));
    mx1 = fmaxf(mx1, __shfl_xor(mx1, 32));
    if (lane < 32) { redm[w][0][lane] = mx0; redm[w][1][lane] = mx1; }
    __syncthreads();
    float gmx0 = fmaxf(fmaxf(redm[0][0][q32], redm[1][0][q32]), fmaxf(redm[2][0][q32], redm[3][0][q32]));
    float gmx1 = fmaxf(fmaxf(redm[0][1][q32], redm[1][1][q32]), fmaxf(redm[2][1][q32], redm[3][1][q32]));
    float Mn0 = fmaxf(M0, gmx0), Mn1 = fmaxf(M1, gmx1);
    float rf0 = __expf(M0 - Mn0), rf1 = __expf(M1 - Mn1);
    M0 = Mn0; M1 = Mn1;
    float cs0 = 0.f, cs1 = 0.f;
    #pragma unroll
    for (int r = 0; r < 16; ++r) {
      float p;
      p = __expf(sa0t0[r] - Mn0); sa0t0[r] = p; cs0 += p;
      p = __expf(sa0t1[r] - Mn0); sa0t1[r] = p; cs0 += p;
      p = __expf(sa1t0[r] - Mn1); sa1t0[r] = p; cs1 += p;
      p = __expf(sa1t1[r] - Mn1); sa1t1[r] = p; cs1 += p;
    }
    cs0 += __shfl_xor(cs0, 32);
    cs1 += __shfl_xor(cs1, 32);
    if (lane < 32) { reds[w][0][lane] = cs0; reds[w][1][lane] = cs1; }

    #pragma unroll
    for (int j = 0; j < 4; ++j) {
      uint2 pk;
      pk.x = (unsigned)f2bf(sa0t0[4*j+0]) | ((unsigned)f2bf(sa0t0[4*j+1]) << 16);
      pk.y = (unsigned)f2bf(sa0t0[4*j+2]) | ((unsigned)f2bf(sa0t0[4*j+3]) << 16);
      *(uint2*)&PB[q32 * PROW + w * 64 + j * 8 + hl * 4] = pk;
      pk.x = (unsigned)f2bf(sa0t1[4*j+0]) | ((unsigned)f2bf(sa0t1[4*j+1]) << 16);
      pk.y = (unsigned)f2bf(sa0t1[4*j+2]) | ((unsigned)f2bf(sa0t1[4*j+3]) << 16);
      *(uint2*)&PB[q32 * PROW + w * 64 + 32 + j * 8 + hl * 4] = pk;
      pk.x = (unsigned)f2bf(sa1t0[4*j+0]) | ((unsigned)f2bf(sa1t0[4*j+1]) << 16);
      pk.y = (unsigned)f2bf(sa1t0[4*j+2]) | ((unsigned)f2bf(sa1t0[4*j+3]) << 16);
      *(uint2*)&PB[(32 + q32) * PROW + w * 64 + j * 8 + hl * 4] = pk;
      pk.x = (unsigned)f2bf(sa1t1[4*j+0]) | ((unsigned)f2bf(sa1t1[4*j+1]) << 16);
      pk.y = (unsigned)f2bf(sa1t1[4*j+2]) | ((unsigned)f2bf(sa1t1[4*j+3]) << 16);
      *(uint2*)&PB[(32 + q32) * PROW + w * 64 + 32 + j * 8 + hl * 4] = pk;
    }
    __syncthreads();
    float ct0 = reds[0][0][q32] + reds[1][0][q32] + reds[2][0][q32] + reds[3][0][q32];
    float ct1 = reds[0][1][q32] + reds[1][1][q32] + reds[2][1][q32] + reds[3][1][q32];
    if (w == 0 && lane < 32) {
      Srow[lane]      = (mc == 0) ? ct0 : Srow[lane]      * rf0 + ct0;
      Srow[32 + lane] = (mc == 0) ? ct1 : Srow[32 + lane] * rf1 + ct1;
      rfrow[lane] = rf0; rfrow[32 + lane] = rf1;
    }
    __syncthreads();

    // ---- PV over this chunk ----
    if (mc > 0) {
      float rfq[4];
      #pragma unroll
      for (int qs = 0; qs < 4; ++qs) rfq[qs] = rfrow[qs * 16 + q16];
      #pragma unroll
      for (int c4 = 0; c4 < 4; ++c4)
        #pragma unroll
        for (int qs = 0; qs < 4; ++qs) oacc[c4][qs] *= rfq[qs];
    }
    LOADVB(1)
    __builtin_amdgcn_s_setprio(1);
    #pragma unroll
    for (int kp = 0; kp < 4; ++kp) {
      PVMFMA(2 * kp, va0, va1, va2, va3)
      if (2 * kp + 2 < 8) LOADVA(2 * kp + 2)
      PVMFMA(2 * kp + 1, vb0, vb1, vb2, vb3)
      if (2 * kp + 3 < 8) LOADVB(2 * kp + 3)
    }
    __builtin_amdgcn_s_setprio(0);
  }

  // ---- epilogue: stage into PB (obuf[n 64][cv 256], stride PROW), then 16B/lane block write ----
  __syncthreads();
  float rinv[4];
  #pragma unroll
  for (int qs = 0; qs < 4; ++qs) rinv[qs] = 1.0f / Srow[qs * 16 + q16];
  #pragma unroll
  for (int c4 = 0; c4 < 4; ++c4)
    #pragma unroll
    for (int qs = 0; qs < 4; ++qs) {
      uint2 pk;
      pk.x = (unsigned)f2bf(oacc[c4][qs][0] * rinv[qs]) | ((unsigned)f2bf(oacc[c4][qs][1] * rinv[qs]) << 16);
      pk.y = (unsigned)f2bf(oacc[c4][qs][2] * rinv[qs]) | ((unsigned)f2bf(oacc[c4][qs][3] * rinv[qs]) << 16);
      *(uint2*)&PB[(qs * 16 + q16) * PROW + w * 64 + c4 * 16 + qt * 4] = pk;
    }
  __syncthreads();
  const size_t obase = (size_t)(b * 256 + bx * 4) * 4096;
  #pragma unroll
  for (int it = 0; it < 8; ++it) {
    int u = it * 256 + tid;      // 16B unit
    int so = u * 8;              // shorts
    int ntl = so >> 12;
    int rem = so & 4095;
    int ks = rem >> 9;
    int slot = (rem >> 3) & 63;
    int qq = slot & 15, cg = slot >> 4;
    uint4 val = *(const uint4*)&PB[(ntl * 16 + qq) * PROW + ks * 32 + cg * 8];
    *(uint4*)(oT + obase + so) = val;
  }
}

// ---------- final conv: FM A (oT) and FM W, XCD-local b ----------

__global__ __launch_bounds__(256)
void conv_final(const unsigned short* __restrict__ A, const unsigned short* __restrict__ W,
                const float* __restrict__ bias, float* __restrict__ out,
                const float* __restrict__ resid, const float* __restrict__ gamma_p)
{
  const int bid = blockIdx.x;
  const int b = bid & 7;
  const int idx = bid >> 3;
  const int n0 = (idx & 31) * 128;
  const int oc0 = (idx >> 5) * 128;
  const int tid = threadIdx.x, w = tid >> 6, lane = tid & 63, q = lane & 15, qt = lane >> 4;

  f32x4 acc[2][8];
  #pragma unroll
  for (int nt = 0; nt < 2; ++nt)
    #pragma unroll
    for (int ot = 0; ot < 8; ++ot) acc[nt][ot] = (f32x4){0.f, 0.f, 0.f, 0.f};

  #pragma unroll
  for (int ks = 0; ks < 8; ++ks) {
    bf16x8 A_[2], B_[8];
    #pragma unroll
    for (int nt = 0; nt < 2; ++nt)
      A_[nt] = *(const bf16x8*)(A + (((size_t)(b * 256 + (n0 >> 4) + w * 2 + nt) * 8 + ks) << 9) + lane * 8);
    #pragma unroll
    for (int ot = 0; ot < 8; ++ot)
      B_[ot] = *(const bf16x8*)(W + (((size_t)((oc0 >> 4) + ot) * 8 + ks) << 9) + lane * 8);
    #pragma unroll
    for (int nt = 0; nt < 2; ++nt)
      #pragma unroll
      for (int ot = 0; ot < 8; ++ot)
        acc[nt][ot] = MFMA16(A_[nt], B_[ot], acc[nt][ot]);
  }

  const float gm = gamma_p[0];
  #pragma unroll
  for (int ot = 0; ot < 8; ++ot) {
    int oc = oc0 + ot * 16 + q;
    float bs = bias[oc];
    #pragma unroll
    for (int nt = 0; nt < 2; ++nt) {
      int n = n0 + w * 32 + nt * 16 + qt * 4;
      size_t o = ((size_t)(b * 512) + oc) * 4096 + n;
      float4 rs = *(const float4*)&resid[o];
      float4 ov;
      ov.x = gm * (acc[nt][ot][0] + bs) + rs.x;
      ov.y = gm * (acc[nt][ot][1] + bs) + rs.y;
      ov.z = gm * (acc[nt][ot][2] + bs) + rs.z;
      ov.w = gm * (acc[nt][ot][3] + bs) + rs.w;
      *(float4*)&out[o] = ov;
    }
  }
}

// ---------- launch ----------

extern "C" void kernel_launch(void* const* d_in, const int* in_sizes, int n_in,
                              void* d_out, int out_size, void* d_ws, size_t ws_size,
                              hipStream_t stream) {
  const float* x     = (const float*)d_in[0];
  const float* Wf    = (const float*)d_in[1];
  const float* bf    = (const float*)d_in[2];
  const float* Wg    = (const float*)d_in[3];
  const float* bg    = (const float*)d_in[4];
  const float* Wh    = (const float*)d_in[5];
  const float* bh    = (const float*)d_in[6];
  const float* Wv    = (const float*)d_in[7];
  const float* bv    = (const float*)d_in[8];
  const float* gamma = (const float*)d_in[9];
  float* out = (float*)d_out;
  char* w = (char*)d_ws;

  unsigned short* fhi = (unsigned short*)(w);                 // 4 MB  FM [8][128][4][512]
  unsigned short* flo = (unsigned short*)(w + 4194304);       // 4 MB
  unsigned short* ghi = (unsigned short*)(w + 8388608);       // 1 MB  FM [8][32][4][512]
  unsigned short* glo = (unsigned short*)(w + 9437184);       // 1 MB
  unsigned short* vp  = (unsigned short*)(w + 10485760);      // 4 MB  FM [8][16][32][512]
  unsigned short* oT  = (unsigned short*)(w + 14680064);      // 16 MB FM [8][256][8][512]
  unsigned short* wfh = (unsigned short*)(w + 31457280);      // 64 KB FM
  unsigned short* wfl = (unsigned short*)(w + 31522816);
  unsigned short* wgh = (unsigned short*)(w + 31588352);
  unsigned short* wgl = (unsigned short*)(w + 31653888);
  unsigned short* whb = (unsigned short*)(w + 31719424);      // 256 KB FM
  unsigned short* wvb = (unsigned short*)(w + 31981568);      // 256 KB FM

  prep_k<<<1280, 256, 0, stream>>>(Wf, Wg, Wh, Wv, wfh, wfl, wgh, wgl, whb, wvb);

  conv_all<<<512, 256, 0, stream>>>(x, wfh, wfl, wgh, wgl, whb,
                                    bf, bg, bh, fhi, flo, ghi, glo, vp);

  attn_mfma<<<512, 256, 0, stream>>>(fhi, flo, ghi, glo, vp, oT);

  conv_final<<<1024, 256, 0, stream>>>(oT, wvb, bv, out, x, gamma);
}